// Round 3
// baseline (7080.716 us; speedup 1.0000x reference)
//
#include <hip/hip_runtime.h>
#include <hip/hip_bf16.h>
#include <cstddef>
#include <cstdint>

typedef __hip_bfloat16 bf16;

// ---------- helpers ----------
__device__ inline float ldf(const float* p) { return *p; }
__device__ inline float ldf(const bf16* p) { return __bfloat162float(*p); }
__device__ inline void stf(float* p, float v) { *p = v; }
__device__ inline void stf(bf16* p, float v) { *p = __float2bfloat16(v); }

// Problem constants
// BS=32, T=64, NE=32, NA=8, ED=128, H=512, A=512, NH=8, HD=64, NACT=32

// ---------- generic tiled GEMM ----------
template<int ACT, bool BT, bool QG, bool MASKQ, typename TA, typename TB, typename TC>
__global__ __launch_bounds__(256) void gemm_k(
    const TA* __restrict__ A, const TB* __restrict__ B,
    const float* __restrict__ bias, TC* __restrict__ C,
    int M, int N, int K, const int* __restrict__ smask)
{
    const int BM = 64, BN = 64, BK = 16;
    __shared__ float As[BM][BK + 1];
    __shared__ float Bs[BK][BN + 1];
    int tid = threadIdx.x;
    int n0 = blockIdx.x * BN;
    int m0 = blockIdx.y * BM;
    int ty = tid >> 4, tx = tid & 15;
    float acc[4][4] = {};

    for (int k0 = 0; k0 < K; k0 += BK) {
        #pragma unroll
        for (int i = 0; i < 4; ++i) {
            int l = tid * 4 + i;
            int r = l >> 4, c = l & 15;
            int gm = m0 + r;
            int ar = QG ? (((gm >> 3) << 5) | (gm & 7)) : gm;
            As[r][c] = ldf(&A[(size_t)ar * K + k0 + c]);
        }
        #pragma unroll
        for (int i = 0; i < 4; ++i) {
            int l = tid * 4 + i;
            if (BT) {
                int n = l >> 4, kk = l & 15;
                int gn = n0 + n;
                Bs[kk][n] = (gn < N) ? ldf(&B[(size_t)gn * K + k0 + kk]) : 0.f;
            } else {
                int r = l >> 6, c = l & 63;
                int gn = n0 + c;
                Bs[r][c] = (gn < N) ? ldf(&B[(size_t)(k0 + r) * N + gn]) : 0.f;
            }
        }
        __syncthreads();
        #pragma unroll
        for (int kk = 0; kk < BK; ++kk) {
            float a[4], b[4];
            #pragma unroll
            for (int i = 0; i < 4; ++i) a[i] = As[ty + i * 16][kk];
            #pragma unroll
            for (int j = 0; j < 4; ++j) b[j] = Bs[kk][tx + j * 16];
            #pragma unroll
            for (int i = 0; i < 4; ++i)
                #pragma unroll
                for (int j = 0; j < 4; ++j) acc[i][j] += a[i] * b[j];
        }
        __syncthreads();
    }

    #pragma unroll
    for (int i = 0; i < 4; ++i) {
        int gm = m0 + ty + i * 16;
        bool mz = false;
        if (MASKQ) {
            int a_ = gm & 7, t_ = (gm >> 3) & 63, b_ = gm >> 9;
            mz = smask[((b_ << 6) + t_) * 32 + a_] != 0;
        }
        #pragma unroll
        for (int j = 0; j < 4; ++j) {
            int gn = n0 + tx + j * 16;
            if (gn < N) {
                float v = acc[i][j] + bias[gn];
                if (ACT == 1) v = fmaxf(v, 0.f);
                if (MASKQ && mz) v = 0.f;
                stf(&C[(size_t)gm * N + gn], v);
            }
        }
    }
}

// ---------- attention: one wave per (b,t,h) ----------
__global__ __launch_bounds__(64) void attn_k(
    const bf16* __restrict__ qb, const bf16* __restrict__ kb, const bf16* __restrict__ vb,
    const int* __restrict__ obs, const int* __restrict__ smask, float* __restrict__ xs)
{
    __shared__ float qs[8 * 64], ks[32 * 64], vs[32 * 64], wsm[8 * 32];
    int bid = blockIdx.x;
    int h = bid & 7;
    int bt = bid >> 3;
    int t = bt & 63, b = bt >> 6;
    int tid = threadIdx.x;

    #pragma unroll
    for (int i = 0; i < 8; ++i) {
        int l = tid + i * 64;
        int e = l >> 6, d = l & 63;
        qs[l] = __bfloat162float(qb[((size_t)bt * 8 + e) * 512 + h * 64 + d]);
    }
    #pragma unroll
    for (int i = 0; i < 32; ++i) {
        int l = tid + i * 64;
        int e = l >> 6, d = l & 63;
        ks[l] = __bfloat162float(kb[((size_t)bt * 32 + e) * 512 + h * 64 + d]);
        vs[l] = __bfloat162float(vb[((size_t)bt * 32 + e) * 512 + h * 64 + d]);
    }
    __syncthreads();

    int ql = tid >> 3, jl = tid & 7;
    float s[4];
    #pragma unroll
    for (int c = 0; c < 4; ++c) {
        int kl = jl + c * 8;
        float acc = 0.f;
        for (int d = 0; d < 64; ++d) acc += qs[ql * 64 + d] * ks[kl * 64 + d];
        acc *= 0.125f;
        bool m = obs[(((size_t)bt * 32) + ql) * 32 + kl] != 0;
        s[c] = m ? -__builtin_inff() : acc;
    }
    float mx = fmaxf(fmaxf(s[0], s[1]), fmaxf(s[2], s[3]));
    for (int off = 1; off < 8; off <<= 1) mx = fmaxf(mx, __shfl_xor(mx, off));
    float e4[4]; float sum = 0.f;
    bool allmasked = (mx == -__builtin_inff());
    #pragma unroll
    for (int c = 0; c < 4; ++c) {
        e4[c] = (allmasked || s[c] == -__builtin_inff()) ? 0.f : expf(s[c] - mx);
        sum += e4[c];
    }
    for (int off = 1; off < 8; off <<= 1) sum += __shfl_xor(sum, off);
    float inv = (sum > 0.f) ? 1.f / sum : 0.f;
    #pragma unroll
    for (int c = 0; c < 4; ++c) wsm[ql * 32 + jl + c * 8] = e4[c] * inv;
    __syncthreads();

    bool amask = smask[(size_t)bt * 32 + ql] != 0;
    #pragma unroll
    for (int dd = 0; dd < 8; ++dd) {
        int d = jl + dd * 8;
        float acc = 0.f;
        for (int kl = 0; kl < 32; ++kl) acc += wsm[ql * 32 + kl] * vs[kl * 64 + d];
        if (amask) acc = 0.f;
        xs[((size_t)(t * 256 + b * 8 + ql)) * 512 + h * 64 + d] = acc;
    }
}

// ---------- persistent GRU: 1 launch, 64 steps, grid barrier per step ----------
// grid = 256 WGs x 256 thr. WG (mi,ni): rows mi*16..+15, h-cols ni*32..+31.
// Lane (l=tid&15, cg=tid>>4): row = mi*16+l, cols c1=ni*32+2*cg, c2=c1+1.
// gi: [64*256,1536] f32 (includes bih). Whh: [1536,512] f32. bhh: [1536].
__global__ __launch_bounds__(256) void gru_persist_k(
    const float* __restrict__ gi, const float* __restrict__ Whh,
    const float* __restrict__ bhh, const float* __restrict__ h0,
    float* __restrict__ hb0, float* __restrict__ hb1,
    const int* __restrict__ smask, float* __restrict__ hs_out,
    int* __restrict__ bar)
{
    __shared__ float hls[16 * 516];   // 16 rows x 512 cols, stride 516 (bank pad)
    const int tid = threadIdx.x;
    const int wg  = blockIdx.x;
    const int mi = wg >> 4, ni = wg & 15;
    const int r0 = mi * 16;
    const int l  = tid & 15, cg = tid >> 4;
    const int row = r0 + l;
    const int c1 = ni * 32 + cg * 2, c2 = c1 + 1;

    const float* w_r1 = Whh + (size_t)(c1) * 512;
    const float* w_r2 = Whh + (size_t)(c2) * 512;
    const float* w_z1 = Whh + (size_t)(512 + c1) * 512;
    const float* w_z2 = Whh + (size_t)(512 + c2) * 512;
    const float* w_n1 = Whh + (size_t)(1024 + c1) * 512;
    const float* w_n2 = Whh + (size_t)(1024 + c2) * 512;
    const float bh_r1 = bhh[c1], bh_r2 = bhh[c2];
    const float bh_z1 = bhh[512 + c1], bh_z2 = bhh[512 + c2];
    const float bh_n1 = bhh[1024 + c1], bh_n2 = bhh[1024 + c2];
    const int b_ = row >> 3, a_ = row & 7;

    for (int t = 0; t < 64; ++t) {
        const float* hsrc = (t == 0) ? h0 : ((t & 1) ? hb0 : hb1);
        // stage h rows r0..r0+15 (all 512 cols) into LDS, coalesced float4
        #pragma unroll
        for (int i = 0; i < 8; ++i) {
            int f = i * 1024 + tid * 4;
            int rr = f >> 9, cc = f & 511;
            float4 v = *(const float4*)(hsrc + (size_t)(r0 + rr) * 512 + cc);
            *(float4*)&hls[rr * 516 + cc] = v;
        }
        __syncthreads();

        float ar1 = 0.f, az1 = 0.f, an1 = 0.f, ar2 = 0.f, az2 = 0.f, an2 = 0.f;
        #pragma unroll 2
        for (int k = 0; k < 512; k += 4) {
            float4 hv  = *(const float4*)&hls[l * 516 + k];
            float4 vr1 = *(const float4*)(w_r1 + k);
            float4 vz1 = *(const float4*)(w_z1 + k);
            float4 vn1 = *(const float4*)(w_n1 + k);
            float4 vr2 = *(const float4*)(w_r2 + k);
            float4 vz2 = *(const float4*)(w_z2 + k);
            float4 vn2 = *(const float4*)(w_n2 + k);
            ar1 += hv.x * vr1.x + hv.y * vr1.y + hv.z * vr1.z + hv.w * vr1.w;
            az1 += hv.x * vz1.x + hv.y * vz1.y + hv.z * vz1.z + hv.w * vz1.w;
            an1 += hv.x * vn1.x + hv.y * vn1.y + hv.z * vn1.z + hv.w * vn1.w;
            ar2 += hv.x * vr2.x + hv.y * vr2.y + hv.z * vr2.z + hv.w * vr2.w;
            az2 += hv.x * vz2.x + hv.y * vz2.y + hv.z * vz2.z + hv.w * vz2.w;
            an2 += hv.x * vn2.x + hv.y * vn2.y + hv.z * vn2.z + hv.w * vn2.w;
        }

        size_t gb = ((size_t)t * 256 + row) * 1536;
        float2 gr = *(const float2*)(gi + gb + c1);
        float2 gz = *(const float2*)(gi + gb + 512 + c1);
        float2 gn = *(const float2*)(gi + gb + 1024 + c1);
        float hp1 = hls[l * 516 + c1], hp2 = hls[l * 516 + c2];
        float r1 = 1.f / (1.f + expf(-(gr.x + ar1 + bh_r1)));
        float r2 = 1.f / (1.f + expf(-(gr.y + ar2 + bh_r2)));
        float z1 = 1.f / (1.f + expf(-(gz.x + az1 + bh_z1)));
        float z2 = 1.f / (1.f + expf(-(gz.y + az2 + bh_z2)));
        float n1 = tanhf(gn.x + r1 * (an1 + bh_n1));
        float n2 = tanhf(gn.y + r2 * (an2 + bh_n2));
        float hn1 = (1.f - z1) * n1 + z1 * hp1;
        float hn2 = (1.f - z2) * n2 + z2 * hp2;

        float* hdst = (t & 1) ? hb1 : hb0;
        *(float2*)(hdst + (size_t)row * 512 + c1) = make_float2(hn1, hn2);
        bool m = smask[((b_ << 6) + t) * 32 + a_] != 0;
        size_t orow = ((size_t)((b_ << 6) + t) * 8 + a_) * 512;
        *(float2*)(hs_out + orow + c1) = make_float2(m ? 0.f : hn1, m ? 0.f : hn2);

        // grid barrier (skip after last step)
        if (t != 63) {
            __threadfence();
            __syncthreads();
            if (tid == 0) {
                atomicAdd(bar + t, 1);
                long it = 0;
                while (__hip_atomic_load(bar + t, __ATOMIC_RELAXED,
                                         __HIP_MEMORY_SCOPE_AGENT) < 256 &&
                       it < 100000000L) {
                    __builtin_amdgcn_s_sleep(2);
                    ++it;
                }
            }
            __syncthreads();
            __threadfence();
        }
    }
}

// ---------- launch ----------
extern "C" void kernel_launch(void* const* d_in, const int* in_sizes, int n_in,
                              void* d_out, int out_size, void* d_ws, size_t ws_size,
                              hipStream_t stream)
{
    const float* inputs = (const float*)d_in[0];
    const int*   obs    = (const int*)d_in[1];
    const int*   smask  = (const int*)d_in[2];
    const float* h0     = (const float*)d_in[3];
    const float* W1  = (const float*)d_in[4];  const float* b1  = (const float*)d_in[5];
    const float* Wq  = (const float*)d_in[6];  const float* bq  = (const float*)d_in[7];
    const float* Wk  = (const float*)d_in[8];  const float* bk  = (const float*)d_in[9];
    const float* Wv  = (const float*)d_in[10]; const float* bv  = (const float*)d_in[11];
    const float* Wih = (const float*)d_in[12]; const float* bih = (const float*)d_in[13];
    const float* Whh = (const float*)d_in[14]; const float* bhh = (const float*)d_in[15];
    const float* Wo  = (const float*)d_in[16]; const float* bo  = (const float*)d_in[17];

    char* ws = (char*)d_ws;
    bf16*  x  = (bf16*)(ws + 0);
    float* xs = (float*)(ws + 0);
    bf16* qb = (bf16*)(ws + 67108864ull);
    bf16* kb = (bf16*)(ws + 83886080ull);
    bf16* vb = (bf16*)(ws + 150994944ull);
    float* gi = (float*)(ws + 67108864ull);
    float* hbuf0 = (float*)(ws + 218103808ull);
    float* hbuf1 = (float*)(ws + 218628096ull);
    int*   bar   = (int*)(ws + 219152384ull);   // 64 ints

    float* out    = (float*)d_out;
    float* hs_out = out + 524288;

    hipMemsetAsync(bar, 0, 256, stream);

    // 1. fc1
    gemm_k<1, false, false, false><<<dim3(8, 1024), 256, 0, stream>>>(
        inputs, W1, b1, x, 65536, 512, 128, nullptr);
    // 2. q (gathered agent rows)
    gemm_k<0, false, true, false><<<dim3(8, 256), 256, 0, stream>>>(
        x, Wq, bq, qb, 16384, 512, 512, nullptr);
    // 3. k
    gemm_k<0, false, false, false><<<dim3(8, 1024), 256, 0, stream>>>(
        x, Wk, bk, kb, 65536, 512, 512, nullptr);
    // 4. v
    gemm_k<1, false, false, false><<<dim3(8, 1024), 256, 0, stream>>>(
        x, Wv, bv, vb, 65536, 512, 512, nullptr);
    // 5. attention -> xs f32 (region A; x dead)
    attn_k<<<dim3(16384), 64, 0, stream>>>(qb, kb, vb, obs, smask, xs);
    // 6. gi = xs @ Wih^T + bih (region B; q/k/v dead)
    gemm_k<0, true, false, false><<<dim3(24, 256), 256, 0, stream>>>(
        xs, Wih, bih, gi, 16384, 1536, 512, nullptr);
    // 7. persistent GRU: one launch, all 64 steps
    gru_persist_k<<<dim3(256), 256, 0, stream>>>(
        gi, Whh, bhh, h0, hbuf0, hbuf1, smask, hs_out, bar);
    // 8. qout
    gemm_k<0, false, false, true><<<dim3(1, 256), 256, 0, stream>>>(
        hs_out, Wo, bo, out, 16384, 32, 512, smask);
}

// Round 4
// 3705.061 us; speedup vs baseline: 1.9111x; 1.9111x over previous
//
#include <hip/hip_runtime.h>
#include <hip/hip_bf16.h>
#include <cstddef>
#include <cstdint>

typedef __hip_bfloat16 bf16;
typedef __attribute__((ext_vector_type(2))) _Float16 half2v;

// ---------- helpers ----------
__device__ inline float ldf(const float* p) { return *p; }
__device__ inline float ldf(const bf16* p) { return __bfloat162float(*p); }
__device__ inline void stf(float* p, float v) { *p = v; }
__device__ inline void stf(bf16* p, float v) { *p = __float2bfloat16(v); }

__device__ inline float dot2f(uint32_t a, uint32_t b, float c) {
#if __has_builtin(__builtin_amdgcn_fdot2)
    return __builtin_amdgcn_fdot2(__builtin_bit_cast(half2v, a),
                                  __builtin_bit_cast(half2v, b), c, false);
#else
    union { uint32_t u; _Float16 h[2]; } ua, ub;
    ua.u = a; ub.u = b;
    return c + (float)ua.h[0] * (float)ub.h[0] + (float)ua.h[1] * (float)ub.h[1];
#endif
}

// Problem constants: BS=32, T=64, NE=32, NA=8, ED=128, H=512, A=512, NH=8, HD=64, NACT=32

// ---------- generic tiled GEMM (unchanged from round 2) ----------
template<int ACT, bool BT, bool QG, bool MASKQ, typename TA, typename TB, typename TC>
__global__ __launch_bounds__(256) void gemm_k(
    const TA* __restrict__ A, const TB* __restrict__ B,
    const float* __restrict__ bias, TC* __restrict__ C,
    int M, int N, int K, const int* __restrict__ smask)
{
    const int BM = 64, BN = 64, BK = 16;
    __shared__ float As[BM][BK + 1];
    __shared__ float Bs[BK][BN + 1];
    int tid = threadIdx.x;
    int n0 = blockIdx.x * BN;
    int m0 = blockIdx.y * BM;
    int ty = tid >> 4, tx = tid & 15;
    float acc[4][4] = {};

    for (int k0 = 0; k0 < K; k0 += BK) {
        #pragma unroll
        for (int i = 0; i < 4; ++i) {
            int l = tid * 4 + i;
            int r = l >> 4, c = l & 15;
            int gm = m0 + r;
            int ar = QG ? (((gm >> 3) << 5) | (gm & 7)) : gm;
            As[r][c] = ldf(&A[(size_t)ar * K + k0 + c]);
        }
        #pragma unroll
        for (int i = 0; i < 4; ++i) {
            int l = tid * 4 + i;
            if (BT) {
                int n = l >> 4, kk = l & 15;
                int gn = n0 + n;
                Bs[kk][n] = (gn < N) ? ldf(&B[(size_t)gn * K + k0 + kk]) : 0.f;
            } else {
                int r = l >> 6, c = l & 63;
                int gn = n0 + c;
                Bs[r][c] = (gn < N) ? ldf(&B[(size_t)(k0 + r) * N + gn]) : 0.f;
            }
        }
        __syncthreads();
        #pragma unroll
        for (int kk = 0; kk < BK; ++kk) {
            float a[4], b[4];
            #pragma unroll
            for (int i = 0; i < 4; ++i) a[i] = As[ty + i * 16][kk];
            #pragma unroll
            for (int j = 0; j < 4; ++j) b[j] = Bs[kk][tx + j * 16];
            #pragma unroll
            for (int i = 0; i < 4; ++i)
                #pragma unroll
                for (int j = 0; j < 4; ++j) acc[i][j] += a[i] * b[j];
        }
        __syncthreads();
    }

    #pragma unroll
    for (int i = 0; i < 4; ++i) {
        int gm = m0 + ty + i * 16;
        bool mz = false;
        if (MASKQ) {
            int a_ = gm & 7, t_ = (gm >> 3) & 63, b_ = gm >> 9;
            mz = smask[((b_ << 6) + t_) * 32 + a_] != 0;
        }
        #pragma unroll
        for (int j = 0; j < 4; ++j) {
            int gn = n0 + tx + j * 16;
            if (gn < N) {
                float v = acc[i][j] + bias[gn];
                if (ACT == 1) v = fmaxf(v, 0.f);
                if (MASKQ && mz) v = 0.f;
                stf(&C[(size_t)gm * N + gn], v);
            }
        }
    }
}

// ---------- attention (unchanged) ----------
__global__ __launch_bounds__(64) void attn_k(
    const bf16* __restrict__ qb, const bf16* __restrict__ kb, const bf16* __restrict__ vb,
    const int* __restrict__ obs, const int* __restrict__ smask, float* __restrict__ xs)
{
    __shared__ float qs[8 * 64], ks[32 * 64], vs[32 * 64], wsm[8 * 32];
    int bid = blockIdx.x;
    int h = bid & 7;
    int bt = bid >> 3;
    int t = bt & 63, b = bt >> 6;
    int tid = threadIdx.x;

    #pragma unroll
    for (int i = 0; i < 8; ++i) {
        int l = tid + i * 64;
        int e = l >> 6, d = l & 63;
        qs[l] = __bfloat162float(qb[((size_t)bt * 8 + e) * 512 + h * 64 + d]);
    }
    #pragma unroll
    for (int i = 0; i < 32; ++i) {
        int l = tid + i * 64;
        int e = l >> 6, d = l & 63;
        ks[l] = __bfloat162float(kb[((size_t)bt * 32 + e) * 512 + h * 64 + d]);
        vs[l] = __bfloat162float(vb[((size_t)bt * 32 + e) * 512 + h * 64 + d]);
    }
    __syncthreads();

    int ql = tid >> 3, jl = tid & 7;
    float s[4];
    #pragma unroll
    for (int c = 0; c < 4; ++c) {
        int kl = jl + c * 8;
        float acc = 0.f;
        for (int d = 0; d < 64; ++d) acc += qs[ql * 64 + d] * ks[kl * 64 + d];
        acc *= 0.125f;
        bool m = obs[(((size_t)bt * 32) + ql) * 32 + kl] != 0;
        s[c] = m ? -__builtin_inff() : acc;
    }
    float mx = fmaxf(fmaxf(s[0], s[1]), fmaxf(s[2], s[3]));
    for (int off = 1; off < 8; off <<= 1) mx = fmaxf(mx, __shfl_xor(mx, off));
    float e4[4]; float sum = 0.f;
    bool allmasked = (mx == -__builtin_inff());
    #pragma unroll
    for (int c = 0; c < 4; ++c) {
        e4[c] = (allmasked || s[c] == -__builtin_inff()) ? 0.f : expf(s[c] - mx);
        sum += e4[c];
    }
    for (int off = 1; off < 8; off <<= 1) sum += __shfl_xor(sum, off);
    float inv = (sum > 0.f) ? 1.f / sum : 0.f;
    #pragma unroll
    for (int c = 0; c < 4; ++c) wsm[ql * 32 + jl + c * 8] = e4[c] * inv;
    __syncthreads();

    bool amask = smask[(size_t)bt * 32 + ql] != 0;
    #pragma unroll
    for (int dd = 0; dd < 8; ++dd) {
        int d = jl + dd * 8;
        float acc = 0.f;
        for (int kl = 0; kl < 32; ++kl) acc += wsm[ql * 32 + kl] * vs[kl * 64 + d];
        if (amask) acc = 0.f;
        xs[((size_t)(t * 256 + b * 8 + ql)) * 512 + h * 64 + d] = acc;
    }
}

// ---------- Whh prep: [1536][512] f32 -> w2[k2][1536] u32 (f16x2 over k-pairs) ----------
__global__ __launch_bounds__(256) void prep_whh_k(
    const float* __restrict__ Whh, uint32_t* __restrict__ w2)
{
    int idx = blockIdx.x * 256 + threadIdx.x;   // 0..393215
    int gc = idx >> 8;                           // 0..1535 (gate-col)
    int k2 = idx & 255;                          // k-pair
    float2 wv = *(const float2*)(Whh + (size_t)gc * 512 + 2 * k2);
    half2v h; h[0] = (_Float16)wv.x; h[1] = (_Float16)wv.y;
    w2[(size_t)k2 * 1536 + gc] = __builtin_bit_cast(uint32_t, h);
}

// ---------- fused GRU: 128 WGs x 256 thr, 2 rows/WG, 64 steps, NO grid sync ----------
// Row-independence: h_next[row] depends only on h_prev[row]. h lives in regs+LDS.
// gi: [64*256][1536] f32 (includes bih). w2: f16x2-packed Whh^T. bhh: [1536].
__global__ __launch_bounds__(256) void gru_fused_k(
    const float* __restrict__ gi, const uint32_t* __restrict__ w2,
    const float* __restrict__ bhh, const float* __restrict__ h0,
    const int* __restrict__ smask, float* __restrict__ hs_out)
{
    __shared__ uint32_t h2s[512];   // [2 rows][256 k-pairs] f16x2
    const int tid = threadIdx.x;
    const int r0 = blockIdx.x * 2;
    const int c0 = tid * 2;

    const float bhr0 = bhh[c0],        bhr1 = bhh[c0 + 1];
    const float bhz0 = bhh[512 + c0],  bhz1 = bhh[512 + c0 + 1];
    const float bhn0 = bhh[1024 + c0], bhn1 = bhh[1024 + c0 + 1];

    float hA0 = h0[(size_t)r0 * 512 + c0],       hA1 = h0[(size_t)r0 * 512 + c0 + 1];
    float hB0 = h0[(size_t)(r0 + 1) * 512 + c0], hB1 = h0[(size_t)(r0 + 1) * 512 + c0 + 1];
    {
        half2v pa; pa[0] = (_Float16)hA0; pa[1] = (_Float16)hA1;
        half2v pb; pb[0] = (_Float16)hB0; pb[1] = (_Float16)hB1;
        h2s[tid]       = __builtin_bit_cast(uint32_t, pa);
        h2s[256 + tid] = __builtin_bit_cast(uint32_t, pb);
    }
    const int bA = r0 >> 3, aA = r0 & 7;
    const int bB = (r0 + 1) >> 3, aB = (r0 + 1) & 7;
    __syncthreads();

    for (int t = 0; t < 64; ++t) {
        size_t gbA = ((size_t)t * 256 + r0) * 1536;
        size_t gbB = gbA + 1536;
        float2 girA = *(const float2*)(gi + gbA + c0);
        float2 gizA = *(const float2*)(gi + gbA + 512 + c0);
        float2 ginA = *(const float2*)(gi + gbA + 1024 + c0);
        float2 girB = *(const float2*)(gi + gbB + c0);
        float2 gizB = *(const float2*)(gi + gbB + 512 + c0);
        float2 ginB = *(const float2*)(gi + gbB + 1024 + c0);

        float arA0 = 0, arA1 = 0, azA0 = 0, azA1 = 0, anA0 = 0, anA1 = 0;
        float arB0 = 0, arB1 = 0, azB0 = 0, azB1 = 0, anB0 = 0, anB1 = 0;

        for (int k4 = 0; k4 < 256; k4 += 4) {
            uint4 hA4 = *(const uint4*)&h2s[k4];
            uint4 hB4 = *(const uint4*)&h2s[256 + k4];
            uint32_t ha[4] = {hA4.x, hA4.y, hA4.z, hA4.w};
            uint32_t hb[4] = {hB4.x, hB4.y, hB4.z, hB4.w};
            #pragma unroll
            for (int u = 0; u < 4; ++u) {
                const uint32_t* wp = w2 + (size_t)(k4 + u) * 1536;
                uint2 wr = *(const uint2*)(wp + c0);
                uint2 wz = *(const uint2*)(wp + 512 + c0);
                uint2 wn = *(const uint2*)(wp + 1024 + c0);
                arA0 = dot2f(ha[u], wr.x, arA0); arA1 = dot2f(ha[u], wr.y, arA1);
                azA0 = dot2f(ha[u], wz.x, azA0); azA1 = dot2f(ha[u], wz.y, azA1);
                anA0 = dot2f(ha[u], wn.x, anA0); anA1 = dot2f(ha[u], wn.y, anA1);
                arB0 = dot2f(hb[u], wr.x, arB0); arB1 = dot2f(hb[u], wr.y, arB1);
                azB0 = dot2f(hb[u], wz.x, azB0); azB1 = dot2f(hb[u], wz.y, azB1);
                anB0 = dot2f(hb[u], wn.x, anB0); anB1 = dot2f(hb[u], wn.y, anB1);
            }
        }

        float rA0 = 1.f / (1.f + expf(-(girA.x + arA0 + bhr0)));
        float rA1 = 1.f / (1.f + expf(-(girA.y + arA1 + bhr1)));
        float zA0 = 1.f / (1.f + expf(-(gizA.x + azA0 + bhz0)));
        float zA1 = 1.f / (1.f + expf(-(gizA.y + azA1 + bhz1)));
        float nA0 = tanhf(ginA.x + rA0 * (anA0 + bhn0));
        float nA1 = tanhf(ginA.y + rA1 * (anA1 + bhn1));
        float hnA0 = (1.f - zA0) * nA0 + zA0 * hA0;
        float hnA1 = (1.f - zA1) * nA1 + zA1 * hA1;

        float rB0 = 1.f / (1.f + expf(-(girB.x + arB0 + bhr0)));
        float rB1 = 1.f / (1.f + expf(-(girB.y + arB1 + bhr1)));
        float zB0 = 1.f / (1.f + expf(-(gizB.x + azB0 + bhz0)));
        float zB1 = 1.f / (1.f + expf(-(gizB.y + azB1 + bhz1)));
        float nB0 = tanhf(ginB.x + rB0 * (anB0 + bhn0));
        float nB1 = tanhf(ginB.y + rB1 * (anB1 + bhn1));
        float hnB0 = (1.f - zB0) * nB0 + zB0 * hB0;
        float hnB1 = (1.f - zB1) * nB1 + zB1 * hB1;

        __syncthreads();   // all dot-readers done with h2s
        {
            half2v pa; pa[0] = (_Float16)hnA0; pa[1] = (_Float16)hnA1;
            half2v pb; pb[0] = (_Float16)hnB0; pb[1] = (_Float16)hnB1;
            h2s[tid]       = __builtin_bit_cast(uint32_t, pa);
            h2s[256 + tid] = __builtin_bit_cast(uint32_t, pb);
        }
        hA0 = hnA0; hA1 = hnA1; hB0 = hnB0; hB1 = hnB1;

        bool mA = smask[((bA << 6) + t) * 32 + aA] != 0;
        bool mB = smask[((bB << 6) + t) * 32 + aB] != 0;
        *(float2*)(hs_out + ((size_t)((bA << 6) + t) * 8 + aA) * 512 + c0) =
            make_float2(mA ? 0.f : hnA0, mA ? 0.f : hnA1);
        *(float2*)(hs_out + ((size_t)((bB << 6) + t) * 8 + aB) * 512 + c0) =
            make_float2(mB ? 0.f : hnB0, mB ? 0.f : hnB1);
        __syncthreads();   // h2s update visible before next step's dots
    }
}

// ---------- launch ----------
extern "C" void kernel_launch(void* const* d_in, const int* in_sizes, int n_in,
                              void* d_out, int out_size, void* d_ws, size_t ws_size,
                              hipStream_t stream)
{
    const float* inputs = (const float*)d_in[0];
    const int*   obs    = (const int*)d_in[1];
    const int*   smask  = (const int*)d_in[2];
    const float* h0     = (const float*)d_in[3];
    const float* W1  = (const float*)d_in[4];  const float* b1  = (const float*)d_in[5];
    const float* Wq  = (const float*)d_in[6];  const float* bq  = (const float*)d_in[7];
    const float* Wk  = (const float*)d_in[8];  const float* bk  = (const float*)d_in[9];
    const float* Wv  = (const float*)d_in[10]; const float* bv  = (const float*)d_in[11];
    const float* Wih = (const float*)d_in[12]; const float* bih = (const float*)d_in[13];
    const float* Whh = (const float*)d_in[14]; const float* bhh = (const float*)d_in[15];
    const float* Wo  = (const float*)d_in[16]; const float* bo  = (const float*)d_in[17];

    char* ws = (char*)d_ws;
    bf16*  x  = (bf16*)(ws + 0);
    float* xs = (float*)(ws + 0);
    bf16* qb = (bf16*)(ws + 67108864ull);
    bf16* kb = (bf16*)(ws + 83886080ull);
    bf16* vb = (bf16*)(ws + 150994944ull);
    float* gi = (float*)(ws + 67108864ull);
    uint32_t* w2 = (uint32_t*)(ws + 218103808ull);   // 1.5 MB

    float* out    = (float*)d_out;
    float* hs_out = out + 524288;

    // 0. pack Whh -> f16x2 transposed
    prep_whh_k<<<dim3(1536), 256, 0, stream>>>(Whh, w2);
    // 1. fc1
    gemm_k<1, false, false, false><<<dim3(8, 1024), 256, 0, stream>>>(
        inputs, W1, b1, x, 65536, 512, 128, nullptr);
    // 2. q (gathered agent rows)
    gemm_k<0, false, true, false><<<dim3(8, 256), 256, 0, stream>>>(
        x, Wq, bq, qb, 16384, 512, 512, nullptr);
    // 3. k
    gemm_k<0, false, false, false><<<dim3(8, 1024), 256, 0, stream>>>(
        x, Wk, bk, kb, 65536, 512, 512, nullptr);
    // 4. v
    gemm_k<1, false, false, false><<<dim3(8, 1024), 256, 0, stream>>>(
        x, Wv, bv, vb, 65536, 512, 512, nullptr);
    // 5. attention -> xs f32 (region A; x dead)
    attn_k<<<dim3(16384), 64, 0, stream>>>(qb, kb, vb, obs, smask, xs);
    // 6. gi = xs @ Wih^T + bih (region B; q/k/v dead)
    gemm_k<0, true, false, false><<<dim3(24, 256), 256, 0, stream>>>(
        xs, Wih, bih, gi, 16384, 1536, 512, nullptr);
    // 7. fused GRU: one launch, 64 steps, no grid sync (row-independent recurrence)
    gru_fused_k<<<dim3(128), 256, 0, stream>>>(gi, w2, bhh, h0, smask, hs_out);
    // 8. qout
    gemm_k<0, false, false, true><<<dim3(1, 256), 256, 0, stream>>>(
        hs_out, Wo, bo, out, 16384, 32, 512, smask);
}

// Round 5
// 1941.633 us; speedup vs baseline: 3.6468x; 1.9082x over previous
//
#include <hip/hip_runtime.h>
#include <hip/hip_bf16.h>
#include <cstddef>
#include <cstdint>

typedef __hip_bfloat16 bf16;
typedef __attribute__((ext_vector_type(2))) _Float16 half2v;
typedef __attribute__((ext_vector_type(8))) short short8;
typedef __attribute__((ext_vector_type(4))) float f32x4;

// ---------- helpers ----------
__device__ inline float ldf(const float* p) { return *p; }
__device__ inline float ldf(const bf16* p) { return __bfloat162float(*p); }
__device__ inline void stf(float* p, float v) { *p = v; }
__device__ inline void stf(bf16* p, float v) { *p = __float2bfloat16(v); }
__device__ inline short bfb(float v) { return __builtin_bit_cast(short, __float2bfloat16(v)); }

__device__ inline float dot2f(uint32_t a, uint32_t b, float c) {
#if __has_builtin(__builtin_amdgcn_fdot2)
    return __builtin_amdgcn_fdot2(__builtin_bit_cast(half2v, a),
                                  __builtin_bit_cast(half2v, b), c, false);
#else
    union { uint32_t u; _Float16 h[2]; } ua, ub;
    ua.u = a; ub.u = b;
    return c + (float)ua.h[0] * (float)ub.h[0] + (float)ua.h[1] * (float)ub.h[1];
#endif
}

// Problem constants: BS=32, T=64, NE=32, NA=8, ED=128, H=512, A=512, NH=8, HD=64, NACT=32

// ---------- MFMA bf16 GEMM: C[M,N] = act(A[M,K] @ Bt[N,K]^T + bias) ----------
// 128x128 tile, BK=32, 256 thr = 4 waves (2x2), wave owns 64x64 (4x4 frags 16x16).
// TA: float (convert-in-staging) or bf16. QG: q-row gather. ACT 1 = relu.
template<int ACT, bool QG, typename TA, typename TC>
__global__ __launch_bounds__(256) void mfma_gemm_k(
    const TA* __restrict__ A, const bf16* __restrict__ Bt,
    const float* __restrict__ bias, TC* __restrict__ C,
    int M, int N, int K)
{
    __shared__ short As[128][40];   // pad 32->40 (80B rows, 16B-aligned, banks spread)
    __shared__ short Bs[128][40];
    const int tid = threadIdx.x;
    const int lane = tid & 63, wid = tid >> 6;
    const int wm = wid >> 1, wn = wid & 1;
    const int bm = blockIdx.y * 128, bn = blockIdx.x * 128;
    const int fr = lane & 15, fq = lane >> 4;
    const int sr = tid >> 1, sk = (tid & 1) * 16;   // staging: row, k-offset

    f32x4 acc[4][4] = {};

    for (int k0 = 0; k0 < K; k0 += 32) {
        // stage A row (bm+sr), k0+sk..+15
        {
            int gm = bm + sr;
            int ar = QG ? (((gm >> 3) << 5) | (gm & 7)) : gm;
            if constexpr (sizeof(TA) == 4) {
                const float* ap = (const float*)A + (size_t)ar * K + k0 + sk;
                short tmp[16];
                #pragma unroll
                for (int j = 0; j < 16; ++j) tmp[j] = bfb(ap[j]);
                *(uint4*)&As[sr][sk]     = *(const uint4*)&tmp[0];
                *(uint4*)&As[sr][sk + 8] = *(const uint4*)&tmp[8];
            } else {
                const short* ap = (const short*)A + (size_t)ar * K + k0 + sk;
                *(uint4*)&As[sr][sk]     = *(const uint4*)(ap);
                *(uint4*)&As[sr][sk + 8] = *(const uint4*)(ap + 8);
            }
        }
        // stage B row (bn+sr), k0+sk..+15
        {
            const short* bp = (const short*)Bt + (size_t)(bn + sr) * K + k0 + sk;
            *(uint4*)&Bs[sr][sk]     = *(const uint4*)(bp);
            *(uint4*)&Bs[sr][sk + 8] = *(const uint4*)(bp + 8);
        }
        __syncthreads();

        short8 af[4], bg[4];
        #pragma unroll
        for (int m = 0; m < 4; ++m)
            af[m] = *(const short8*)&As[wm * 64 + m * 16 + fr][fq * 8];
        #pragma unroll
        for (int n = 0; n < 4; ++n)
            bg[n] = *(const short8*)&Bs[wn * 64 + n * 16 + fr][fq * 8];
        #pragma unroll
        for (int m = 0; m < 4; ++m)
            #pragma unroll
            for (int n = 0; n < 4; ++n)
                acc[m][n] = __builtin_amdgcn_mfma_f32_16x16x32_bf16(
                    af[m], bg[n], acc[m][n], 0, 0, 0);
        __syncthreads();
    }

    // epilogue: C/D layout col = lane&15, row = (lane>>4)*4 + reg
    #pragma unroll
    for (int m = 0; m < 4; ++m) {
        #pragma unroll
        for (int n = 0; n < 4; ++n) {
            int col = bn + wn * 64 + n * 16 + fr;
            float bv = bias[col];
            #pragma unroll
            for (int r = 0; r < 4; ++r) {
                int row = bm + wm * 64 + m * 16 + fq * 4 + r;
                float v = acc[m][n][r] + bv;
                if (ACT == 1) v = fmaxf(v, 0.f);
                stf(&C[(size_t)row * N + col], v);
            }
        }
    }
}

// ---------- weight prep ----------
// transpose-convert f32 [K][N] -> bf16 [N][K]
__global__ __launch_bounds__(256) void tconv_k(
    const float* __restrict__ in, bf16* __restrict__ out, int K, int N)
{
    int idx = blockIdx.x * 256 + threadIdx.x;
    if (idx >= K * N) return;
    int n = idx / K, k = idx - n * K;
    out[idx] = __float2bfloat16(in[(size_t)k * N + n]);
}
// plain convert f32 -> bf16
__global__ __launch_bounds__(256) void conv_k(
    const float* __restrict__ in, bf16* __restrict__ out, int n)
{
    int i = blockIdx.x * 256 + threadIdx.x;
    if (i < n) out[i] = __float2bfloat16(in[i]);
}

// ---------- legacy VALU GEMM (qout only: N=32) ----------
template<int ACT, bool BT, bool QG, bool MASKQ, typename TA, typename TB, typename TC>
__global__ __launch_bounds__(256) void gemm_k(
    const TA* __restrict__ A, const TB* __restrict__ B,
    const float* __restrict__ bias, TC* __restrict__ C,
    int M, int N, int K, const int* __restrict__ smask)
{
    const int BM = 64, BN = 64, BK = 16;
    __shared__ float Asl[BM][BK + 1];
    __shared__ float Bsl[BK][BN + 1];
    int tid = threadIdx.x;
    int n0 = blockIdx.x * BN;
    int m0 = blockIdx.y * BM;
    int ty = tid >> 4, tx = tid & 15;
    float acc[4][4] = {};

    for (int k0 = 0; k0 < K; k0 += BK) {
        #pragma unroll
        for (int i = 0; i < 4; ++i) {
            int l = tid * 4 + i;
            int r = l >> 4, c = l & 15;
            int gm = m0 + r;
            int ar = QG ? (((gm >> 3) << 5) | (gm & 7)) : gm;
            Asl[r][c] = ldf(&A[(size_t)ar * K + k0 + c]);
        }
        #pragma unroll
        for (int i = 0; i < 4; ++i) {
            int l = tid * 4 + i;
            if (BT) {
                int n = l >> 4, kk = l & 15;
                int gn = n0 + n;
                Bsl[kk][n] = (gn < N) ? ldf(&B[(size_t)gn * K + k0 + kk]) : 0.f;
            } else {
                int r = l >> 6, c = l & 63;
                int gn = n0 + c;
                Bsl[r][c] = (gn < N) ? ldf(&B[(size_t)(k0 + r) * N + gn]) : 0.f;
            }
        }
        __syncthreads();
        #pragma unroll
        for (int kk = 0; kk < BK; ++kk) {
            float a[4], b[4];
            #pragma unroll
            for (int i = 0; i < 4; ++i) a[i] = Asl[ty + i * 16][kk];
            #pragma unroll
            for (int j = 0; j < 4; ++j) b[j] = Bsl[kk][tx + j * 16];
            #pragma unroll
            for (int i = 0; i < 4; ++i)
                #pragma unroll
                for (int j = 0; j < 4; ++j) acc[i][j] += a[i] * b[j];
        }
        __syncthreads();
    }

    #pragma unroll
    for (int i = 0; i < 4; ++i) {
        int gm = m0 + ty + i * 16;
        bool mz = false;
        if (MASKQ) {
            int a_ = gm & 7, t_ = (gm >> 3) & 63, b_ = gm >> 9;
            mz = smask[((b_ << 6) + t_) * 32 + a_] != 0;
        }
        #pragma unroll
        for (int j = 0; j < 4; ++j) {
            int gn = n0 + tx + j * 16;
            if (gn < N) {
                float v = acc[i][j] + bias[gn];
                if (ACT == 1) v = fmaxf(v, 0.f);
                if (MASKQ && mz) v = 0.f;
                stf(&C[(size_t)gm * N + gn], v);
            }
        }
    }
}

// ---------- attention: one wave per (b,t,h) ----------
__global__ __launch_bounds__(64) void attn_k(
    const bf16* __restrict__ qb, const bf16* __restrict__ kb, const bf16* __restrict__ vb,
    const int* __restrict__ obs, const int* __restrict__ smask, bf16* __restrict__ xs)
{
    __shared__ float qs[8 * 64], ks[32 * 64], vs[32 * 64], wsm[8 * 32];
    int bid = blockIdx.x;
    int h = bid & 7;
    int bt = bid >> 3;
    int t = bt & 63, b = bt >> 6;
    int tid = threadIdx.x;

    #pragma unroll
    for (int i = 0; i < 8; ++i) {
        int l = tid + i * 64;
        int e = l >> 6, d = l & 63;
        qs[l] = __bfloat162float(qb[((size_t)bt * 8 + e) * 512 + h * 64 + d]);
    }
    #pragma unroll
    for (int i = 0; i < 32; ++i) {
        int l = tid + i * 64;
        int e = l >> 6, d = l & 63;
        ks[l] = __bfloat162float(kb[((size_t)bt * 32 + e) * 512 + h * 64 + d]);
        vs[l] = __bfloat162float(vb[((size_t)bt * 32 + e) * 512 + h * 64 + d]);
    }
    __syncthreads();

    int ql = tid >> 3, jl = tid & 7;
    float s[4];
    #pragma unroll
    for (int c = 0; c < 4; ++c) {
        int kl = jl + c * 8;
        float acc = 0.f;
        for (int d = 0; d < 64; ++d) acc += qs[ql * 64 + d] * ks[kl * 64 + d];
        acc *= 0.125f;
        bool m = obs[(((size_t)bt * 32) + ql) * 32 + kl] != 0;
        s[c] = m ? -__builtin_inff() : acc;
    }
    float mx = fmaxf(fmaxf(s[0], s[1]), fmaxf(s[2], s[3]));
    for (int off = 1; off < 8; off <<= 1) mx = fmaxf(mx, __shfl_xor(mx, off));
    float e4[4]; float sum = 0.f;
    bool allmasked = (mx == -__builtin_inff());
    #pragma unroll
    for (int c = 0; c < 4; ++c) {
        e4[c] = (allmasked || s[c] == -__builtin_inff()) ? 0.f : expf(s[c] - mx);
        sum += e4[c];
    }
    for (int off = 1; off < 8; off <<= 1) sum += __shfl_xor(sum, off);
    float inv = (sum > 0.f) ? 1.f / sum : 0.f;
    #pragma unroll
    for (int c = 0; c < 4; ++c) wsm[ql * 32 + jl + c * 8] = e4[c] * inv;
    __syncthreads();

    bool amask = smask[(size_t)bt * 32 + ql] != 0;
    #pragma unroll
    for (int dd = 0; dd < 8; ++dd) {
        int d = jl + dd * 8;
        float acc = 0.f;
        for (int kl = 0; kl < 32; ++kl) acc += wsm[ql * 32 + kl] * vs[kl * 64 + d];
        if (amask) acc = 0.f;
        xs[((size_t)(t * 256 + b * 8 + ql)) * 512 + h * 64 + d] = __float2bfloat16(acc);
    }
}

// ---------- Whh prep: [1536][512] f32 -> w2[kpair][1536] u32 (f16x2) ----------
__global__ __launch_bounds__(256) void prep_whh_k(
    const float* __restrict__ Whh, uint32_t* __restrict__ w2)
{
    int idx = blockIdx.x * 256 + threadIdx.x;
    int gc = idx >> 8;
    int k2 = idx & 255;
    float2 wv = *(const float2*)(Whh + (size_t)gc * 512 + 2 * k2);
    half2v h; h[0] = (_Float16)wv.x; h[1] = (_Float16)wv.y;
    w2[(size_t)k2 * 1536 + gc] = __builtin_bit_cast(uint32_t, h);
}

// ---------- fused GRU v2: 128 WGs x 1024 thr (16 waves/CU = 4/SIMD) ----------
// 2 rows/WG; K split in 4 disjoint slices across thread-quarters (no dup w-reads);
// LDS reduction of partial dots; no grid sync (row-independent recurrence).
__global__ __launch_bounds__(1024) void gru_fused2_k(
    const float* __restrict__ gi, const uint32_t* __restrict__ w2,
    const float* __restrict__ bhh, const float* __restrict__ h0,
    const int* __restrict__ smask, float* __restrict__ hs_out)
{
    __shared__ uint32_t h2s[2][256];       // f16x2 h (dots)
    __shared__ float hf[2][512];           // f32 h state
    __shared__ float part[4][2][512][3];   // [kslice][row][col][gate] 48 KB
    const int tid = threadIdx.x;
    const int ks = tid >> 8;               // K-slice 0..3 (64 kpairs each)
    const int cp = tid & 255;
    const int c0 = cp * 2;
    const int r0 = blockIdx.x * 2;
    const int kb = ks * 64;

    // gate-phase constants (tid < 512 only uses them)
    const int grr = tid >> 8;              // 0/1 when tid<512
    const int gcc = (tid & 255) * 2;
    float bhr0 = 0, bhr1 = 0, bhz0 = 0, bhz1 = 0, bhn0 = 0, bhn1 = 0;
    int gb_ = 0, ga_ = 0;
    if (tid < 512) {
        bhr0 = bhh[gcc];        bhr1 = bhh[gcc + 1];
        bhz0 = bhh[512 + gcc];  bhz1 = bhh[512 + gcc + 1];
        bhn0 = bhh[1024 + gcc]; bhn1 = bhh[1024 + gcc + 1];
        int row = r0 + grr;
        gb_ = row >> 3; ga_ = row & 7;
        float2 hv = *(const float2*)(h0 + (size_t)row * 512 + gcc);
        hf[grr][gcc] = hv.x; hf[grr][gcc + 1] = hv.y;
        half2v p; p[0] = (_Float16)hv.x; p[1] = (_Float16)hv.y;
        h2s[grr][tid & 255] = __builtin_bit_cast(uint32_t, p);
    }
    __syncthreads();

    for (int t = 0; t < 64; ++t) {
        // ---- dot phase: all 1024 threads, disjoint (kslice, colpair) w-reads ----
        float rA0 = 0, rA1 = 0, zA0 = 0, zA1 = 0, nA0 = 0, nA1 = 0;
        float rB0 = 0, rB1 = 0, zB0 = 0, zB1 = 0, nB0 = 0, nB1 = 0;
        #pragma unroll 4
        for (int kp = kb; kp < kb + 64; ++kp) {
            uint32_t ha = h2s[0][kp], hb = h2s[1][kp];
            const uint32_t* wp = w2 + (size_t)kp * 1536 + c0;
            uint2 wr = *(const uint2*)(wp);
            uint2 wz = *(const uint2*)(wp + 512);
            uint2 wn = *(const uint2*)(wp + 1024);
            rA0 = dot2f(ha, wr.x, rA0); rA1 = dot2f(ha, wr.y, rA1);
            zA0 = dot2f(ha, wz.x, zA0); zA1 = dot2f(ha, wz.y, zA1);
            nA0 = dot2f(ha, wn.x, nA0); nA1 = dot2f(ha, wn.y, nA1);
            rB0 = dot2f(hb, wr.x, rB0); rB1 = dot2f(hb, wr.y, rB1);
            zB0 = dot2f(hb, wz.x, zB0); zB1 = dot2f(hb, wz.y, zB1);
            nB0 = dot2f(hb, wn.x, nB0); nB1 = dot2f(hb, wn.y, nB1);
        }
        part[ks][0][c0][0] = rA0; part[ks][0][c0 + 1][0] = rA1;
        part[ks][0][c0][1] = zA0; part[ks][0][c0 + 1][1] = zA1;
        part[ks][0][c0][2] = nA0; part[ks][0][c0 + 1][2] = nA1;
        part[ks][1][c0][0] = rB0; part[ks][1][c0 + 1][0] = rB1;
        part[ks][1][c0][1] = zB0; part[ks][1][c0 + 1][1] = zB1;
        part[ks][1][c0][2] = nB0; part[ks][1][c0 + 1][2] = nB1;
        __syncthreads();

        // ---- gate phase: tid < 512 (2 rows x 256 colpairs) ----
        if (tid < 512) {
            float sr0 = 0, sz0 = 0, sn0 = 0, sr1 = 0, sz1 = 0, sn1 = 0;
            #pragma unroll
            for (int s = 0; s < 4; ++s) {
                sr0 += part[s][grr][gcc][0];     sz0 += part[s][grr][gcc][1];
                sn0 += part[s][grr][gcc][2];
                sr1 += part[s][grr][gcc + 1][0]; sz1 += part[s][grr][gcc + 1][1];
                sn1 += part[s][grr][gcc + 1][2];
            }
            size_t gbase = ((size_t)t * 256 + r0 + grr) * 1536;
            float2 gr = *(const float2*)(gi + gbase + gcc);
            float2 gz = *(const float2*)(gi + gbase + 512 + gcc);
            float2 gn = *(const float2*)(gi + gbase + 1024 + gcc);
            float hp0 = hf[grr][gcc], hp1 = hf[grr][gcc + 1];
            float r0g = 1.f / (1.f + expf(-(gr.x + sr0 + bhr0)));
            float r1g = 1.f / (1.f + expf(-(gr.y + sr1 + bhr1)));
            float z0g = 1.f / (1.f + expf(-(gz.x + sz0 + bhz0)));
            float z1g = 1.f / (1.f + expf(-(gz.y + sz1 + bhz1)));
            float n0g = tanhf(gn.x + r0g * (sn0 + bhn0));
            float n1g = tanhf(gn.y + r1g * (sn1 + bhn1));
            float hn0 = (1.f - z0g) * n0g + z0g * hp0;
            float hn1 = (1.f - z1g) * n1g + z1g * hp1;
            hf[grr][gcc] = hn0; hf[grr][gcc + 1] = hn1;
            half2v p; p[0] = (_Float16)hn0; p[1] = (_Float16)hn1;
            h2s[grr][tid & 255] = __builtin_bit_cast(uint32_t, p);
            bool m = smask[((gb_ << 6) + t) * 32 + ga_] != 0;
            *(float2*)(hs_out + ((size_t)((gb_ << 6) + t) * 8 + ga_) * 512 + gcc) =
                make_float2(m ? 0.f : hn0, m ? 0.f : hn1);
        }
        __syncthreads();
    }
}

// ---------- launch ----------
extern "C" void kernel_launch(void* const* d_in, const int* in_sizes, int n_in,
                              void* d_out, int out_size, void* d_ws, size_t ws_size,
                              hipStream_t stream)
{
    const float* inputs = (const float*)d_in[0];
    const int*   obs    = (const int*)d_in[1];
    const int*   smask  = (const int*)d_in[2];
    const float* h0     = (const float*)d_in[3];
    const float* W1  = (const float*)d_in[4];  const float* b1  = (const float*)d_in[5];
    const float* Wq  = (const float*)d_in[6];  const float* bq  = (const float*)d_in[7];
    const float* Wk  = (const float*)d_in[8];  const float* bk  = (const float*)d_in[9];
    const float* Wv  = (const float*)d_in[10]; const float* bv  = (const float*)d_in[11];
    const float* Wih = (const float*)d_in[12]; const float* bih = (const float*)d_in[13];
    const float* Whh = (const float*)d_in[14]; const float* bhh = (const float*)d_in[15];
    const float* Wo  = (const float*)d_in[16]; const float* bo  = (const float*)d_in[17];

    char* ws = (char*)d_ws;
    // lifetimes: x [0,64M) fc1->v;  xs bf16 [0,16M) attn->gi;
    // qb [64,80M); kb [80,144M); vb [144,208M);
    // gi f32 [16,112M) gi-GEMM->GRU;  w2 [112,113.5M); Wihb [113.5,115M);
    // W1t/Wqt/Wkt/Wvt at [208,209.625M).  Peak < 210 MiB (proven ws floor).
    bf16*  x    = (bf16*)(ws + 0);
    bf16*  xs   = (bf16*)(ws + 0);
    bf16*  qb   = (bf16*)(ws + 67108864ull);
    bf16*  kb   = (bf16*)(ws + 83886080ull);
    bf16*  vb   = (bf16*)(ws + 150994944ull);
    float* gi   = (float*)(ws + 16777216ull);
    uint32_t* w2   = (uint32_t*)(ws + 117440512ull);
    bf16*  Wihb = (bf16*)(ws + 119013376ull);
    bf16*  W1t  = (bf16*)(ws + 218103808ull);
    bf16*  Wqt  = (bf16*)(ws + 218234880ull);
    bf16*  Wkt  = (bf16*)(ws + 218759168ull);
    bf16*  Wvt  = (bf16*)(ws + 219283456ull);

    float* out    = (float*)d_out;
    float* hs_out = out + 524288;

    // 0. weight prep (transpose f32 [K][N] -> bf16 [N][K])
    tconv_k<<<dim3(256), 256, 0, stream>>>(W1, W1t, 128, 512);
    tconv_k<<<dim3(1024), 256, 0, stream>>>(Wq, Wqt, 512, 512);
    tconv_k<<<dim3(1024), 256, 0, stream>>>(Wk, Wkt, 512, 512);
    tconv_k<<<dim3(1024), 256, 0, stream>>>(Wv, Wvt, 512, 512);
    // 1. fc1 (A = f32 inputs, converted in staging)
    mfma_gemm_k<1, false, float, bf16><<<dim3(4, 512), 256, 0, stream>>>(
        inputs, W1t, b1, x, 65536, 512, 128);
    // 2-4. projections
    mfma_gemm_k<0, true, bf16, bf16><<<dim3(4, 128), 256, 0, stream>>>(
        x, Wqt, bq, qb, 16384, 512, 512);
    mfma_gemm_k<0, false, bf16, bf16><<<dim3(4, 512), 256, 0, stream>>>(
        x, Wkt, bk, kb, 65536, 512, 512);
    mfma_gemm_k<1, false, bf16, bf16><<<dim3(4, 512), 256, 0, stream>>>(
        x, Wvt, bv, vb, 65536, 512, 512);
    // 5. attention -> xs bf16 (x dead)
    attn_k<<<dim3(16384), 64, 0, stream>>>(qb, kb, vb, obs, smask, xs);
    // 5b. GRU weight prep (into regions dead after attn)
    conv_k<<<dim3(3072), 256, 0, stream>>>(Wih, Wihb, 1536 * 512);
    prep_whh_k<<<dim3(1536), 256, 0, stream>>>(Whh, w2);
    // 6. gi = xs @ Wih^T + bih -> f32
    mfma_gemm_k<0, false, bf16, float><<<dim3(12, 128), 256, 0, stream>>>(
        xs, Wihb, bih, gi, 16384, 1536, 512);
    // 7. fused GRU v2
    gru_fused2_k<<<dim3(128), 1024, 0, stream>>>(gi, w2, bhh, h0, smask, hs_out);
    // 8. qout
    gemm_k<0, false, false, true><<<dim3(1, 256), 256, 0, stream>>>(
        hs_out, Wo, bo, out, 16384, 32, 512, smask);
}

// Round 6
// 1715.222 us; speedup vs baseline: 4.1282x; 1.1320x over previous
//
#include <hip/hip_runtime.h>
#include <hip/hip_bf16.h>
#include <cstddef>
#include <cstdint>

typedef __hip_bfloat16 bf16;
typedef __attribute__((ext_vector_type(2))) _Float16 half2v;
typedef __attribute__((ext_vector_type(8))) _Float16 half8;
typedef __attribute__((ext_vector_type(8))) short short8;
typedef __attribute__((ext_vector_type(4))) float f32x4;

// ---------- helpers ----------
__device__ inline float ldf(const float* p) { return *p; }
__device__ inline float ldf(const bf16* p) { return __bfloat162float(*p); }
__device__ inline void stf(float* p, float v) { *p = v; }
__device__ inline void stf(bf16* p, float v) { *p = __float2bfloat16(v); }
__device__ inline short bfb(float v) { return __builtin_bit_cast(short, __float2bfloat16(v)); }

// Problem constants: BS=32, T=64, NE=32, NA=8, ED=128, H=512, A=512, NH=8, HD=64, NACT=32

// ---------- MFMA bf16 GEMM: C[M,N] = act(A[M,K] @ Bt[N,K]^T + bias) ----------
// 128x128 tile, BK=32, 256 thr = 4 waves (2x2), wave owns 64x64.
// GI2: store transposed f32 to gi2[(gm>>8)*1536 + col][256 rows] (float4 over rows).
template<int ACT, bool QG, bool GI2, typename TA, typename TC>
__global__ __launch_bounds__(256) void mfma_gemm_k(
    const TA* __restrict__ A, const bf16* __restrict__ Bt,
    const float* __restrict__ bias, TC* __restrict__ C,
    int M, int N, int K)
{
    __shared__ short As[128][40];
    __shared__ short Bs[128][40];
    const int tid = threadIdx.x;
    const int lane = tid & 63, wid = tid >> 6;
    const int wm = wid >> 1, wn = wid & 1;
    const int bm = blockIdx.y * 128, bn = blockIdx.x * 128;
    const int fr = lane & 15, fq = lane >> 4;
    const int sr = tid >> 1, sk = (tid & 1) * 16;

    f32x4 acc[4][4] = {};

    for (int k0 = 0; k0 < K; k0 += 32) {
        {
            int gm = bm + sr;
            int ar = QG ? (((gm >> 3) << 5) | (gm & 7)) : gm;
            if constexpr (sizeof(TA) == 4) {
                const float* ap = (const float*)A + (size_t)ar * K + k0 + sk;
                short tmp[16];
                #pragma unroll
                for (int j = 0; j < 16; ++j) tmp[j] = bfb(ap[j]);
                *(uint4*)&As[sr][sk]     = *(const uint4*)&tmp[0];
                *(uint4*)&As[sr][sk + 8] = *(const uint4*)&tmp[8];
            } else {
                const short* ap = (const short*)A + (size_t)ar * K + k0 + sk;
                *(uint4*)&As[sr][sk]     = *(const uint4*)(ap);
                *(uint4*)&As[sr][sk + 8] = *(const uint4*)(ap + 8);
            }
        }
        {
            const short* bp = (const short*)Bt + (size_t)(bn + sr) * K + k0 + sk;
            *(uint4*)&Bs[sr][sk]     = *(const uint4*)(bp);
            *(uint4*)&Bs[sr][sk + 8] = *(const uint4*)(bp + 8);
        }
        __syncthreads();

        short8 af[4], bg[4];
        #pragma unroll
        for (int m = 0; m < 4; ++m)
            af[m] = *(const short8*)&As[wm * 64 + m * 16 + fr][fq * 8];
        #pragma unroll
        for (int n = 0; n < 4; ++n)
            bg[n] = *(const short8*)&Bs[wn * 64 + n * 16 + fr][fq * 8];
        #pragma unroll
        for (int m = 0; m < 4; ++m)
            #pragma unroll
            for (int n = 0; n < 4; ++n)
                acc[m][n] = __builtin_amdgcn_mfma_f32_16x16x32_bf16(
                    af[m], bg[n], acc[m][n], 0, 0, 0);
        __syncthreads();
    }

    #pragma unroll
    for (int m = 0; m < 4; ++m) {
        #pragma unroll
        for (int n = 0; n < 4; ++n) {
            int col = bn + wn * 64 + n * 16 + fr;
            float bv = bias[col];
            if constexpr (GI2) {
                int gm0 = bm + wm * 64 + m * 16 + fq * 4;   // reg-0 row; rows gm0..gm0+3
                float4 v = make_float4(acc[m][n][0] + bv, acc[m][n][1] + bv,
                                       acc[m][n][2] + bv, acc[m][n][3] + bv);
                *(float4*)((float*)C + ((size_t)(gm0 >> 8) * 1536 + col) * 256 + (gm0 & 255)) = v;
            } else {
                #pragma unroll
                for (int r = 0; r < 4; ++r) {
                    int row = bm + wm * 64 + m * 16 + fq * 4 + r;
                    float v = acc[m][n][r] + bv;
                    if (ACT == 1) v = fmaxf(v, 0.f);
                    stf(&C[(size_t)row * N + col], v);
                }
            }
        }
    }
}

// ---------- weight prep ----------
__global__ __launch_bounds__(256) void tconv_k(
    const float* __restrict__ in, bf16* __restrict__ out, int K, int N)
{
    int idx = blockIdx.x * 256 + threadIdx.x;
    if (idx >= K * N) return;
    int n = idx / K, k = idx - n * K;
    out[idx] = __float2bfloat16(in[(size_t)k * N + n]);
}
__global__ __launch_bounds__(256) void conv_k(
    const float* __restrict__ in, bf16* __restrict__ out, int n)
{
    int i = blockIdx.x * 256 + threadIdx.x;
    if (i < n) out[i] = __float2bfloat16(in[i]);
}
__global__ __launch_bounds__(256) void conv_f16_k(
    const float* __restrict__ in, _Float16* __restrict__ out, int n)
{
    int i = blockIdx.x * 256 + threadIdx.x;
    if (i < n) out[i] = (_Float16)in[i];
}

// ---------- legacy VALU GEMM (qout only: N=32) ----------
template<int ACT, bool BT, bool QG, bool MASKQ, typename TA, typename TB, typename TC>
__global__ __launch_bounds__(256) void gemm_k(
    const TA* __restrict__ A, const TB* __restrict__ B,
    const float* __restrict__ bias, TC* __restrict__ C,
    int M, int N, int K, const int* __restrict__ smask)
{
    const int BM = 64, BN = 64, BK = 16;
    __shared__ float Asl[BM][BK + 1];
    __shared__ float Bsl[BK][BN + 1];
    int tid = threadIdx.x;
    int n0 = blockIdx.x * BN;
    int m0 = blockIdx.y * BM;
    int ty = tid >> 4, tx = tid & 15;
    float acc[4][4] = {};

    for (int k0 = 0; k0 < K; k0 += BK) {
        #pragma unroll
        for (int i = 0; i < 4; ++i) {
            int l = tid * 4 + i;
            int r = l >> 4, c = l & 15;
            int gm = m0 + r;
            int ar = QG ? (((gm >> 3) << 5) | (gm & 7)) : gm;
            Asl[r][c] = ldf(&A[(size_t)ar * K + k0 + c]);
        }
        #pragma unroll
        for (int i = 0; i < 4; ++i) {
            int l = tid * 4 + i;
            if (BT) {
                int n = l >> 4, kk = l & 15;
                int gn = n0 + n;
                Bsl[kk][n] = (gn < N) ? ldf(&B[(size_t)gn * K + k0 + kk]) : 0.f;
            } else {
                int r = l >> 6, c = l & 63;
                int gn = n0 + c;
                Bsl[r][c] = (gn < N) ? ldf(&B[(size_t)(k0 + r) * N + gn]) : 0.f;
            }
        }
        __syncthreads();
        #pragma unroll
        for (int kk = 0; kk < BK; ++kk) {
            float a[4], b[4];
            #pragma unroll
            for (int i = 0; i < 4; ++i) a[i] = Asl[ty + i * 16][kk];
            #pragma unroll
            for (int j = 0; j < 4; ++j) b[j] = Bsl[kk][tx + j * 16];
            #pragma unroll
            for (int i = 0; i < 4; ++i)
                #pragma unroll
                for (int j = 0; j < 4; ++j) acc[i][j] += a[i] * b[j];
        }
        __syncthreads();
    }

    #pragma unroll
    for (int i = 0; i < 4; ++i) {
        int gm = m0 + ty + i * 16;
        bool mz = false;
        if (MASKQ) {
            int a_ = gm & 7, t_ = (gm >> 3) & 63, b_ = gm >> 9;
            mz = smask[((b_ << 6) + t_) * 32 + a_] != 0;
        }
        #pragma unroll
        for (int j = 0; j < 4; ++j) {
            int gn = n0 + tx + j * 16;
            if (gn < N) {
                float v = acc[i][j] + bias[gn];
                if (ACT == 1) v = fmaxf(v, 0.f);
                if (MASKQ && mz) v = 0.f;
                stf(&C[(size_t)gm * N + gn], v);
            }
        }
    }
}

// ---------- attention: one wave per (b,t,h) ----------
__global__ __launch_bounds__(64) void attn_k(
    const bf16* __restrict__ qb, const bf16* __restrict__ kb, const bf16* __restrict__ vb,
    const int* __restrict__ obs, const int* __restrict__ smask, bf16* __restrict__ xs)
{
    __shared__ float qs[8 * 64], ks[32 * 64], vs[32 * 64], wsm[8 * 32];
    int bid = blockIdx.x;
    int h = bid & 7;
    int bt = bid >> 3;
    int t = bt & 63, b = bt >> 6;
    int tid = threadIdx.x;

    #pragma unroll
    for (int i = 0; i < 8; ++i) {
        int l = tid + i * 64;
        int e = l >> 6, d = l & 63;
        qs[l] = __bfloat162float(qb[((size_t)bt * 8 + e) * 512 + h * 64 + d]);
    }
    #pragma unroll
    for (int i = 0; i < 32; ++i) {
        int l = tid + i * 64;
        int e = l >> 6, d = l & 63;
        ks[l] = __bfloat162float(kb[((size_t)bt * 32 + e) * 512 + h * 64 + d]);
        vs[l] = __bfloat162float(vb[((size_t)bt * 32 + e) * 512 + h * 64 + d]);
    }
    __syncthreads();

    int ql = tid >> 3, jl = tid & 7;
    float s[4];
    #pragma unroll
    for (int c = 0; c < 4; ++c) {
        int kl = jl + c * 8;
        float acc = 0.f;
        for (int d = 0; d < 64; ++d) acc += qs[ql * 64 + d] * ks[kl * 64 + d];
        acc *= 0.125f;
        bool m = obs[(((size_t)bt * 32) + ql) * 32 + kl] != 0;
        s[c] = m ? -__builtin_inff() : acc;
    }
    float mx = fmaxf(fmaxf(s[0], s[1]), fmaxf(s[2], s[3]));
    for (int off = 1; off < 8; off <<= 1) mx = fmaxf(mx, __shfl_xor(mx, off));
    float e4[4]; float sum = 0.f;
    bool allmasked = (mx == -__builtin_inff());
    #pragma unroll
    for (int c = 0; c < 4; ++c) {
        e4[c] = (allmasked || s[c] == -__builtin_inff()) ? 0.f : expf(s[c] - mx);
        sum += e4[c];
    }
    for (int off = 1; off < 8; off <<= 1) sum += __shfl_xor(sum, off);
    float inv = (sum > 0.f) ? 1.f / sum : 0.f;
    #pragma unroll
    for (int c = 0; c < 4; ++c) wsm[ql * 32 + jl + c * 8] = e4[c] * inv;
    __syncthreads();

    bool amask = smask[(size_t)bt * 32 + ql] != 0;
    #pragma unroll
    for (int dd = 0; dd < 8; ++dd) {
        int d = jl + dd * 8;
        float acc = 0.f;
        for (int kl = 0; kl < 32; ++kl) acc += wsm[ql * 32 + kl] * vs[kl * 64 + d];
        if (amask) acc = 0.f;
        xs[((size_t)(t * 256 + b * 8 + ql)) * 512 + h * 64 + d] = __float2bfloat16(acc);
    }
}

// ---------- GRU v3: w pinned in LDS, h exchanged via L2, MFMA f16 ----------
// 64 WGs x 256 thr. WG g: rows [mh*128, +128), h-cols [cs*16, +16), mh=g>>5, cs=g&31.
// LDS holds the WG's 48x512 f16 w-slice (rows: r|z|n gates x 16 cols) for all 64 steps.
// Per step: gh = h @ w^T via MFMA; gates fuse lane-locally (C-layout); h_prev in regs;
// gi2 is the transposed [t][gatecol][row] f32 layout (float4 loads).
// Cross-WG h via double-buffered f16 slabs + fence/atomic barrier (round-3-proven).
__global__ __launch_bounds__(256) void gru_mfma_k(
    const float* __restrict__ gi2, const float* __restrict__ Whh,
    const float* __restrict__ bhh, const float* __restrict__ h0,
    const int* __restrict__ smask, float* __restrict__ hs_out,
    _Float16* __restrict__ ha, _Float16* __restrict__ hb, int* __restrict__ bar)
{
    __shared__ _Float16 ws16[48 * 520];   // stride 520: 2-way banks (free), 16B-aligned rows
    const int tid = threadIdx.x;
    const int g = blockIdx.x;
    const int mh = g >> 5, cs = g & 31;
    const int hc0 = cs * 16;
    const int lane = tid & 63, w = tid >> 6;
    const int fr = lane & 15, fq = lane >> 4;
    const int rbase = mh * 128 + w * 32;
    const int hcol = hc0 + fr;

    // stage w slice: LDS row j (0..47) = Whh[(j>>4)*512 + hc0 + (j&15)][0..512)
    for (int i = tid; i < 12288; i += 256) {   // float2 units
        int flat = i * 2;
        int r = flat >> 9, c = flat & 511;
        int wr = (r >> 4) * 512 + hc0 + (r & 15);
        float2 v = *(const float2*)(Whh + (size_t)wr * 512 + c);
        half2v p; p[0] = (_Float16)v.x; p[1] = (_Float16)v.y;
        *(uint32_t*)&ws16[r * 520 + c] = __builtin_bit_cast(uint32_t, p);
    }

    const float bhr = bhh[hcol], bhz = bhh[512 + hcol], bhn = bhh[1024 + hcol];

    // h_prev in regs, C-layout rows: rbase + mt*16 + fq*4 + r
    float hp[2][4];
    #pragma unroll
    for (int mt = 0; mt < 2; ++mt)
        #pragma unroll
        for (int r = 0; r < 4; ++r)
            hp[mt][r] = h0[(size_t)(rbase + mt * 16 + fq * 4 + r) * 512 + hcol];

    __syncthreads();

    for (int t = 0; t < 64; ++t) {
        const _Float16* hsrc = (t & 1) ? hb : ha;   // t=0 reads ha (prep); src(t)=dst(t-1)
        _Float16*       hdst = (t & 1) ? ha : hb;

        f32x4 acc[2][3] = {};
        const _Float16* aptr0 = hsrc + (size_t)(rbase + fr) * 512 + fq * 8;
        const _Float16* aptr1 = aptr0 + (size_t)16 * 512;
        half8 acur0 = *(const half8*)aptr0;
        half8 acur1 = *(const half8*)aptr1;
        #pragma unroll
        for (int ks = 0; ks < 16; ++ks) {
            half8 anx0 = acur0, anx1 = acur1;
            if (ks < 15) {
                anx0 = *(const half8*)(aptr0 + (ks + 1) * 32);
                anx1 = *(const half8*)(aptr1 + (ks + 1) * 32);
            }
            const _Float16* bbase = &ws16[fr * 520 + ks * 32 + fq * 8];
            half8 b0 = *(const half8*)(bbase);
            half8 b1 = *(const half8*)(bbase + 16 * 520);
            half8 b2 = *(const half8*)(bbase + 32 * 520);
            acc[0][0] = __builtin_amdgcn_mfma_f32_16x16x32_f16(acur0, b0, acc[0][0], 0, 0, 0);
            acc[0][1] = __builtin_amdgcn_mfma_f32_16x16x32_f16(acur0, b1, acc[0][1], 0, 0, 0);
            acc[0][2] = __builtin_amdgcn_mfma_f32_16x16x32_f16(acur0, b2, acc[0][2], 0, 0, 0);
            acc[1][0] = __builtin_amdgcn_mfma_f32_16x16x32_f16(acur1, b0, acc[1][0], 0, 0, 0);
            acc[1][1] = __builtin_amdgcn_mfma_f32_16x16x32_f16(acur1, b1, acc[1][1], 0, 0, 0);
            acc[1][2] = __builtin_amdgcn_mfma_f32_16x16x32_f16(acur1, b2, acc[1][2], 0, 0, 0);
            acur0 = anx0; acur1 = anx1;
        }

        // gate fusion + stores (C-layout: col = hcol, rows = grow0..+3)
        #pragma unroll
        for (int mt = 0; mt < 2; ++mt) {
            int grow0 = rbase + mt * 16 + fq * 4;
            float4 gr = *(const float4*)(gi2 + ((size_t)t * 1536 + hcol)        * 256 + grow0);
            float4 gz = *(const float4*)(gi2 + ((size_t)t * 1536 + 512 + hcol)  * 256 + grow0);
            float4 gn = *(const float4*)(gi2 + ((size_t)t * 1536 + 1024 + hcol) * 256 + grow0);
            float grA[4] = {gr.x, gr.y, gr.z, gr.w};
            float gzA[4] = {gz.x, gz.y, gz.z, gz.w};
            float gnA[4] = {gn.x, gn.y, gn.z, gn.w};
            #pragma unroll
            for (int r = 0; r < 4; ++r) {
                int row = grow0 + r;
                float rg = 1.f / (1.f + expf(-(grA[r] + acc[mt][0][r] + bhr)));
                float zg = 1.f / (1.f + expf(-(gzA[r] + acc[mt][1][r] + bhz)));
                float ng = tanhf(gnA[r] + rg * (acc[mt][2][r] + bhn));
                float hn = (1.f - zg) * ng + zg * hp[mt][r];
                hp[mt][r] = hn;
                hdst[(size_t)row * 512 + hcol] = (_Float16)hn;
                int b_ = row >> 3, a_ = row & 7;
                bool msk = smask[((b_ << 6) + t) * 32 + a_] != 0;
                hs_out[((size_t)((b_ << 6) + t) * 8 + a_) * 512 + hcol] = msk ? 0.f : hn;
            }
        }

        if (t != 63) {
            __threadfence();
            __syncthreads();
            if (tid == 0) {
                atomicAdd(bar + t, 1);
                long it = 0;
                while (__hip_atomic_load(bar + t, __ATOMIC_RELAXED,
                                         __HIP_MEMORY_SCOPE_AGENT) < 64 &&
                       it < 100000000L) {
                    __builtin_amdgcn_s_sleep(2);
                    ++it;
                }
            }
            __syncthreads();
            __threadfence();
        }
    }
}

// ---------- launch ----------
extern "C" void kernel_launch(void* const* d_in, const int* in_sizes, int n_in,
                              void* d_out, int out_size, void* d_ws, size_t ws_size,
                              hipStream_t stream)
{
    const float* inputs = (const float*)d_in[0];
    const int*   obs    = (const int*)d_in[1];
    const int*   smask  = (const int*)d_in[2];
    const float* h0     = (const float*)d_in[3];
    const float* W1  = (const float*)d_in[4];  const float* b1  = (const float*)d_in[5];
    const float* Wq  = (const float*)d_in[6];  const float* bq  = (const float*)d_in[7];
    const float* Wk  = (const float*)d_in[8];  const float* bk  = (const float*)d_in[9];
    const float* Wv  = (const float*)d_in[10]; const float* bv  = (const float*)d_in[11];
    const float* Wih = (const float*)d_in[12]; const float* bih = (const float*)d_in[13];
    const float* Whh = (const float*)d_in[14]; const float* bhh = (const float*)d_in[15];
    const float* Wo  = (const float*)d_in[16]; const float* bo  = (const float*)d_in[17];

    char* ws = (char*)d_ws;
    // lifetimes: x/xs [0,64M)/[0,16M); gi2 [16,112M) (overwrites dead qb/kb after attn);
    // qb [64,80M); kb [80,144M); vb [144,208M); Wihb [113.5,115M);
    // W1t..Wvt [208,209.7M); ha/hb/bar [209.7,210.3M).
    bf16*  x    = (bf16*)(ws + 0);
    bf16*  xs   = (bf16*)(ws + 0);
    bf16*  qb   = (bf16*)(ws + 67108864ull);
    bf16*  kb   = (bf16*)(ws + 83886080ull);
    bf16*  vb   = (bf16*)(ws + 150994944ull);
    float* gi2  = (float*)(ws + 16777216ull);
    bf16*  Wihb = (bf16*)(ws + 119013376ull);
    bf16*  W1t  = (bf16*)(ws + 218103808ull);
    bf16*  Wqt  = (bf16*)(ws + 218234880ull);
    bf16*  Wkt  = (bf16*)(ws + 218759168ull);
    bf16*  Wvt  = (bf16*)(ws + 219283456ull);
    _Float16* ha = (_Float16*)(ws + 219807744ull);   // 256 KB
    _Float16* hb = (_Float16*)(ws + 220069888ull);   // 256 KB
    int*   bar  = (int*)(ws + 220332032ull);         // 64 ints

    float* out    = (float*)d_out;
    float* hs_out = out + 524288;

    hipMemsetAsync(bar, 0, 256, stream);

    // 0. weight prep
    tconv_k<<<dim3(256), 256, 0, stream>>>(W1, W1t, 128, 512);
    tconv_k<<<dim3(1024), 256, 0, stream>>>(Wq, Wqt, 512, 512);
    tconv_k<<<dim3(1024), 256, 0, stream>>>(Wk, Wkt, 512, 512);
    tconv_k<<<dim3(1024), 256, 0, stream>>>(Wv, Wvt, 512, 512);
    conv_f16_k<<<dim3(512), 256, 0, stream>>>(h0, ha, 131072);
    // 1. fc1
    mfma_gemm_k<1, false, false, float, bf16><<<dim3(4, 512), 256, 0, stream>>>(
        inputs, W1t, b1, x, 65536, 512, 128);
    // 2-4. projections
    mfma_gemm_k<0, true, false, bf16, bf16><<<dim3(4, 128), 256, 0, stream>>>(
        x, Wqt, bq, qb, 16384, 512, 512);
    mfma_gemm_k<0, false, false, bf16, bf16><<<dim3(4, 512), 256, 0, stream>>>(
        x, Wkt, bk, kb, 65536, 512, 512);
    mfma_gemm_k<1, false, false, bf16, bf16><<<dim3(4, 512), 256, 0, stream>>>(
        x, Wvt, bv, vb, 65536, 512, 512);
    // 5. attention -> xs bf16 (x dead)
    attn_k<<<dim3(16384), 64, 0, stream>>>(qb, kb, vb, obs, smask, xs);
    // 5b. Wih -> bf16
    conv_k<<<dim3(3072), 256, 0, stream>>>(Wih, Wihb, 1536 * 512);
    // 6. gi2 = (xs @ Wih^T + bih), stored transposed [t][gatecol][row]
    mfma_gemm_k<0, false, true, bf16, float><<<dim3(12, 128), 256, 0, stream>>>(
        xs, Wihb, bih, gi2, 16384, 1536, 512);
    // 7. GRU v3: w-in-LDS persistent, 64 WGs, device barrier per step
    gru_mfma_k<<<dim3(64), 256, 0, stream>>>(
        gi2, Whh, bhh, h0, smask, hs_out, ha, hb, bar);
    // 8. qout
    gemm_k<0, false, false, true><<<dim3(1, 256), 256, 0, stream>>>(
        hs_out, Wo, bo, out, 16384, 32, 512, smask);
}

// Round 7
// 1473.409 us; speedup vs baseline: 4.8057x; 1.1641x over previous
//
#include <hip/hip_runtime.h>
#include <hip/hip_bf16.h>
#include <cstddef>
#include <cstdint>

typedef __hip_bfloat16 bf16;
typedef __attribute__((ext_vector_type(2))) _Float16 half2v;
typedef __attribute__((ext_vector_type(8))) _Float16 half8;
typedef __attribute__((ext_vector_type(8))) short short8;
typedef __attribute__((ext_vector_type(4))) float f32x4;

// ---------- helpers ----------
__device__ inline float ldf(const float* p) { return *p; }
__device__ inline float ldf(const bf16* p) { return __bfloat162float(*p); }
__device__ inline void stf(float* p, float v) { *p = v; }
__device__ inline void stf(bf16* p, float v) { *p = __float2bfloat16(v); }
__device__ inline short bfb(float v) { return __builtin_bit_cast(short, __float2bfloat16(v)); }

// Problem constants: BS=32, T=64, NE=32, NA=8, ED=128, H=512, A=512, NH=8, HD=64, NACT=32

// ---------- MFMA bf16 GEMM: C[M,N] = act(A[M,K] @ Bt[N,K]^T + bias) ----------
template<int ACT, bool QG, bool GI2, typename TA, typename TC>
__global__ __launch_bounds__(256) void mfma_gemm_k(
    const TA* __restrict__ A, const bf16* __restrict__ Bt,
    const float* __restrict__ bias, TC* __restrict__ C,
    int M, int N, int K)
{
    __shared__ short As[128][40];
    __shared__ short Bs[128][40];
    const int tid = threadIdx.x;
    const int lane = tid & 63, wid = tid >> 6;
    const int wm = wid >> 1, wn = wid & 1;
    const int bm = blockIdx.y * 128, bn = blockIdx.x * 128;
    const int fr = lane & 15, fq = lane >> 4;
    const int sr = tid >> 1, sk = (tid & 1) * 16;

    f32x4 acc[4][4] = {};

    for (int k0 = 0; k0 < K; k0 += 32) {
        {
            int gm = bm + sr;
            int ar = QG ? (((gm >> 3) << 5) | (gm & 7)) : gm;
            if constexpr (sizeof(TA) == 4) {
                const float* ap = (const float*)A + (size_t)ar * K + k0 + sk;
                short tmp[16];
                #pragma unroll
                for (int j = 0; j < 16; ++j) tmp[j] = bfb(ap[j]);
                *(uint4*)&As[sr][sk]     = *(const uint4*)&tmp[0];
                *(uint4*)&As[sr][sk + 8] = *(const uint4*)&tmp[8];
            } else {
                const short* ap = (const short*)A + (size_t)ar * K + k0 + sk;
                *(uint4*)&As[sr][sk]     = *(const uint4*)(ap);
                *(uint4*)&As[sr][sk + 8] = *(const uint4*)(ap + 8);
            }
        }
        {
            const short* bp = (const short*)Bt + (size_t)(bn + sr) * K + k0 + sk;
            *(uint4*)&Bs[sr][sk]     = *(const uint4*)(bp);
            *(uint4*)&Bs[sr][sk + 8] = *(const uint4*)(bp + 8);
        }
        __syncthreads();

        short8 af[4], bg[4];
        #pragma unroll
        for (int m = 0; m < 4; ++m)
            af[m] = *(const short8*)&As[wm * 64 + m * 16 + fr][fq * 8];
        #pragma unroll
        for (int n = 0; n < 4; ++n)
            bg[n] = *(const short8*)&Bs[wn * 64 + n * 16 + fr][fq * 8];
        #pragma unroll
        for (int m = 0; m < 4; ++m)
            #pragma unroll
            for (int n = 0; n < 4; ++n)
                acc[m][n] = __builtin_amdgcn_mfma_f32_16x16x32_bf16(
                    af[m], bg[n], acc[m][n], 0, 0, 0);
        __syncthreads();
    }

    #pragma unroll
    for (int m = 0; m < 4; ++m) {
        #pragma unroll
        for (int n = 0; n < 4; ++n) {
            int col = bn + wn * 64 + n * 16 + fr;
            float bv = bias[col];
            if constexpr (GI2) {
                int gm0 = bm + wm * 64 + m * 16 + fq * 4;
                float4 v = make_float4(acc[m][n][0] + bv, acc[m][n][1] + bv,
                                       acc[m][n][2] + bv, acc[m][n][3] + bv);
                *(float4*)((float*)C + ((size_t)(gm0 >> 8) * 1536 + col) * 256 + (gm0 & 255)) = v;
            } else {
                #pragma unroll
                for (int r = 0; r < 4; ++r) {
                    int row = bm + wm * 64 + m * 16 + fq * 4 + r;
                    float v = acc[m][n][r] + bv;
                    if (ACT == 1) v = fmaxf(v, 0.f);
                    stf(&C[(size_t)row * N + col], v);
                }
            }
        }
    }
}

// ---------- weight prep ----------
__global__ __launch_bounds__(256) void tconv_k(
    const float* __restrict__ in, bf16* __restrict__ out, int K, int N)
{
    int idx = blockIdx.x * 256 + threadIdx.x;
    if (idx >= K * N) return;
    int n = idx / K, k = idx - n * K;
    out[idx] = __float2bfloat16(in[(size_t)k * N + n]);
}
__global__ __launch_bounds__(256) void conv_k(
    const float* __restrict__ in, bf16* __restrict__ out, int n)
{
    int i = blockIdx.x * 256 + threadIdx.x;
    if (i < n) out[i] = __float2bfloat16(in[i]);
}
__global__ __launch_bounds__(256) void conv_f16_k(
    const float* __restrict__ in, _Float16* __restrict__ out, int n)
{
    int i = blockIdx.x * 256 + threadIdx.x;
    if (i < n) out[i] = (_Float16)in[i];
}

// ---------- legacy VALU GEMM (qout only: N=32) ----------
template<int ACT, bool BT, bool QG, bool MASKQ, typename TA, typename TB, typename TC>
__global__ __launch_bounds__(256) void gemm_k(
    const TA* __restrict__ A, const TB* __restrict__ B,
    const float* __restrict__ bias, TC* __restrict__ C,
    int M, int N, int K, const int* __restrict__ smask)
{
    const int BM = 64, BN = 64, BK = 16;
    __shared__ float Asl[BM][BK + 1];
    __shared__ float Bsl[BK][BN + 1];
    int tid = threadIdx.x;
    int n0 = blockIdx.x * BN;
    int m0 = blockIdx.y * BM;
    int ty = tid >> 4, tx = tid & 15;
    float acc[4][4] = {};

    for (int k0 = 0; k0 < K; k0 += BK) {
        #pragma unroll
        for (int i = 0; i < 4; ++i) {
            int l = tid * 4 + i;
            int r = l >> 4, c = l & 15;
            int gm = m0 + r;
            int ar = QG ? (((gm >> 3) << 5) | (gm & 7)) : gm;
            Asl[r][c] = ldf(&A[(size_t)ar * K + k0 + c]);
        }
        #pragma unroll
        for (int i = 0; i < 4; ++i) {
            int l = tid * 4 + i;
            if (BT) {
                int n = l >> 4, kk = l & 15;
                int gn = n0 + n;
                Bsl[kk][n] = (gn < N) ? ldf(&B[(size_t)gn * K + k0 + kk]) : 0.f;
            } else {
                int r = l >> 6, c = l & 63;
                int gn = n0 + c;
                Bsl[r][c] = (gn < N) ? ldf(&B[(size_t)(k0 + r) * N + gn]) : 0.f;
            }
        }
        __syncthreads();
        #pragma unroll
        for (int kk = 0; kk < BK; ++kk) {
            float a[4], b[4];
            #pragma unroll
            for (int i = 0; i < 4; ++i) a[i] = Asl[ty + i * 16][kk];
            #pragma unroll
            for (int j = 0; j < 4; ++j) b[j] = Bsl[kk][tx + j * 16];
            #pragma unroll
            for (int i = 0; i < 4; ++i)
                #pragma unroll
                for (int j = 0; j < 4; ++j) acc[i][j] += a[i] * b[j];
        }
        __syncthreads();
    }

    #pragma unroll
    for (int i = 0; i < 4; ++i) {
        int gm = m0 + ty + i * 16;
        bool mz = false;
        if (MASKQ) {
            int a_ = gm & 7, t_ = (gm >> 3) & 63, b_ = gm >> 9;
            mz = smask[((b_ << 6) + t_) * 32 + a_] != 0;
        }
        #pragma unroll
        for (int j = 0; j < 4; ++j) {
            int gn = n0 + tx + j * 16;
            if (gn < N) {
                float v = acc[i][j] + bias[gn];
                if (ACT == 1) v = fmaxf(v, 0.f);
                if (MASKQ && mz) v = 0.f;
                stf(&C[(size_t)gm * N + gn], v);
            }
        }
    }
}

// ---------- attention: one wave per (b,t,h) ----------
__global__ __launch_bounds__(64) void attn_k(
    const bf16* __restrict__ qb, const bf16* __restrict__ kb, const bf16* __restrict__ vb,
    const int* __restrict__ obs, const int* __restrict__ smask, bf16* __restrict__ xs)
{
    __shared__ float qs[8 * 64], ks[32 * 64], vs[32 * 64], wsm[8 * 32];
    int bid = blockIdx.x;
    int h = bid & 7;
    int bt = bid >> 3;
    int t = bt & 63, b = bt >> 6;
    int tid = threadIdx.x;

    #pragma unroll
    for (int i = 0; i < 8; ++i) {
        int l = tid + i * 64;
        int e = l >> 6, d = l & 63;
        qs[l] = __bfloat162float(qb[((size_t)bt * 8 + e) * 512 + h * 64 + d]);
    }
    #pragma unroll
    for (int i = 0; i < 32; ++i) {
        int l = tid + i * 64;
        int e = l >> 6, d = l & 63;
        ks[l] = __bfloat162float(kb[((size_t)bt * 32 + e) * 512 + h * 64 + d]);
        vs[l] = __bfloat162float(vb[((size_t)bt * 32 + e) * 512 + h * 64 + d]);
    }
    __syncthreads();

    int ql = tid >> 3, jl = tid & 7;
    float s[4];
    #pragma unroll
    for (int c = 0; c < 4; ++c) {
        int kl = jl + c * 8;
        float acc = 0.f;
        for (int d = 0; d < 64; ++d) acc += qs[ql * 64 + d] * ks[kl * 64 + d];
        acc *= 0.125f;
        bool m = obs[(((size_t)bt * 32) + ql) * 32 + kl] != 0;
        s[c] = m ? -__builtin_inff() : acc;
    }
    float mx = fmaxf(fmaxf(s[0], s[1]), fmaxf(s[2], s[3]));
    for (int off = 1; off < 8; off <<= 1) mx = fmaxf(mx, __shfl_xor(mx, off));
    float e4[4]; float sum = 0.f;
    bool allmasked = (mx == -__builtin_inff());
    #pragma unroll
    for (int c = 0; c < 4; ++c) {
        e4[c] = (allmasked || s[c] == -__builtin_inff()) ? 0.f : expf(s[c] - mx);
        sum += e4[c];
    }
    for (int off = 1; off < 8; off <<= 1) sum += __shfl_xor(sum, off);
    float inv = (sum > 0.f) ? 1.f / sum : 0.f;
    #pragma unroll
    for (int c = 0; c < 4; ++c) wsm[ql * 32 + jl + c * 8] = e4[c] * inv;
    __syncthreads();

    bool amask = smask[(size_t)bt * 32 + ql] != 0;
    #pragma unroll
    for (int dd = 0; dd < 8; ++dd) {
        int d = jl + dd * 8;
        float acc = 0.f;
        for (int kl = 0; kl < 32; ++kl) acc += wsm[ql * 32 + kl] * vs[kl * 64 + d];
        if (amask) acc = 0.f;
        xs[((size_t)(t * 256 + b * 8 + ql)) * 512 + h * 64 + d] = __float2bfloat16(acc);
    }
}

// ---------- GRU v4: group-local rows, 1 wave/CU, full prefetch ----------
// 256 WGs x 64 thr. WG g: grp=g&7 (rows grp*32..+32), cu=g>>3 (cols cu*16..+16).
// LDS: WG's 48x512 f16 w-slice (r|z|n x 16 cols), resident 64 steps.
// Per step: prefetch ALL 32 A half8s; 96 MFMA; gates lane-local (C-layout);
// gi2/smask for t+1 prefetched during barrier window. 8 independent 32-WG barriers.
struct GiRegs {
    float4 r0, z0, n0, r1, z1, n1;
    int m0[4], m1[4];
};
__device__ inline GiRegs load_gi(const float* __restrict__ gi2,
                                 const int* __restrict__ smask,
                                 int t, int row00, int row01, int hcol)
{
    GiRegs g;
    g.r0 = *(const float4*)(gi2 + ((size_t)t * 1536 + hcol)        * 256 + row00);
    g.z0 = *(const float4*)(gi2 + ((size_t)t * 1536 + 512 + hcol)  * 256 + row00);
    g.n0 = *(const float4*)(gi2 + ((size_t)t * 1536 + 1024 + hcol) * 256 + row00);
    g.r1 = *(const float4*)(gi2 + ((size_t)t * 1536 + hcol)        * 256 + row01);
    g.z1 = *(const float4*)(gi2 + ((size_t)t * 1536 + 512 + hcol)  * 256 + row01);
    g.n1 = *(const float4*)(gi2 + ((size_t)t * 1536 + 1024 + hcol) * 256 + row01);
    #pragma unroll
    for (int r = 0; r < 4; ++r) {
        int rowA = row00 + r, rowB = row01 + r;
        g.m0[r] = smask[(((rowA >> 3) << 6) + t) * 32 + (rowA & 7)];
        g.m1[r] = smask[(((rowB >> 3) << 6) + t) * 32 + (rowB & 7)];
    }
    return g;
}

__global__ __launch_bounds__(64, 1) void gru_xcd_k(
    const float* __restrict__ gi2, const float* __restrict__ Whh,
    const float* __restrict__ bhh, const float* __restrict__ h0,
    const int* __restrict__ smask, float* __restrict__ hs_out,
    _Float16* __restrict__ ha, _Float16* __restrict__ hb, int* __restrict__ bar)
{
    __shared__ _Float16 ws16[48 * 520];
    const int lane = threadIdx.x;
    const int g = blockIdx.x;
    const int grp = g & 7, cu = g >> 3;
    const int r0 = grp * 32;
    const int hc0 = cu * 16;
    const int fr = lane & 15, fq = lane >> 4;
    const int hcol = hc0 + fr;
    const int row00 = r0 + fq * 4;
    const int row01 = r0 + 16 + fq * 4;

    // stage w slice: LDS row j (0..47) = Whh[(j>>4)*512 + hc0 + (j&15)][0..512)
    for (int i = lane; i < 6144; i += 64) {
        int flat = i * 4;
        int r = flat >> 9, c = flat & 511;
        int wr = (r >> 4) * 512 + hc0 + (r & 15);
        float4 v = *(const float4*)(Whh + (size_t)wr * 512 + c);
        half2v p0; p0[0] = (_Float16)v.x; p0[1] = (_Float16)v.y;
        half2v p1; p1[0] = (_Float16)v.z; p1[1] = (_Float16)v.w;
        *(uint32_t*)&ws16[r * 520 + c]     = __builtin_bit_cast(uint32_t, p0);
        *(uint32_t*)&ws16[r * 520 + c + 2] = __builtin_bit_cast(uint32_t, p1);
    }

    const float bhr = bhh[hcol], bhz = bhh[512 + hcol], bhn = bhh[1024 + hcol];

    float hp[2][4];
    #pragma unroll
    for (int mt = 0; mt < 2; ++mt)
        #pragma unroll
        for (int r = 0; r < 4; ++r)
            hp[mt][r] = h0[(size_t)(r0 + mt * 16 + fq * 4 + r) * 512 + hcol];

    __syncthreads();   // w staged

    GiRegs gc = load_gi(gi2, smask, 0, row00, row01, hcol);

    for (int t = 0; t < 64; ++t) {
        const _Float16* hsrc = (t & 1) ? hb : ha;
        _Float16*       hdst = (t & 1) ? ha : hb;

        // prefetch entire A slab (32 half8 = 128 VGPR), all loads in flight at once
        half8 aA[2][16];
        #pragma unroll
        for (int mt = 0; mt < 2; ++mt) {
            const _Float16* ap = hsrc + (size_t)(r0 + mt * 16 + fr) * 512 + fq * 8;
            #pragma unroll
            for (int ks = 0; ks < 16; ++ks)
                aA[mt][ks] = *(const half8*)(ap + ks * 32);
        }

        f32x4 acc[2][3] = {};
        #pragma unroll
        for (int ks = 0; ks < 16; ++ks) {
            const _Float16* bbase = &ws16[fr * 520 + ks * 32 + fq * 8];
            half8 b0 = *(const half8*)(bbase);
            half8 b1 = *(const half8*)(bbase + 16 * 520);
            half8 b2 = *(const half8*)(bbase + 32 * 520);
            acc[0][0] = __builtin_amdgcn_mfma_f32_16x16x32_f16(aA[0][ks], b0, acc[0][0], 0, 0, 0);
            acc[0][1] = __builtin_amdgcn_mfma_f32_16x16x32_f16(aA[0][ks], b1, acc[0][1], 0, 0, 0);
            acc[0][2] = __builtin_amdgcn_mfma_f32_16x16x32_f16(aA[0][ks], b2, acc[0][2], 0, 0, 0);
            acc[1][0] = __builtin_amdgcn_mfma_f32_16x16x32_f16(aA[1][ks], b0, acc[1][0], 0, 0, 0);
            acc[1][1] = __builtin_amdgcn_mfma_f32_16x16x32_f16(aA[1][ks], b1, acc[1][1], 0, 0, 0);
            acc[1][2] = __builtin_amdgcn_mfma_f32_16x16x32_f16(aA[1][ks], b2, acc[1][2], 0, 0, 0);
        }

        // gate fusion + stores (C-layout: col = hcol, rows = row0x..+3)
        float grA[2][4] = {{gc.r0.x, gc.r0.y, gc.r0.z, gc.r0.w}, {gc.r1.x, gc.r1.y, gc.r1.z, gc.r1.w}};
        float gzA[2][4] = {{gc.z0.x, gc.z0.y, gc.z0.z, gc.z0.w}, {gc.z1.x, gc.z1.y, gc.z1.z, gc.z1.w}};
        float gnA[2][4] = {{gc.n0.x, gc.n0.y, gc.n0.z, gc.n0.w}, {gc.n1.x, gc.n1.y, gc.n1.z, gc.n1.w}};
        #pragma unroll
        for (int mt = 0; mt < 2; ++mt) {
            int grow0 = (mt == 0) ? row00 : row01;
            #pragma unroll
            for (int r = 0; r < 4; ++r) {
                int row = grow0 + r;
                float rg = 1.f / (1.f + expf(-(grA[mt][r] + acc[mt][0][r] + bhr)));
                float zg = 1.f / (1.f + expf(-(gzA[mt][r] + acc[mt][1][r] + bhz)));
                float ng = tanhf(gnA[mt][r] + rg * (acc[mt][2][r] + bhn));
                float hn = (1.f - zg) * ng + zg * hp[mt][r];
                hp[mt][r] = hn;
                hdst[(size_t)row * 512 + hcol] = (_Float16)hn;
                int b_ = row >> 3, a_ = row & 7;
                bool msk = ((mt == 0) ? gc.m0[r] : gc.m1[r]) != 0;
                hs_out[((size_t)((b_ << 6) + t) * 8 + a_) * 512 + hcol] = msk ? 0.f : hn;
            }
        }

        if (t != 63) {
            __threadfence();   // release: drain hdst stores
            if (lane == 0) atomicAdd(bar + grp * 64 + t, 1);
            // prefetch next step's gi2/smask while the barrier settles
            GiRegs gn2 = load_gi(gi2, smask, t + 1, row00, row01, hcol);
            long it = 0;
            while (__hip_atomic_load(bar + grp * 64 + t, __ATOMIC_RELAXED,
                                     __HIP_MEMORY_SCOPE_AGENT) < 32 &&
                   it < 100000000L) {
                __builtin_amdgcn_s_sleep(2);
                ++it;
            }
            __threadfence();   // acquire: next A-loads see fresh h
            __builtin_amdgcn_sched_barrier(0);
            gc = gn2;
        }
    }
}

// ---------- launch ----------
extern "C" void kernel_launch(void* const* d_in, const int* in_sizes, int n_in,
                              void* d_out, int out_size, void* d_ws, size_t ws_size,
                              hipStream_t stream)
{
    const float* inputs = (const float*)d_in[0];
    const int*   obs    = (const int*)d_in[1];
    const int*   smask  = (const int*)d_in[2];
    const float* h0     = (const float*)d_in[3];
    const float* W1  = (const float*)d_in[4];  const float* b1  = (const float*)d_in[5];
    const float* Wq  = (const float*)d_in[6];  const float* bq  = (const float*)d_in[7];
    const float* Wk  = (const float*)d_in[8];  const float* bk  = (const float*)d_in[9];
    const float* Wv  = (const float*)d_in[10]; const float* bv  = (const float*)d_in[11];
    const float* Wih = (const float*)d_in[12]; const float* bih = (const float*)d_in[13];
    const float* Whh = (const float*)d_in[14]; const float* bhh = (const float*)d_in[15];
    const float* Wo  = (const float*)d_in[16]; const float* bo  = (const float*)d_in[17];

    char* ws = (char*)d_ws;
    bf16*  x    = (bf16*)(ws + 0);
    bf16*  xs   = (bf16*)(ws + 0);
    bf16*  qb   = (bf16*)(ws + 67108864ull);
    bf16*  kb   = (bf16*)(ws + 83886080ull);
    bf16*  vb   = (bf16*)(ws + 150994944ull);
    float* gi2  = (float*)(ws + 16777216ull);
    bf16*  Wihb = (bf16*)(ws + 119013376ull);
    bf16*  W1t  = (bf16*)(ws + 218103808ull);
    bf16*  Wqt  = (bf16*)(ws + 218234880ull);
    bf16*  Wkt  = (bf16*)(ws + 218759168ull);
    bf16*  Wvt  = (bf16*)(ws + 219283456ull);
    _Float16* ha = (_Float16*)(ws + 219807744ull);   // 256 KB
    _Float16* hb = (_Float16*)(ws + 220069888ull);   // 256 KB
    int*   bar  = (int*)(ws + 220332032ull);         // 8 grp x 64 t ints = 2 KB

    float* out    = (float*)d_out;
    float* hs_out = out + 524288;

    hipMemsetAsync(bar, 0, 2048, stream);

    // 0. weight prep
    tconv_k<<<dim3(256), 256, 0, stream>>>(W1, W1t, 128, 512);
    tconv_k<<<dim3(1024), 256, 0, stream>>>(Wq, Wqt, 512, 512);
    tconv_k<<<dim3(1024), 256, 0, stream>>>(Wk, Wkt, 512, 512);
    tconv_k<<<dim3(1024), 256, 0, stream>>>(Wv, Wvt, 512, 512);
    conv_f16_k<<<dim3(512), 256, 0, stream>>>(h0, ha, 131072);
    // 1. fc1
    mfma_gemm_k<1, false, false, float, bf16><<<dim3(4, 512), 256, 0, stream>>>(
        inputs, W1t, b1, x, 65536, 512, 128);
    // 2-4. projections
    mfma_gemm_k<0, true, false, bf16, bf16><<<dim3(4, 128), 256, 0, stream>>>(
        x, Wqt, bq, qb, 16384, 512, 512);
    mfma_gemm_k<0, false, false, bf16, bf16><<<dim3(4, 512), 256, 0, stream>>>(
        x, Wkt, bk, kb, 65536, 512, 512);
    mfma_gemm_k<1, false, false, bf16, bf16><<<dim3(4, 512), 256, 0, stream>>>(
        x, Wvt, bv, vb, 65536, 512, 512);
    // 5. attention -> xs bf16 (x dead)
    attn_k<<<dim3(16384), 64, 0, stream>>>(qb, kb, vb, obs, smask, xs);
    // 5b. Wih -> bf16
    conv_k<<<dim3(3072), 256, 0, stream>>>(Wih, Wihb, 1536 * 512);
    // 6. gi2 = (xs @ Wih^T + bih), stored transposed [t][gatecol][row]
    mfma_gemm_k<0, false, true, bf16, float><<<dim3(12, 128), 256, 0, stream>>>(
        xs, Wihb, bih, gi2, 16384, 1536, 512);
    // 7. GRU v4: 256 WGs x 64 thr, 8 group-local barriers, full prefetch
    gru_xcd_k<<<dim3(256), 64, 0, stream>>>(
        gi2, Whh, bhh, h0, smask, hs_out, ha, hb, bar);
    // 8. qout
    gemm_k<0, false, false, true><<<dim3(1, 256), 256, 0, stream>>>(
        hs_out, Wo, bo, out, 16384, 32, 512, smask);
}

// Round 8
// 901.016 us; speedup vs baseline: 7.8586x; 1.6353x over previous
//
#include <hip/hip_runtime.h>
#include <hip/hip_bf16.h>
#include <cstddef>
#include <cstdint>

typedef __hip_bfloat16 bf16;
typedef __attribute__((ext_vector_type(2))) _Float16 half2v;
typedef __attribute__((ext_vector_type(8))) _Float16 half8;
typedef __attribute__((ext_vector_type(8))) short short8;
typedef __attribute__((ext_vector_type(4))) float f32x4;
typedef __attribute__((ext_vector_type(2))) unsigned long long u64x2;

// ---------- helpers ----------
__device__ inline float ldf(const float* p) { return *p; }
__device__ inline float ldf(const bf16* p) { return __bfloat162float(*p); }
__device__ inline void stf(float* p, float v) { *p = v; }
__device__ inline void stf(bf16* p, float v) { *p = __float2bfloat16(v); }
__device__ inline short bfb(float v) { return __builtin_bit_cast(short, __float2bfloat16(v)); }

__device__ inline half8 h8_from(unsigned long long lo, unsigned long long hi) {
    u64x2 t; t.x = lo; t.y = hi;
    return __builtin_bit_cast(half8, t);
}

// Problem constants: BS=32, T=64, NE=32, NA=8, ED=128, H=512, A=512, NH=8, HD=64, NACT=32

// ---------- MFMA bf16 GEMM: C[M,N] = act(A[M,K] @ Bt[N,K]^T + bias) ----------
template<int ACT, bool QG, bool GI2, typename TA, typename TC>
__global__ __launch_bounds__(256) void mfma_gemm_k(
    const TA* __restrict__ A, const bf16* __restrict__ Bt,
    const float* __restrict__ bias, TC* __restrict__ C,
    int M, int N, int K)
{
    __shared__ short As[128][40];
    __shared__ short Bs[128][40];
    const int tid = threadIdx.x;
    const int lane = tid & 63, wid = tid >> 6;
    const int wm = wid >> 1, wn = wid & 1;
    const int bm = blockIdx.y * 128, bn = blockIdx.x * 128;
    const int fr = lane & 15, fq = lane >> 4;
    const int sr = tid >> 1, sk = (tid & 1) * 16;

    f32x4 acc[4][4] = {};

    for (int k0 = 0; k0 < K; k0 += 32) {
        {
            int gm = bm + sr;
            int ar = QG ? (((gm >> 3) << 5) | (gm & 7)) : gm;
            if constexpr (sizeof(TA) == 4) {
                const float* ap = (const float*)A + (size_t)ar * K + k0 + sk;
                short tmp[16];
                #pragma unroll
                for (int j = 0; j < 16; ++j) tmp[j] = bfb(ap[j]);
                *(uint4*)&As[sr][sk]     = *(const uint4*)&tmp[0];
                *(uint4*)&As[sr][sk + 8] = *(const uint4*)&tmp[8];
            } else {
                const short* ap = (const short*)A + (size_t)ar * K + k0 + sk;
                *(uint4*)&As[sr][sk]     = *(const uint4*)(ap);
                *(uint4*)&As[sr][sk + 8] = *(const uint4*)(ap + 8);
            }
        }
        {
            const short* bp = (const short*)Bt + (size_t)(bn + sr) * K + k0 + sk;
            *(uint4*)&Bs[sr][sk]     = *(const uint4*)(bp);
            *(uint4*)&Bs[sr][sk + 8] = *(const uint4*)(bp + 8);
        }
        __syncthreads();

        short8 af[4], bg[4];
        #pragma unroll
        for (int m = 0; m < 4; ++m)
            af[m] = *(const short8*)&As[wm * 64 + m * 16 + fr][fq * 8];
        #pragma unroll
        for (int n = 0; n < 4; ++n)
            bg[n] = *(const short8*)&Bs[wn * 64 + n * 16 + fr][fq * 8];
        #pragma unroll
        for (int m = 0; m < 4; ++m)
            #pragma unroll
            for (int n = 0; n < 4; ++n)
                acc[m][n] = __builtin_amdgcn_mfma_f32_16x16x32_bf16(
                    af[m], bg[n], acc[m][n], 0, 0, 0);
        __syncthreads();
    }

    #pragma unroll
    for (int m = 0; m < 4; ++m) {
        #pragma unroll
        for (int n = 0; n < 4; ++n) {
            int col = bn + wn * 64 + n * 16 + fr;
            float bv = bias[col];
            if constexpr (GI2) {
                int gm0 = bm + wm * 64 + m * 16 + fq * 4;
                float4 v = make_float4(acc[m][n][0] + bv, acc[m][n][1] + bv,
                                       acc[m][n][2] + bv, acc[m][n][3] + bv);
                *(float4*)((float*)C + ((size_t)(gm0 >> 8) * 1536 + col) * 256 + (gm0 & 255)) = v;
            } else {
                #pragma unroll
                for (int r = 0; r < 4; ++r) {
                    int row = bm + wm * 64 + m * 16 + fq * 4 + r;
                    float v = acc[m][n][r] + bv;
                    if (ACT == 1) v = fmaxf(v, 0.f);
                    stf(&C[(size_t)row * N + col], v);
                }
            }
        }
    }
}

// ---------- weight prep ----------
__global__ __launch_bounds__(256) void tconv_k(
    const float* __restrict__ in, bf16* __restrict__ out, int K, int N)
{
    int idx = blockIdx.x * 256 + threadIdx.x;
    if (idx >= K * N) return;
    int n = idx / K, k = idx - n * K;
    out[idx] = __float2bfloat16(in[(size_t)k * N + n]);
}
__global__ __launch_bounds__(256) void conv_k(
    const float* __restrict__ in, bf16* __restrict__ out, int n)
{
    int i = blockIdx.x * 256 + threadIdx.x;
    if (i < n) out[i] = __float2bfloat16(in[i]);
}
__global__ __launch_bounds__(256) void conv_f16_k(
    const float* __restrict__ in, _Float16* __restrict__ out, int n)
{
    int i = blockIdx.x * 256 + threadIdx.x;
    if (i < n) out[i] = (_Float16)in[i];
}

// ---------- legacy VALU GEMM (qout only: N=32) ----------
template<int ACT, bool BT, bool QG, bool MASKQ, typename TA, typename TB, typename TC>
__global__ __launch_bounds__(256) void gemm_k(
    const TA* __restrict__ A, const TB* __restrict__ B,
    const float* __restrict__ bias, TC* __restrict__ C,
    int M, int N, int K, const int* __restrict__ smask)
{
    const int BM = 64, BN = 64, BK = 16;
    __shared__ float Asl[BM][BK + 1];
    __shared__ float Bsl[BK][BN + 1];
    int tid = threadIdx.x;
    int n0 = blockIdx.x * BN;
    int m0 = blockIdx.y * BM;
    int ty = tid >> 4, tx = tid & 15;
    float acc[4][4] = {};

    for (int k0 = 0; k0 < K; k0 += BK) {
        #pragma unroll
        for (int i = 0; i < 4; ++i) {
            int l = tid * 4 + i;
            int r = l >> 4, c = l & 15;
            int gm = m0 + r;
            int ar = QG ? (((gm >> 3) << 5) | (gm & 7)) : gm;
            Asl[r][c] = ldf(&A[(size_t)ar * K + k0 + c]);
        }
        #pragma unroll
        for (int i = 0; i < 4; ++i) {
            int l = tid * 4 + i;
            if (BT) {
                int n = l >> 4, kk = l & 15;
                int gn = n0 + n;
                Bsl[kk][n] = (gn < N) ? ldf(&B[(size_t)gn * K + k0 + kk]) : 0.f;
            } else {
                int r = l >> 6, c = l & 63;
                int gn = n0 + c;
                Bsl[r][c] = (gn < N) ? ldf(&B[(size_t)(k0 + r) * N + gn]) : 0.f;
            }
        }
        __syncthreads();
        #pragma unroll
        for (int kk = 0; kk < BK; ++kk) {
            float a[4], b[4];
            #pragma unroll
            for (int i = 0; i < 4; ++i) a[i] = Asl[ty + i * 16][kk];
            #pragma unroll
            for (int j = 0; j < 4; ++j) b[j] = Bsl[kk][tx + j * 16];
            #pragma unroll
            for (int i = 0; i < 4; ++i)
                #pragma unroll
                for (int j = 0; j < 4; ++j) acc[i][j] += a[i] * b[j];
        }
        __syncthreads();
    }

    #pragma unroll
    for (int i = 0; i < 4; ++i) {
        int gm = m0 + ty + i * 16;
        bool mz = false;
        if (MASKQ) {
            int a_ = gm & 7, t_ = (gm >> 3) & 63, b_ = gm >> 9;
            mz = smask[((b_ << 6) + t_) * 32 + a_] != 0;
        }
        #pragma unroll
        for (int j = 0; j < 4; ++j) {
            int gn = n0 + tx + j * 16;
            if (gn < N) {
                float v = acc[i][j] + bias[gn];
                if (ACT == 1) v = fmaxf(v, 0.f);
                if (MASKQ && mz) v = 0.f;
                stf(&C[(size_t)gm * N + gn], v);
            }
        }
    }
}

// ---------- attention: one wave per (b,t,h) ----------
__global__ __launch_bounds__(64) void attn_k(
    const bf16* __restrict__ qb, const bf16* __restrict__ kb, const bf16* __restrict__ vb,
    const int* __restrict__ obs, const int* __restrict__ smask, bf16* __restrict__ xs)
{
    __shared__ float qs[8 * 64], ks[32 * 64], vs[32 * 64], wsm[8 * 32];
    int bid = blockIdx.x;
    int h = bid & 7;
    int bt = bid >> 3;
    int t = bt & 63, b = bt >> 6;
    int tid = threadIdx.x;

    #pragma unroll
    for (int i = 0; i < 8; ++i) {
        int l = tid + i * 64;
        int e = l >> 6, d = l & 63;
        qs[l] = __bfloat162float(qb[((size_t)bt * 8 + e) * 512 + h * 64 + d]);
    }
    #pragma unroll
    for (int i = 0; i < 32; ++i) {
        int l = tid + i * 64;
        int e = l >> 6, d = l & 63;
        ks[l] = __bfloat162float(kb[((size_t)bt * 32 + e) * 512 + h * 64 + d]);
        vs[l] = __bfloat162float(vb[((size_t)bt * 32 + e) * 512 + h * 64 + d]);
    }
    __syncthreads();

    int ql = tid >> 3, jl = tid & 7;
    float s[4];
    #pragma unroll
    for (int c = 0; c < 4; ++c) {
        int kl = jl + c * 8;
        float acc = 0.f;
        for (int d = 0; d < 64; ++d) acc += qs[ql * 64 + d] * ks[kl * 64 + d];
        acc *= 0.125f;
        bool m = obs[(((size_t)bt * 32) + ql) * 32 + kl] != 0;
        s[c] = m ? -__builtin_inff() : acc;
    }
    float mx = fmaxf(fmaxf(s[0], s[1]), fmaxf(s[2], s[3]));
    for (int off = 1; off < 8; off <<= 1) mx = fmaxf(mx, __shfl_xor(mx, off));
    float e4[4]; float sum = 0.f;
    bool allmasked = (mx == -__builtin_inff());
    #pragma unroll
    for (int c = 0; c < 4; ++c) {
        e4[c] = (allmasked || s[c] == -__builtin_inff()) ? 0.f : expf(s[c] - mx);
        sum += e4[c];
    }
    for (int off = 1; off < 8; off <<= 1) sum += __shfl_xor(sum, off);
    float inv = (sum > 0.f) ? 1.f / sum : 0.f;
    #pragma unroll
    for (int c = 0; c < 4; ++c) wsm[ql * 32 + jl + c * 8] = e4[c] * inv;
    __syncthreads();

    bool amask = smask[(size_t)bt * 32 + ql] != 0;
    #pragma unroll
    for (int dd = 0; dd < 8; ++dd) {
        int d = jl + dd * 8;
        float acc = 0.f;
        for (int kl = 0; kl < 32; ++kl) acc += wsm[ql * 32 + kl] * vs[kl * 64 + d];
        if (amask) acc = 0.f;
        xs[((size_t)(t * 256 + b * 8 + ql)) * 512 + h * 64 + d] = __float2bfloat16(acc);
    }
}

// ---------- GRU v5: group-local rows, sc-bypassed h exchange, no bulk fences ----------
// 256 WGs x 64 thr. WG g: grp=g&7 (rows grp*32..+32), cu=g>>3 (cols cu*16..+16).
// h exchanged via agent-scope relaxed atomics (bypass non-coherent XCD L2 -> L3
// coherence point); NO __threadfence (avoids per-step buffer_wbl2/L2-inv storms).
// Barrier: vmcnt(0) drain -> atomicAdd -> all-lane relaxed poll -> sched_barrier.
struct GiRegs {
    float4 r0, z0, n0, r1, z1, n1;
    int m0[4], m1[4];
};
__device__ inline GiRegs load_gi(const float* __restrict__ gi2,
                                 const int* __restrict__ smask,
                                 int t, int row00, int row01, int hcol)
{
    GiRegs g;
    g.r0 = *(const float4*)(gi2 + ((size_t)t * 1536 + hcol)        * 256 + row00);
    g.z0 = *(const float4*)(gi2 + ((size_t)t * 1536 + 512 + hcol)  * 256 + row00);
    g.n0 = *(const float4*)(gi2 + ((size_t)t * 1536 + 1024 + hcol) * 256 + row00);
    g.r1 = *(const float4*)(gi2 + ((size_t)t * 1536 + hcol)        * 256 + row01);
    g.z1 = *(const float4*)(gi2 + ((size_t)t * 1536 + 512 + hcol)  * 256 + row01);
    g.n1 = *(const float4*)(gi2 + ((size_t)t * 1536 + 1024 + hcol) * 256 + row01);
    #pragma unroll
    for (int r = 0; r < 4; ++r) {
        int rowA = row00 + r, rowB = row01 + r;
        g.m0[r] = smask[(((rowA >> 3) << 6) + t) * 32 + (rowA & 7)];
        g.m1[r] = smask[(((rowB >> 3) << 6) + t) * 32 + (rowB & 7)];
    }
    return g;
}

__global__ __launch_bounds__(64, 1) void gru_xcd_k(
    const float* __restrict__ gi2, const float* __restrict__ Whh,
    const float* __restrict__ bhh, const float* __restrict__ h0,
    const int* __restrict__ smask, float* __restrict__ hs_out,
    _Float16* __restrict__ ha, _Float16* __restrict__ hb, int* __restrict__ bar)
{
    __shared__ _Float16 ws16[48 * 520];
    const int lane = threadIdx.x;
    const int g = blockIdx.x;
    const int grp = g & 7, cu = g >> 3;
    const int r0 = grp * 32;
    const int hc0 = cu * 16;
    const int fr = lane & 15, fq = lane >> 4;
    const int hcol = hc0 + fr;
    const int row00 = r0 + fq * 4;
    const int row01 = r0 + 16 + fq * 4;

    // stage w slice: LDS row j (0..47) = Whh[(j>>4)*512 + hc0 + (j&15)][0..512)
    for (int i = lane; i < 6144; i += 64) {
        int flat = i * 4;
        int r = flat >> 9, c = flat & 511;
        int wr = (r >> 4) * 512 + hc0 + (r & 15);
        float4 v = *(const float4*)(Whh + (size_t)wr * 512 + c);
        half2v p0; p0[0] = (_Float16)v.x; p0[1] = (_Float16)v.y;
        half2v p1; p1[0] = (_Float16)v.z; p1[1] = (_Float16)v.w;
        *(uint32_t*)&ws16[r * 520 + c]     = __builtin_bit_cast(uint32_t, p0);
        *(uint32_t*)&ws16[r * 520 + c + 2] = __builtin_bit_cast(uint32_t, p1);
    }

    const float bhr = bhh[hcol], bhz = bhh[512 + hcol], bhn = bhh[1024 + hcol];

    float hp[2][4];
    #pragma unroll
    for (int mt = 0; mt < 2; ++mt)
        #pragma unroll
        for (int r = 0; r < 4; ++r)
            hp[mt][r] = h0[(size_t)(r0 + mt * 16 + fq * 4 + r) * 512 + hcol];

    __syncthreads();   // w staged

    GiRegs gc = load_gi(gi2, smask, 0, row00, row01, hcol);

    for (int t = 0; t < 64; ++t) {
        const _Float16* hsrc = (t & 1) ? hb : ha;
        _Float16*       hdst = (t & 1) ? ha : hb;

        // A-slab via agent-scope relaxed 8B loads (bypass stale L1/L2; compiler
        // tracks waitcnt). 64 loads/lane, all independent.
        half8 aA[2][16];
        #pragma unroll
        for (int mt = 0; mt < 2; ++mt) {
            const unsigned long long* ap = (const unsigned long long*)
                (hsrc + (size_t)(r0 + mt * 16 + fr) * 512 + fq * 8);
            #pragma unroll
            for (int ks = 0; ks < 16; ++ks) {
                unsigned long long lo = __hip_atomic_load(ap + ks * 8,
                    __ATOMIC_RELAXED, __HIP_MEMORY_SCOPE_AGENT);
                unsigned long long hi = __hip_atomic_load(ap + ks * 8 + 1,
                    __ATOMIC_RELAXED, __HIP_MEMORY_SCOPE_AGENT);
                aA[mt][ks] = h8_from(lo, hi);
            }
        }

        f32x4 acc[2][3] = {};
        #pragma unroll
        for (int ks = 0; ks < 16; ++ks) {
            const _Float16* bbase = &ws16[fr * 520 + ks * 32 + fq * 8];
            half8 b0 = *(const half8*)(bbase);
            half8 b1 = *(const half8*)(bbase + 16 * 520);
            half8 b2 = *(const half8*)(bbase + 32 * 520);
            acc[0][0] = __builtin_amdgcn_mfma_f32_16x16x32_f16(aA[0][ks], b0, acc[0][0], 0, 0, 0);
            acc[0][1] = __builtin_amdgcn_mfma_f32_16x16x32_f16(aA[0][ks], b1, acc[0][1], 0, 0, 0);
            acc[0][2] = __builtin_amdgcn_mfma_f32_16x16x32_f16(aA[0][ks], b2, acc[0][2], 0, 0, 0);
            acc[1][0] = __builtin_amdgcn_mfma_f32_16x16x32_f16(aA[1][ks], b0, acc[1][0], 0, 0, 0);
            acc[1][1] = __builtin_amdgcn_mfma_f32_16x16x32_f16(aA[1][ks], b1, acc[1][1], 0, 0, 0);
            acc[1][2] = __builtin_amdgcn_mfma_f32_16x16x32_f16(aA[1][ks], b2, acc[1][2], 0, 0, 0);
        }

        // gate fusion; h-state stays f32 in regs
        float grA[2][4] = {{gc.r0.x, gc.r0.y, gc.r0.z, gc.r0.w}, {gc.r1.x, gc.r1.y, gc.r1.z, gc.r1.w}};
        float gzA[2][4] = {{gc.z0.x, gc.z0.y, gc.z0.z, gc.z0.w}, {gc.z1.x, gc.z1.y, gc.z1.z, gc.z1.w}};
        float gnA[2][4] = {{gc.n0.x, gc.n0.y, gc.n0.z, gc.n0.w}, {gc.n1.x, gc.n1.y, gc.n1.z, gc.n1.w}};
        float hnv[2][4];
        #pragma unroll
        for (int mt = 0; mt < 2; ++mt) {
            int grow0 = (mt == 0) ? row00 : row01;
            #pragma unroll
            for (int r = 0; r < 4; ++r) {
                float rg = 1.f / (1.f + expf(-(grA[mt][r] + acc[mt][0][r] + bhr)));
                float zg = 1.f / (1.f + expf(-(gzA[mt][r] + acc[mt][1][r] + bhz)));
                float ng = tanhf(gnA[mt][r] + rg * (acc[mt][2][r] + bhn));
                float hn = (1.f - zg) * ng + zg * hp[mt][r];
                hp[mt][r] = hn;
                hnv[mt][r] = hn;
                // h exchange store: agent-scope relaxed 2B (bypasses XCD L2)
                unsigned short hbits = __builtin_bit_cast(unsigned short, (_Float16)hn);
                __hip_atomic_store((unsigned short*)(hdst + (size_t)(grow0 + r) * 512 + hcol),
                                   hbits, __ATOMIC_RELAXED, __HIP_MEMORY_SCOPE_AGENT);
            }
        }

        if (t != 63) {
            // drain h stores to the coherence point, then signal
            asm volatile("s_waitcnt vmcnt(0)" ::: "memory");
            if (lane == 0) atomicAdd(bar + grp * 64 + t, 1);
            // overlap: hs_out stores + next-step gi/smask prefetch during the wait
            #pragma unroll
            for (int mt = 0; mt < 2; ++mt) {
                int grow0 = (mt == 0) ? row00 : row01;
                #pragma unroll
                for (int r = 0; r < 4; ++r) {
                    int row = grow0 + r;
                    int b_ = row >> 3, a_ = row & 7;
                    bool msk = ((mt == 0) ? gc.m0[r] : gc.m1[r]) != 0;
                    hs_out[((size_t)((b_ << 6) + t) * 8 + a_) * 512 + hcol] =
                        msk ? 0.f : hnv[mt][r];
                }
            }
            GiRegs gn2 = load_gi(gi2, smask, t + 1, row00, row01, hcol);
            long it = 0;
            while (__hip_atomic_load(bar + grp * 64 + t, __ATOMIC_RELAXED,
                                     __HIP_MEMORY_SCOPE_AGENT) < 32 &&
                   it < 100000000L) {
                __builtin_amdgcn_s_sleep(1);
                ++it;
            }
            __builtin_amdgcn_sched_barrier(0);
            gc = gn2;
        } else {
            #pragma unroll
            for (int mt = 0; mt < 2; ++mt) {
                int grow0 = (mt == 0) ? row00 : row01;
                #pragma unroll
                for (int r = 0; r < 4; ++r) {
                    int row = grow0 + r;
                    int b_ = row >> 3, a_ = row & 7;
                    bool msk = ((mt == 0) ? gc.m0[r] : gc.m1[r]) != 0;
                    hs_out[((size_t)((b_ << 6) + t) * 8 + a_) * 512 + hcol] =
                        msk ? 0.f : hnv[mt][r];
                }
            }
        }
    }
}

// ---------- launch ----------
extern "C" void kernel_launch(void* const* d_in, const int* in_sizes, int n_in,
                              void* d_out, int out_size, void* d_ws, size_t ws_size,
                              hipStream_t stream)
{
    const float* inputs = (const float*)d_in[0];
    const int*   obs    = (const int*)d_in[1];
    const int*   smask  = (const int*)d_in[2];
    const float* h0     = (const float*)d_in[3];
    const float* W1  = (const float*)d_in[4];  const float* b1  = (const float*)d_in[5];
    const float* Wq  = (const float*)d_in[6];  const float* bq  = (const float*)d_in[7];
    const float* Wk  = (const float*)d_in[8];  const float* bk  = (const float*)d_in[9];
    const float* Wv  = (const float*)d_in[10]; const float* bv  = (const float*)d_in[11];
    const float* Wih = (const float*)d_in[12]; const float* bih = (const float*)d_in[13];
    const float* Whh = (const float*)d_in[14]; const float* bhh = (const float*)d_in[15];
    const float* Wo  = (const float*)d_in[16]; const float* bo  = (const float*)d_in[17];

    char* ws = (char*)d_ws;
    bf16*  x    = (bf16*)(ws + 0);
    bf16*  xs   = (bf16*)(ws + 0);
    bf16*  qb   = (bf16*)(ws + 67108864ull);
    bf16*  kb   = (bf16*)(ws + 83886080ull);
    bf16*  vb   = (bf16*)(ws + 150994944ull);
    float* gi2  = (float*)(ws + 16777216ull);
    bf16*  Wihb = (bf16*)(ws + 119013376ull);
    bf16*  W1t  = (bf16*)(ws + 218103808ull);
    bf16*  Wqt  = (bf16*)(ws + 218234880ull);
    bf16*  Wkt  = (bf16*)(ws + 218759168ull);
    bf16*  Wvt  = (bf16*)(ws + 219283456ull);
    _Float16* ha = (_Float16*)(ws + 219807744ull);   // 256 KB
    _Float16* hb = (_Float16*)(ws + 220069888ull);   // 256 KB
    int*   bar  = (int*)(ws + 220332032ull);         // 8 grp x 64 t ints = 2 KB

    float* out    = (float*)d_out;
    float* hs_out = out + 524288;

    hipMemsetAsync(bar, 0, 2048, stream);

    // 0. weight prep
    tconv_k<<<dim3(256), 256, 0, stream>>>(W1, W1t, 128, 512);
    tconv_k<<<dim3(1024), 256, 0, stream>>>(Wq, Wqt, 512, 512);
    tconv_k<<<dim3(1024), 256, 0, stream>>>(Wk, Wkt, 512, 512);
    tconv_k<<<dim3(1024), 256, 0, stream>>>(Wv, Wvt, 512, 512);
    conv_f16_k<<<dim3(512), 256, 0, stream>>>(h0, ha, 131072);
    // 1. fc1
    mfma_gemm_k<1, false, false, float, bf16><<<dim3(4, 512), 256, 0, stream>>>(
        inputs, W1t, b1, x, 65536, 512, 128);
    // 2-4. projections
    mfma_gemm_k<0, true, false, bf16, bf16><<<dim3(4, 128), 256, 0, stream>>>(
        x, Wqt, bq, qb, 16384, 512, 512);
    mfma_gemm_k<0, false, false, bf16, bf16><<<dim3(4, 512), 256, 0, stream>>>(
        x, Wkt, bk, kb, 65536, 512, 512);
    mfma_gemm_k<1, false, false, bf16, bf16><<<dim3(4, 512), 256, 0, stream>>>(
        x, Wvt, bv, vb, 65536, 512, 512);
    // 5. attention -> xs bf16 (x dead)
    attn_k<<<dim3(16384), 64, 0, stream>>>(qb, kb, vb, obs, smask, xs);
    // 5b. Wih -> bf16
    conv_k<<<dim3(3072), 256, 0, stream>>>(Wih, Wihb, 1536 * 512);
    // 6. gi2 = (xs @ Wih^T + bih), stored transposed [t][gatecol][row]
    mfma_gemm_k<0, false, true, bf16, float><<<dim3(12, 128), 256, 0, stream>>>(
        xs, Wihb, bih, gi2, 16384, 1536, 512);
    // 7. GRU v5: sc-bypassed exchange, no bulk fences
    gru_xcd_k<<<dim3(256), 64, 0, stream>>>(
        gi2, Whh, bhh, h0, smask, hs_out, ha, hb, bar);
    // 8. qout
    gemm_k<0, false, false, true><<<dim3(1, 256), 256, 0, stream>>>(
        hs_out, Wo, bo, out, 16384, 32, 512, smask);
}

// Round 9
// 899.985 us; speedup vs baseline: 7.8676x; 1.0011x over previous
//
#include <hip/hip_runtime.h>
#include <hip/hip_bf16.h>
#include <cstddef>
#include <cstdint>

typedef __hip_bfloat16 bf16;
typedef __attribute__((ext_vector_type(2))) _Float16 half2v;
typedef __attribute__((ext_vector_type(8))) _Float16 half8;
typedef __attribute__((ext_vector_type(8))) short short8;
typedef __attribute__((ext_vector_type(4))) float f32x4;
typedef __attribute__((ext_vector_type(2))) unsigned long long u64x2;

// ---------- helpers ----------
__device__ inline float ldf(const float* p) { return *p; }
__device__ inline float ldf(const bf16* p) { return __bfloat162float(*p); }
__device__ inline void stf(float* p, float v) { *p = v; }
__device__ inline void stf(bf16* p, float v) { *p = __float2bfloat16(v); }
__device__ inline short bfb(float v) { return __builtin_bit_cast(short, __float2bfloat16(v)); }

__device__ inline half8 h8_from(unsigned long long lo, unsigned long long hi) {
    u64x2 t; t.x = lo; t.y = hi;
    return __builtin_bit_cast(half8, t);
}

// Problem constants: BS=32, T=64, NE=32, NA=8, ED=128, H=512, A=512, NH=8, HD=64, NACT=32

// ---------- MFMA bf16 GEMM: C[M,N] = act(A[M,K] @ Bt[N,K]^T + bias) ----------
// 128x128 tile, BK=32, 256 thr = 4 waves (2x2), wave owns 64x64.
// Staging via global_load_lds dwordx4 (bf16 A) / reg-convert (f32 A, fc1 only).
// Linear LDS [128][32] shorts: DMA dest = wave-uniform base + lane*16B.
template<int ACT, bool QG, bool GI2, typename TA, typename TC>
__global__ __launch_bounds__(256) void mfma_gemm_k(
    const TA* __restrict__ A, const bf16* __restrict__ Bt,
    const float* __restrict__ bias, TC* __restrict__ C,
    int M, int N, int K)
{
    __shared__ short As[4096];   // [128][32] linear
    __shared__ short Bs[4096];
    const int tid = threadIdx.x;
    const int lane = tid & 63, wid = tid >> 6;
    const int wm = wid >> 1, wn = wid & 1;
    const int bm = blockIdx.y * 128, bn = blockIdx.x * 128;
    const int fr = lane & 15, fq = lane >> 4;

    f32x4 acc[4][4] = {};

    for (int k0 = 0; k0 < K; k0 += 32) {
#if __has_builtin(__builtin_amdgcn_global_load_lds)
        // B tile: 8 x 1KB DMA issues (2 per wave). issue jj: rows jj*16..+15.
        #pragma unroll
        for (int j = 0; j < 2; ++j) {
            int jj = wid * 2 + j;
            int row = jj * 16 + (lane >> 2);
            const short* src = (const short*)Bt + (size_t)(bn + row) * K + k0 + (lane & 3) * 8;
            __builtin_amdgcn_global_load_lds(
                (const __attribute__((address_space(1))) void*)src,
                (__attribute__((address_space(3))) void*)&Bs[jj * 512], 16, 0, 0);
        }
        if constexpr (sizeof(TA) == 2) {
            #pragma unroll
            for (int j = 0; j < 2; ++j) {
                int jj = wid * 2 + j;
                int row = jj * 16 + (lane >> 2);
                int gm = bm + row;
                int ar = QG ? (((gm >> 3) << 5) | (gm & 7)) : gm;
                const short* src = (const short*)A + (size_t)ar * K + k0 + (lane & 3) * 8;
                __builtin_amdgcn_global_load_lds(
                    (const __attribute__((address_space(1))) void*)src,
                    (__attribute__((address_space(3))) void*)&As[jj * 512], 16, 0, 0);
            }
        } else {
            // f32 A (fc1): reg-convert staging, 16 shorts/thread
            int sr = tid >> 1, sk = (tid & 1) * 16;
            int gm = bm + sr;
            int ar = QG ? (((gm >> 3) << 5) | (gm & 7)) : gm;
            const float* ap = (const float*)A + (size_t)ar * K + k0 + sk;
            short tmp[16];
            #pragma unroll
            for (int j = 0; j < 16; ++j) tmp[j] = bfb(ap[j]);
            *(uint4*)&As[sr * 32 + sk]     = *(const uint4*)&tmp[0];
            *(uint4*)&As[sr * 32 + sk + 8] = *(const uint4*)&tmp[8];
        }
#else
        {
            int sr = tid >> 1, sk = (tid & 1) * 16;
            int gm = bm + sr;
            int ar = QG ? (((gm >> 3) << 5) | (gm & 7)) : gm;
            if constexpr (sizeof(TA) == 4) {
                const float* ap = (const float*)A + (size_t)ar * K + k0 + sk;
                short tmp[16];
                #pragma unroll
                for (int j = 0; j < 16; ++j) tmp[j] = bfb(ap[j]);
                *(uint4*)&As[sr * 32 + sk]     = *(const uint4*)&tmp[0];
                *(uint4*)&As[sr * 32 + sk + 8] = *(const uint4*)&tmp[8];
            } else {
                const short* ap = (const short*)A + (size_t)ar * K + k0 + sk;
                *(uint4*)&As[sr * 32 + sk]     = *(const uint4*)(ap);
                *(uint4*)&As[sr * 32 + sk + 8] = *(const uint4*)(ap + 8);
            }
            const short* bp = (const short*)Bt + (size_t)(bn + sr) * K + k0 + sk;
            *(uint4*)&Bs[sr * 32 + sk]     = *(const uint4*)(bp);
            *(uint4*)&Bs[sr * 32 + sk + 8] = *(const uint4*)(bp + 8);
        }
#endif
        __syncthreads();

        short8 af[4], bg[4];
        #pragma unroll
        for (int m = 0; m < 4; ++m)
            af[m] = *(const short8*)&As[(wm * 64 + m * 16 + fr) * 32 + fq * 8];
        #pragma unroll
        for (int n = 0; n < 4; ++n)
            bg[n] = *(const short8*)&Bs[(wn * 64 + n * 16 + fr) * 32 + fq * 8];
        #pragma unroll
        for (int m = 0; m < 4; ++m)
            #pragma unroll
            for (int n = 0; n < 4; ++n)
                acc[m][n] = __builtin_amdgcn_mfma_f32_16x16x32_bf16(
                    af[m], bg[n], acc[m][n], 0, 0, 0);
        __syncthreads();
    }

    #pragma unroll
    for (int m = 0; m < 4; ++m) {
        #pragma unroll
        for (int n = 0; n < 4; ++n) {
            int col = bn + wn * 64 + n * 16 + fr;
            float bv = bias[col];
            if constexpr (GI2) {
                int gm0 = bm + wm * 64 + m * 16 + fq * 4;
                float4 v = make_float4(acc[m][n][0] + bv, acc[m][n][1] + bv,
                                       acc[m][n][2] + bv, acc[m][n][3] + bv);
                *(float4*)((float*)C + ((size_t)(gm0 >> 8) * 1536 + col) * 256 + (gm0 & 255)) = v;
            } else {
                #pragma unroll
                for (int r = 0; r < 4; ++r) {
                    int row = bm + wm * 64 + m * 16 + fq * 4 + r;
                    float v = acc[m][n][r] + bv;
                    if (ACT == 1) v = fmaxf(v, 0.f);
                    stf(&C[(size_t)row * N + col], v);
                }
            }
        }
    }
}

// ---------- weight prep ----------
__global__ __launch_bounds__(256) void tconv_k(
    const float* __restrict__ in, bf16* __restrict__ out, int K, int N)
{
    int idx = blockIdx.x * 256 + threadIdx.x;
    if (idx >= K * N) return;
    int n = idx / K, k = idx - n * K;
    out[idx] = __float2bfloat16(in[(size_t)k * N + n]);
}
__global__ __launch_bounds__(256) void conv_k(
    const float* __restrict__ in, bf16* __restrict__ out, int n)
{
    int i = blockIdx.x * 256 + threadIdx.x;
    if (i < n) out[i] = __float2bfloat16(in[i]);
}
__global__ __launch_bounds__(256) void conv_f16_k(
    const float* __restrict__ in, _Float16* __restrict__ out, int n)
{
    int i = blockIdx.x * 256 + threadIdx.x;
    if (i < n) out[i] = (_Float16)in[i];
}

// ---------- legacy VALU GEMM (qout only: N=32) ----------
template<int ACT, bool BT, bool QG, bool MASKQ, typename TA, typename TB, typename TC>
__global__ __launch_bounds__(256) void gemm_k(
    const TA* __restrict__ A, const TB* __restrict__ B,
    const float* __restrict__ bias, TC* __restrict__ C,
    int M, int N, int K, const int* __restrict__ smask)
{
    const int BM = 64, BN = 64, BK = 16;
    __shared__ float Asl[BM][BK + 1];
    __shared__ float Bsl[BK][BN + 1];
    int tid = threadIdx.x;
    int n0 = blockIdx.x * BN;
    int m0 = blockIdx.y * BM;
    int ty = tid >> 4, tx = tid & 15;
    float acc[4][4] = {};

    for (int k0 = 0; k0 < K; k0 += BK) {
        #pragma unroll
        for (int i = 0; i < 4; ++i) {
            int l = tid * 4 + i;
            int r = l >> 4, c = l & 15;
            int gm = m0 + r;
            int ar = QG ? (((gm >> 3) << 5) | (gm & 7)) : gm;
            Asl[r][c] = ldf(&A[(size_t)ar * K + k0 + c]);
        }
        #pragma unroll
        for (int i = 0; i < 4; ++i) {
            int l = tid * 4 + i;
            if (BT) {
                int n = l >> 4, kk = l & 15;
                int gn = n0 + n;
                Bsl[kk][n] = (gn < N) ? ldf(&B[(size_t)gn * K + k0 + kk]) : 0.f;
            } else {
                int r = l >> 6, c = l & 63;
                int gn = n0 + c;
                Bsl[r][c] = (gn < N) ? ldf(&B[(size_t)(k0 + r) * N + gn]) : 0.f;
            }
        }
        __syncthreads();
        #pragma unroll
        for (int kk = 0; kk < BK; ++kk) {
            float a[4], b[4];
            #pragma unroll
            for (int i = 0; i < 4; ++i) a[i] = Asl[ty + i * 16][kk];
            #pragma unroll
            for (int j = 0; j < 4; ++j) b[j] = Bsl[kk][tx + j * 16];
            #pragma unroll
            for (int i = 0; i < 4; ++i)
                #pragma unroll
                for (int j = 0; j < 4; ++j) acc[i][j] += a[i] * b[j];
        }
        __syncthreads();
    }

    #pragma unroll
    for (int i = 0; i < 4; ++i) {
        int gm = m0 + ty + i * 16;
        bool mz = false;
        if (MASKQ) {
            int a_ = gm & 7, t_ = (gm >> 3) & 63, b_ = gm >> 9;
            mz = smask[((b_ << 6) + t_) * 32 + a_] != 0;
        }
        #pragma unroll
        for (int j = 0; j < 4; ++j) {
            int gn = n0 + tx + j * 16;
            if (gn < N) {
                float v = acc[i][j] + bias[gn];
                if (ACT == 1) v = fmaxf(v, 0.f);
                if (MASKQ && mz) v = 0.f;
                stf(&C[(size_t)gm * N + gn], v);
            }
        }
    }
}

// ---------- attention: one wave per (b,t,h) ----------
__global__ __launch_bounds__(64) void attn_k(
    const bf16* __restrict__ qb, const bf16* __restrict__ kb, const bf16* __restrict__ vb,
    const int* __restrict__ obs, const int* __restrict__ smask, bf16* __restrict__ xs)
{
    __shared__ float qs[8 * 64], ks[32 * 64], vs[32 * 64], wsm[8 * 32];
    int bid = blockIdx.x;
    int h = bid & 7;
    int bt = bid >> 3;
    int t = bt & 63, b = bt >> 6;
    int tid = threadIdx.x;

    #pragma unroll
    for (int i = 0; i < 8; ++i) {
        int l = tid + i * 64;
        int e = l >> 6, d = l & 63;
        qs[l] = __bfloat162float(qb[((size_t)bt * 8 + e) * 512 + h * 64 + d]);
    }
    #pragma unroll
    for (int i = 0; i < 32; ++i) {
        int l = tid + i * 64;
        int e = l >> 6, d = l & 63;
        ks[l] = __bfloat162float(kb[((size_t)bt * 32 + e) * 512 + h * 64 + d]);
        vs[l] = __bfloat162float(vb[((size_t)bt * 32 + e) * 512 + h * 64 + d]);
    }
    __syncthreads();

    int ql = tid >> 3, jl = tid & 7;
    float s[4];
    #pragma unroll
    for (int c = 0; c < 4; ++c) {
        int kl = jl + c * 8;
        float acc = 0.f;
        for (int d = 0; d < 64; ++d) acc += qs[ql * 64 + d] * ks[kl * 64 + d];
        acc *= 0.125f;
        bool m = obs[(((size_t)bt * 32) + ql) * 32 + kl] != 0;
        s[c] = m ? -__builtin_inff() : acc;
    }
    float mx = fmaxf(fmaxf(s[0], s[1]), fmaxf(s[2], s[3]));
    for (int off = 1; off < 8; off <<= 1) mx = fmaxf(mx, __shfl_xor(mx, off));
    float e4[4]; float sum = 0.f;
    bool allmasked = (mx == -__builtin_inff());
    #pragma unroll
    for (int c = 0; c < 4; ++c) {
        e4[c] = (allmasked || s[c] == -__builtin_inff()) ? 0.f : expf(s[c] - mx);
        sum += e4[c];
    }
    for (int off = 1; off < 8; off <<= 1) sum += __shfl_xor(sum, off);
    float inv = (sum > 0.f) ? 1.f / sum : 0.f;
    #pragma unroll
    for (int c = 0; c < 4; ++c) wsm[ql * 32 + jl + c * 8] = e4[c] * inv;
    __syncthreads();

    bool amask = smask[(size_t)bt * 32 + ql] != 0;
    #pragma unroll
    for (int dd = 0; dd < 8; ++dd) {
        int d = jl + dd * 8;
        float acc = 0.f;
        for (int kl = 0; kl < 32; ++kl) acc += wsm[ql * 32 + kl] * vs[kl * 64 + d];
        if (amask) acc = 0.f;
        xs[((size_t)(t * 256 + b * 8 + ql)) * 512 + h * 64 + d] = __float2bfloat16(acc);
    }
}

// ---------- GRU v6: flag-based exchange (no atomic RMW), early gi prefetch ----------
// 256 WGs x 64 thr. WG g: grp=g&7 (rows grp*32..+32), cu=g>>3 (cols cu*16..+16).
// h via agent-scope relaxed atomics (bypass XCD L2); per-WG flag store + all-lane
// poll replaces the serializing atomicAdd counter.
struct GiRegs {
    float4 r0, z0, n0, r1, z1, n1;
    int m0[4], m1[4];
};
__device__ inline GiRegs load_gi(const float* __restrict__ gi2,
                                 const int* __restrict__ smask,
                                 int t, int row00, int row01, int hcol)
{
    GiRegs g;
    g.r0 = *(const float4*)(gi2 + ((size_t)t * 1536 + hcol)        * 256 + row00);
    g.z0 = *(const float4*)(gi2 + ((size_t)t * 1536 + 512 + hcol)  * 256 + row00);
    g.n0 = *(const float4*)(gi2 + ((size_t)t * 1536 + 1024 + hcol) * 256 + row00);
    g.r1 = *(const float4*)(gi2 + ((size_t)t * 1536 + hcol)        * 256 + row01);
    g.z1 = *(const float4*)(gi2 + ((size_t)t * 1536 + 512 + hcol)  * 256 + row01);
    g.n1 = *(const float4*)(gi2 + ((size_t)t * 1536 + 1024 + hcol) * 256 + row01);
    #pragma unroll
    for (int r = 0; r < 4; ++r) {
        int rowA = row00 + r, rowB = row01 + r;
        g.m0[r] = smask[(((rowA >> 3) << 6) + t) * 32 + (rowA & 7)];
        g.m1[r] = smask[(((rowB >> 3) << 6) + t) * 32 + (rowB & 7)];
    }
    return g;
}

__global__ __launch_bounds__(64, 1) void gru_xcd_k(
    const float* __restrict__ gi2, const float* __restrict__ Whh,
    const float* __restrict__ bhh, const float* __restrict__ h0,
    const int* __restrict__ smask, float* __restrict__ hs_out,
    _Float16* __restrict__ ha, _Float16* __restrict__ hb, int* __restrict__ flags)
{
    __shared__ _Float16 ws16[48 * 520];
    const int lane = threadIdx.x;
    const int g = blockIdx.x;
    const int grp = g & 7, cu = g >> 3;
    const int r0 = grp * 32;
    const int hc0 = cu * 16;
    const int fr = lane & 15, fq = lane >> 4;
    const int hcol = hc0 + fr;
    const int row00 = r0 + fq * 4;
    const int row01 = r0 + 16 + fq * 4;

    // stage w slice: LDS row j (0..47) = Whh[(j>>4)*512 + hc0 + (j&15)][0..512)
    for (int i = lane; i < 6144; i += 64) {
        int flat = i * 4;
        int r = flat >> 9, c = flat & 511;
        int wr = (r >> 4) * 512 + hc0 + (r & 15);
        float4 v = *(const float4*)(Whh + (size_t)wr * 512 + c);
        half2v p0; p0[0] = (_Float16)v.x; p0[1] = (_Float16)v.y;
        half2v p1; p1[0] = (_Float16)v.z; p1[1] = (_Float16)v.w;
        *(uint32_t*)&ws16[r * 520 + c]     = __builtin_bit_cast(uint32_t, p0);
        *(uint32_t*)&ws16[r * 520 + c + 2] = __builtin_bit_cast(uint32_t, p1);
    }

    const float bhr = bhh[hcol], bhz = bhh[512 + hcol], bhn = bhh[1024 + hcol];

    float hp[2][4];
    #pragma unroll
    for (int mt = 0; mt < 2; ++mt)
        #pragma unroll
        for (int r = 0; r < 4; ++r)
            hp[mt][r] = h0[(size_t)(r0 + mt * 16 + fq * 4 + r) * 512 + hcol];

    __syncthreads();   // w staged

    GiRegs gc = load_gi(gi2, smask, 0, row00, row01, hcol);

    for (int t = 0; t < 64; ++t) {
        const _Float16* hsrc = (t & 1) ? hb : ha;
        _Float16*       hdst = (t & 1) ? ha : hb;

        // A-slab via agent-scope relaxed 8B loads (bypass stale L1/L2)
        half8 aA[2][16];
        #pragma unroll
        for (int mt = 0; mt < 2; ++mt) {
            const unsigned long long* ap = (const unsigned long long*)
                (hsrc + (size_t)(r0 + mt * 16 + fr) * 512 + fq * 8);
            #pragma unroll
            for (int ks = 0; ks < 16; ++ks) {
                unsigned long long lo = __hip_atomic_load(ap + ks * 8,
                    __ATOMIC_RELAXED, __HIP_MEMORY_SCOPE_AGENT);
                unsigned long long hi = __hip_atomic_load(ap + ks * 8 + 1,
                    __ATOMIC_RELAXED, __HIP_MEMORY_SCOPE_AGENT);
                aA[mt][ks] = h8_from(lo, hi);
            }
        }
        // early gi/smask prefetch for t+1: completes under the MFMA phase,
        // so the post-gate vmcnt(0) drain is h-stores only
        GiRegs gn2;
        if (t != 63) gn2 = load_gi(gi2, smask, t + 1, row00, row01, hcol);

        f32x4 acc[2][3] = {};
        #pragma unroll
        for (int ks = 0; ks < 16; ++ks) {
            const _Float16* bbase = &ws16[fr * 520 + ks * 32 + fq * 8];
            half8 b0 = *(const half8*)(bbase);
            half8 b1 = *(const half8*)(bbase + 16 * 520);
            half8 b2 = *(const half8*)(bbase + 32 * 520);
            acc[0][0] = __builtin_amdgcn_mfma_f32_16x16x32_f16(aA[0][ks], b0, acc[0][0], 0, 0, 0);
            acc[0][1] = __builtin_amdgcn_mfma_f32_16x16x32_f16(aA[0][ks], b1, acc[0][1], 0, 0, 0);
            acc[0][2] = __builtin_amdgcn_mfma_f32_16x16x32_f16(aA[0][ks], b2, acc[0][2], 0, 0, 0);
            acc[1][0] = __builtin_amdgcn_mfma_f32_16x16x32_f16(aA[1][ks], b0, acc[1][0], 0, 0, 0);
            acc[1][1] = __builtin_amdgcn_mfma_f32_16x16x32_f16(aA[1][ks], b1, acc[1][1], 0, 0, 0);
            acc[1][2] = __builtin_amdgcn_mfma_f32_16x16x32_f16(aA[1][ks], b2, acc[1][2], 0, 0, 0);
        }

        float grA[2][4] = {{gc.r0.x, gc.r0.y, gc.r0.z, gc.r0.w}, {gc.r1.x, gc.r1.y, gc.r1.z, gc.r1.w}};
        float gzA[2][4] = {{gc.z0.x, gc.z0.y, gc.z0.z, gc.z0.w}, {gc.z1.x, gc.z1.y, gc.z1.z, gc.z1.w}};
        float gnA[2][4] = {{gc.n0.x, gc.n0.y, gc.n0.z, gc.n0.w}, {gc.n1.x, gc.n1.y, gc.n1.z, gc.n1.w}};
        float hnv[2][4];
        #pragma unroll
        for (int mt = 0; mt < 2; ++mt) {
            int grow0 = (mt == 0) ? row00 : row01;
            #pragma unroll
            for (int r = 0; r < 4; ++r) {
                float rg = 1.f / (1.f + expf(-(grA[mt][r] + acc[mt][0][r] + bhr)));
                float zg = 1.f / (1.f + expf(-(gzA[mt][r] + acc[mt][1][r] + bhz)));
                float ng = tanhf(gnA[mt][r] + rg * (acc[mt][2][r] + bhn));
                float hn = (1.f - zg) * ng + zg * hp[mt][r];
                hp[mt][r] = hn;
                hnv[mt][r] = hn;
                unsigned short hbits = __builtin_bit_cast(unsigned short, (_Float16)hn);
                __hip_atomic_store((unsigned short*)(hdst + (size_t)(grow0 + r) * 512 + hcol),
                                   hbits, __ATOMIC_RELAXED, __HIP_MEMORY_SCOPE_AGENT);
            }
        }

        if (t != 63) {
            // drain h stores, then signal via per-WG flag (no RMW serialization)
            asm volatile("s_waitcnt vmcnt(0)" ::: "memory");
            __builtin_amdgcn_sched_barrier(0);
            if (lane == 0)
                __hip_atomic_store(flags + ((size_t)grp * 64 + t) * 32 + cu, 1,
                                   __ATOMIC_RELAXED, __HIP_MEMORY_SCOPE_AGENT);
            // overlap: hs_out stores during the wait
            #pragma unroll
            for (int mt = 0; mt < 2; ++mt) {
                int grow0 = (mt == 0) ? row00 : row01;
                #pragma unroll
                for (int r = 0; r < 4; ++r) {
                    int row = grow0 + r;
                    int b_ = row >> 3, a_ = row & 7;
                    bool msk = ((mt == 0) ? gc.m0[r] : gc.m1[r]) != 0;
                    hs_out[((size_t)((b_ << 6) + t) * 8 + a_) * 512 + hcol] =
                        msk ? 0.f : hnv[mt][r];
                }
            }
            // all-lane poll of 32 flags
            const int* fp = flags + ((size_t)grp * 64 + t) * 32 + (lane & 31);
            long it = 0;
            for (;;) {
                int f = __hip_atomic_load(fp, __ATOMIC_RELAXED, __HIP_MEMORY_SCOPE_AGENT);
                if (__all(f != 0) || it > 100000000L) break;
                __builtin_amdgcn_s_sleep(1);
                ++it;
            }
            __builtin_amdgcn_sched_barrier(0);
            gc = gn2;
        } else {
            #pragma unroll
            for (int mt = 0; mt < 2; ++mt) {
                int grow0 = (mt == 0) ? row00 : row01;
                #pragma unroll
                for (int r = 0; r < 4; ++r) {
                    int row = grow0 + r;
                    int b_ = row >> 3, a_ = row & 7;
                    bool msk = ((mt == 0) ? gc.m0[r] : gc.m1[r]) != 0;
                    hs_out[((size_t)((b_ << 6) + t) * 8 + a_) * 512 + hcol] =
                        msk ? 0.f : hnv[mt][r];
                }
            }
        }
    }
}

// ---------- launch ----------
extern "C" void kernel_launch(void* const* d_in, const int* in_sizes, int n_in,
                              void* d_out, int out_size, void* d_ws, size_t ws_size,
                              hipStream_t stream)
{
    const float* inputs = (const float*)d_in[0];
    const int*   obs    = (const int*)d_in[1];
    const int*   smask  = (const int*)d_in[2];
    const float* h0     = (const float*)d_in[3];
    const float* W1  = (const float*)d_in[4];  const float* b1  = (const float*)d_in[5];
    const float* Wq  = (const float*)d_in[6];  const float* bq  = (const float*)d_in[7];
    const float* Wk  = (const float*)d_in[8];  const float* bk  = (const float*)d_in[9];
    const float* Wv  = (const float*)d_in[10]; const float* bv  = (const float*)d_in[11];
    const float* Wih = (const float*)d_in[12]; const float* bih = (const float*)d_in[13];
    const float* Whh = (const float*)d_in[14]; const float* bhh = (const float*)d_in[15];
    const float* Wo  = (const float*)d_in[16]; const float* bo  = (const float*)d_in[17];

    char* ws = (char*)d_ws;
    bf16*  x    = (bf16*)(ws + 0);
    bf16*  xs   = (bf16*)(ws + 0);
    bf16*  qb   = (bf16*)(ws + 67108864ull);
    bf16*  kb   = (bf16*)(ws + 83886080ull);
    bf16*  vb   = (bf16*)(ws + 150994944ull);
    float* gi2  = (float*)(ws + 16777216ull);
    bf16*  Wihb = (bf16*)(ws + 119013376ull);
    bf16*  W1t  = (bf16*)(ws + 218103808ull);
    bf16*  Wqt  = (bf16*)(ws + 218234880ull);
    bf16*  Wkt  = (bf16*)(ws + 218759168ull);
    bf16*  Wvt  = (bf16*)(ws + 219283456ull);
    _Float16* ha = (_Float16*)(ws + 219807744ull);   // 256 KB
    _Float16* hb = (_Float16*)(ws + 220069888ull);   // 256 KB
    int*   flags = (int*)(ws + 220332032ull);        // 8 grp x 64 t x 32 cu = 64 KB

    float* out    = (float*)d_out;
    float* hs_out = out + 524288;

    hipMemsetAsync(flags, 0, 65536, stream);

    // 0. weight prep
    tconv_k<<<dim3(256), 256, 0, stream>>>(W1, W1t, 128, 512);
    tconv_k<<<dim3(1024), 256, 0, stream>>>(Wq, Wqt, 512, 512);
    tconv_k<<<dim3(1024), 256, 0, stream>>>(Wk, Wkt, 512, 512);
    tconv_k<<<dim3(1024), 256, 0, stream>>>(Wv, Wvt, 512, 512);
    conv_f16_k<<<dim3(512), 256, 0, stream>>>(h0, ha, 131072);
    // 1. fc1
    mfma_gemm_k<1, false, false, float, bf16><<<dim3(4, 512), 256, 0, stream>>>(
        inputs, W1t, b1, x, 65536, 512, 128);
    // 2-4. projections
    mfma_gemm_k<0, true, false, bf16, bf16><<<dim3(4, 128), 256, 0, stream>>>(
        x, Wqt, bq, qb, 16384, 512, 512);
    mfma_gemm_k<0, false, false, bf16, bf16><<<dim3(4, 512), 256, 0, stream>>>(
        x, Wkt, bk, kb, 65536, 512, 512);
    mfma_gemm_k<1, false, false, bf16, bf16><<<dim3(4, 512), 256, 0, stream>>>(
        x, Wvt, bv, vb, 65536, 512, 512);
    // 5. attention -> xs bf16 (x dead)
    attn_k<<<dim3(16384), 64, 0, stream>>>(qb, kb, vb, obs, smask, xs);
    // 5b. Wih -> bf16
    conv_k<<<dim3(3072), 256, 0, stream>>>(Wih, Wihb, 1536 * 512);
    // 6. gi2 = (xs @ Wih^T + bih), stored transposed [t][gatecol][row]
    mfma_gemm_k<0, false, true, bf16, float><<<dim3(12, 128), 256, 0, stream>>>(
        xs, Wihb, bih, gi2, 16384, 1536, 512);
    // 7. GRU v6: flag-based exchange
    gru_xcd_k<<<dim3(256), 64, 0, stream>>>(
        gi2, Whh, bhh, h0, smask, hs_out, ha, hb, flags);
    // 8. qout
    gemm_k<0, false, false, true><<<dim3(1, 256), 256, 0, stream>>>(
        hs_out, Wo, bo, out, 16384, 32, 512, smask);
}

// Round 11
// 799.725 us; speedup vs baseline: 8.8539x; 1.1254x over previous
//
#include <hip/hip_runtime.h>
#include <hip/hip_bf16.h>
#include <cstddef>
#include <cstdint>

typedef __hip_bfloat16 bf16;
typedef __attribute__((ext_vector_type(2))) _Float16 half2v;
typedef __attribute__((ext_vector_type(8))) _Float16 half8;
typedef __attribute__((ext_vector_type(8))) short short8;
typedef __attribute__((ext_vector_type(4))) float f32x4;
typedef __attribute__((ext_vector_type(2))) unsigned long long u64x2;

// ---------- helpers ----------
__device__ inline float ldf(const float* p) { return *p; }
__device__ inline float ldf(const bf16* p) { return __bfloat162float(*p); }
__device__ inline void stf(float* p, float v) { *p = v; }
__device__ inline void stf(bf16* p, float v) { *p = __float2bfloat16(v); }
__device__ inline short bfb(float v) { return __builtin_bit_cast(short, __float2bfloat16(v)); }

__device__ inline half8 h8_from(unsigned long long lo, unsigned long long hi) {
    u64x2 t; t.x = lo; t.y = hi;
    return __builtin_bit_cast(half8, t);
}
// fast gates: v_exp_f32 path, clamped
__device__ inline float fsig(float x) {
    x = fminf(fmaxf(x, -60.f), 60.f);
    return 1.f / (1.f + __expf(-x));
}
__device__ inline float ftanh(float x) {
    x = fminf(fmaxf(x, -15.f), 15.f);
    float e = __expf(2.f * x);
    return 1.f - 2.f / (e + 1.f);
}

// Problem constants: BS=32, T=64, NE=32, NA=8, ED=128, H=512, A=512, NH=8, HD=64, NACT=32

// ---------- MFMA bf16 GEMM: C[M,N] = act(A[M,K] @ Bt[N,K]^T + bias) ----------
// ACT: 0 none, 1 relu, 2 relu iff col>=512 (fused k|v). GI2: transposed f32 store.
template<int ACT, bool QG, bool GI2, typename TA, typename TC>
__global__ __launch_bounds__(256) void mfma_gemm_k(
    const TA* __restrict__ A, const bf16* __restrict__ Bt,
    const float* __restrict__ bias, TC* __restrict__ C,
    int M, int N, int K)
{
    __shared__ short As[4096];   // [128][32] linear
    __shared__ short Bs[4096];
    const int tid = threadIdx.x;
    const int lane = tid & 63, wid = tid >> 6;
    const int wm = wid >> 1, wn = wid & 1;
    const int bm = blockIdx.y * 128, bn = blockIdx.x * 128;
    const int fr = lane & 15, fq = lane >> 4;

    f32x4 acc[4][4] = {};

    for (int k0 = 0; k0 < K; k0 += 32) {
#if __has_builtin(__builtin_amdgcn_global_load_lds)
        #pragma unroll
        for (int j = 0; j < 2; ++j) {
            int jj = wid * 2 + j;
            int row = jj * 16 + (lane >> 2);
            const short* src = (const short*)Bt + (size_t)(bn + row) * K + k0 + (lane & 3) * 8;
            __builtin_amdgcn_global_load_lds(
                (const __attribute__((address_space(1))) void*)src,
                (__attribute__((address_space(3))) void*)&Bs[jj * 512], 16, 0, 0);
        }
        if constexpr (sizeof(TA) == 2) {
            #pragma unroll
            for (int j = 0; j < 2; ++j) {
                int jj = wid * 2 + j;
                int row = jj * 16 + (lane >> 2);
                int gm = bm + row;
                int ar = QG ? (((gm >> 3) << 5) | (gm & 7)) : gm;
                const short* src = (const short*)A + (size_t)ar * K + k0 + (lane & 3) * 8;
                __builtin_amdgcn_global_load_lds(
                    (const __attribute__((address_space(1))) void*)src,
                    (__attribute__((address_space(3))) void*)&As[jj * 512], 16, 0, 0);
            }
        } else {
            int sr = tid >> 1, sk = (tid & 1) * 16;
            int gm = bm + sr;
            int ar = QG ? (((gm >> 3) << 5) | (gm & 7)) : gm;
            const float* ap = (const float*)A + (size_t)ar * K + k0 + sk;
            short tmp[16];
            #pragma unroll
            for (int j = 0; j < 16; ++j) tmp[j] = bfb(ap[j]);
            *(uint4*)&As[sr * 32 + sk]     = *(const uint4*)&tmp[0];
            *(uint4*)&As[sr * 32 + sk + 8] = *(const uint4*)&tmp[8];
        }
#else
        {
            int sr = tid >> 1, sk = (tid & 1) * 16;
            int gm = bm + sr;
            int ar = QG ? (((gm >> 3) << 5) | (gm & 7)) : gm;
            if constexpr (sizeof(TA) == 4) {
                const float* ap = (const float*)A + (size_t)ar * K + k0 + sk;
                short tmp[16];
                #pragma unroll
                for (int j = 0; j < 16; ++j) tmp[j] = bfb(ap[j]);
                *(uint4*)&As[sr * 32 + sk]     = *(const uint4*)&tmp[0];
                *(uint4*)&As[sr * 32 + sk + 8] = *(const uint4*)&tmp[8];
            } else {
                const short* ap = (const short*)A + (size_t)ar * K + k0 + sk;
                *(uint4*)&As[sr * 32 + sk]     = *(const uint4*)(ap);
                *(uint4*)&As[sr * 32 + sk + 8] = *(const uint4*)(ap + 8);
            }
            const short* bp = (const short*)Bt + (size_t)(bn + sr) * K + k0 + sk;
            *(uint4*)&Bs[sr * 32 + sk]     = *(const uint4*)(bp);
            *(uint4*)&Bs[sr * 32 + sk + 8] = *(const uint4*)(bp + 8);
        }
#endif
        __syncthreads();

        short8 af[4], bg[4];
        #pragma unroll
        for (int m = 0; m < 4; ++m)
            af[m] = *(const short8*)&As[(wm * 64 + m * 16 + fr) * 32 + fq * 8];
        #pragma unroll
        for (int n = 0; n < 4; ++n)
            bg[n] = *(const short8*)&Bs[(wn * 64 + n * 16 + fr) * 32 + fq * 8];
        #pragma unroll
        for (int m = 0; m < 4; ++m)
            #pragma unroll
            for (int n = 0; n < 4; ++n)
                acc[m][n] = __builtin_amdgcn_mfma_f32_16x16x32_bf16(
                    af[m], bg[n], acc[m][n], 0, 0, 0);
        __syncthreads();
    }

    #pragma unroll
    for (int m = 0; m < 4; ++m) {
        #pragma unroll
        for (int n = 0; n < 4; ++n) {
            int col = bn + wn * 64 + n * 16 + fr;
            float bv = bias[col];
            if constexpr (GI2) {
                int gm0 = bm + wm * 64 + m * 16 + fq * 4;
                float4 v = make_float4(acc[m][n][0] + bv, acc[m][n][1] + bv,
                                       acc[m][n][2] + bv, acc[m][n][3] + bv);
                *(float4*)((float*)C + ((size_t)(gm0 >> 8) * 1536 + col) * 256 + (gm0 & 255)) = v;
            } else {
                #pragma unroll
                for (int r = 0; r < 4; ++r) {
                    int row = bm + wm * 64 + m * 16 + fq * 4 + r;
                    float v = acc[m][n][r] + bv;
                    if (ACT == 1) v = fmaxf(v, 0.f);
                    if (ACT == 2 && col >= 512) v = fmaxf(v, 0.f);
                    stf(&C[(size_t)row * N + col], v);
                }
            }
        }
    }
}

// ---------- merged prep (NO Wihb here: its region overlaps kv and must be
// converted AFTER attn — see launch; round-10 bug) ----------
__global__ __launch_bounds__(256) void prep_all_k(
    const float* __restrict__ W1, const float* __restrict__ Wq,
    const float* __restrict__ Wk, const float* __restrict__ Wv,
    const float* __restrict__ h0,
    const float* __restrict__ bk, const float* __restrict__ bv,
    bf16* __restrict__ W1t, bf16* __restrict__ Wqt, bf16* __restrict__ Wkvt,
    _Float16* __restrict__ ha, float* __restrict__ bkv)
{
    int idx = blockIdx.x * 256 + threadIdx.x;
    if (idx < 65536) {                       // W1t[n][k] = W1[k][n], K=128
        int n = idx >> 7, k = idx & 127;
        W1t[idx] = __float2bfloat16(W1[(size_t)k * 512 + n]); return;
    }
    idx -= 65536;
    if (idx < 262144) {                      // Wqt[n][k] = Wq[k][n]
        int n = idx >> 9, k = idx & 511;
        Wqt[idx] = __float2bfloat16(Wq[(size_t)k * 512 + n]); return;
    }
    idx -= 262144;
    if (idx < 524288) {                      // Wkvt[n][k]: n<512 from Wk, else Wv
        int n = idx >> 9, k = idx & 511;
        float v = (n < 512) ? Wk[(size_t)k * 512 + n] : Wv[(size_t)k * 512 + (n - 512)];
        Wkvt[idx] = __float2bfloat16(v); return;
    }
    idx -= 524288;
    if (idx < 131072) { ha[idx] = (_Float16)h0[idx]; return; }
    idx -= 131072;
    if (idx < 1024) { bkv[idx] = (idx < 512) ? bk[idx] : bv[idx - 512]; return; }
}

__global__ __launch_bounds__(256) void conv_k(
    const float* __restrict__ in, bf16* __restrict__ out, int n)
{
    int i = blockIdx.x * 256 + threadIdx.x;
    if (i < n) out[i] = __float2bfloat16(in[i]);
}

// ---------- legacy VALU GEMM (qout only: N=32) ----------
template<int ACT, bool BT, bool QG, bool MASKQ, typename TA, typename TB, typename TC>
__global__ __launch_bounds__(256) void gemm_k(
    const TA* __restrict__ A, const TB* __restrict__ B,
    const float* __restrict__ bias, TC* __restrict__ C,
    int M, int N, int K, const int* __restrict__ smask)
{
    const int BM = 64, BN = 64, BK = 16;
    __shared__ float Asl[BM][BK + 1];
    __shared__ float Bsl[BK][BN + 1];
    int tid = threadIdx.x;
    int n0 = blockIdx.x * BN;
    int m0 = blockIdx.y * BM;
    int ty = tid >> 4, tx = tid & 15;
    float acc[4][4] = {};

    for (int k0 = 0; k0 < K; k0 += BK) {
        #pragma unroll
        for (int i = 0; i < 4; ++i) {
            int l = tid * 4 + i;
            int r = l >> 4, c = l & 15;
            int gm = m0 + r;
            int ar = QG ? (((gm >> 3) << 5) | (gm & 7)) : gm;
            Asl[r][c] = ldf(&A[(size_t)ar * K + k0 + c]);
        }
        #pragma unroll
        for (int i = 0; i < 4; ++i) {
            int l = tid * 4 + i;
            if (BT) {
                int n = l >> 4, kk = l & 15;
                int gn = n0 + n;
                Bsl[kk][n] = (gn < N) ? ldf(&B[(size_t)gn * K + k0 + kk]) : 0.f;
            } else {
                int r = l >> 6, c = l & 63;
                int gn = n0 + c;
                Bsl[r][c] = (gn < N) ? ldf(&B[(size_t)(k0 + r) * N + gn]) : 0.f;
            }
        }
        __syncthreads();
        #pragma unroll
        for (int kk = 0; kk < BK; ++kk) {
            float a[4], b[4];
            #pragma unroll
            for (int i = 0; i < 4; ++i) a[i] = Asl[ty + i * 16][kk];
            #pragma unroll
            for (int j = 0; j < 4; ++j) b[j] = Bsl[kk][tx + j * 16];
            #pragma unroll
            for (int i = 0; i < 4; ++i)
                #pragma unroll
                for (int j = 0; j < 4; ++j) acc[i][j] += a[i] * b[j];
        }
        __syncthreads();
    }

    #pragma unroll
    for (int i = 0; i < 4; ++i) {
        int gm = m0 + ty + i * 16;
        bool mz = false;
        if (MASKQ) {
            int a_ = gm & 7, t_ = (gm >> 3) & 63, b_ = gm >> 9;
            mz = smask[((b_ << 6) + t_) * 32 + a_] != 0;
        }
        #pragma unroll
        for (int j = 0; j < 4; ++j) {
            int gn = n0 + tx + j * 16;
            if (gn < N) {
                float v = acc[i][j] + bias[gn];
                if (ACT == 1) v = fmaxf(v, 0.f);
                if (MASKQ && mz) v = 0.f;
                stf(&C[(size_t)gm * N + gn], v);
            }
        }
    }
}

// ---------- attention: one wave per (b,t,h); k/v row-stride parameterized ----------
__global__ __launch_bounds__(64) void attn_k(
    const bf16* __restrict__ qb, const bf16* __restrict__ kb, const bf16* __restrict__ vb,
    const int* __restrict__ obs, const int* __restrict__ smask, bf16* __restrict__ xs,
    int kvstride)
{
    __shared__ float qs[8 * 64], ks[32 * 64], vs[32 * 64], wsm[8 * 32];
    int bid = blockIdx.x;
    int h = bid & 7;
    int bt = bid >> 3;
    int t = bt & 63, b = bt >> 6;
    int tid = threadIdx.x;

    #pragma unroll
    for (int i = 0; i < 8; ++i) {
        int l = tid + i * 64;
        int e = l >> 6, d = l & 63;
        qs[l] = __bfloat162float(qb[((size_t)bt * 8 + e) * 512 + h * 64 + d]);
    }
    #pragma unroll
    for (int i = 0; i < 32; ++i) {
        int l = tid + i * 64;
        int e = l >> 6, d = l & 63;
        ks[l] = __bfloat162float(kb[((size_t)bt * 32 + e) * kvstride + h * 64 + d]);
        vs[l] = __bfloat162float(vb[((size_t)bt * 32 + e) * kvstride + h * 64 + d]);
    }
    __syncthreads();

    int ql = tid >> 3, jl = tid & 7;
    float s[4];
    #pragma unroll
    for (int c = 0; c < 4; ++c) {
        int kl = jl + c * 8;
        float acc = 0.f;
        for (int d = 0; d < 64; ++d) acc += qs[ql * 64 + d] * ks[kl * 64 + d];
        acc *= 0.125f;
        bool m = obs[(((size_t)bt * 32) + ql) * 32 + kl] != 0;
        s[c] = m ? -__builtin_inff() : acc;
    }
    float mx = fmaxf(fmaxf(s[0], s[1]), fmaxf(s[2], s[3]));
    for (int off = 1; off < 8; off <<= 1) mx = fmaxf(mx, __shfl_xor(mx, off));
    float e4[4]; float sum = 0.f;
    bool allmasked = (mx == -__builtin_inff());
    #pragma unroll
    for (int c = 0; c < 4; ++c) {
        e4[c] = (allmasked || s[c] == -__builtin_inff()) ? 0.f : expf(s[c] - mx);
        sum += e4[c];
    }
    for (int off = 1; off < 8; off <<= 1) sum += __shfl_xor(sum, off);
    float inv = (sum > 0.f) ? 1.f / sum : 0.f;
    #pragma unroll
    for (int c = 0; c < 4; ++c) wsm[ql * 32 + jl + c * 8] = e4[c] * inv;
    __syncthreads();

    bool amask = smask[(size_t)bt * 32 + ql] != 0;
    #pragma unroll
    for (int dd = 0; dd < 8; ++dd) {
        int d = jl + dd * 8;
        float acc = 0.f;
        for (int kl = 0; kl < 32; ++kl) acc += wsm[ql * 32 + kl] * vs[kl * 64 + d];
        if (amask) acc = 0.f;
        xs[((size_t)(t * 256 + b * 8 + ql)) * 512 + h * 64 + d] = __float2bfloat16(acc);
    }
}

// ---------- GRU v7: 2 waves/WG (mt-split), fast gates, flag exchange ----------
struct GiR { float4 r, z, n; int m[4]; };
__device__ inline GiR load_gi(const float* __restrict__ gi2,
                              const int* __restrict__ smask,
                              int t, int row0, int hcol)
{
    GiR g;
    g.r = *(const float4*)(gi2 + ((size_t)t * 1536 + hcol)        * 256 + row0);
    g.z = *(const float4*)(gi2 + ((size_t)t * 1536 + 512 + hcol)  * 256 + row0);
    g.n = *(const float4*)(gi2 + ((size_t)t * 1536 + 1024 + hcol) * 256 + row0);
    #pragma unroll
    for (int r = 0; r < 4; ++r) {
        int row = row0 + r;
        g.m[r] = smask[(((row >> 3) << 6) + t) * 32 + (row & 7)];
    }
    return g;
}

__global__ __launch_bounds__(128, 1) void gru_xcd_k(
    const float* __restrict__ gi2, const float* __restrict__ Whh,
    const float* __restrict__ bhh, const float* __restrict__ h0,
    const int* __restrict__ smask, float* __restrict__ hs_out,
    _Float16* __restrict__ ha, _Float16* __restrict__ hb, int* __restrict__ flags)
{
    __shared__ _Float16 ws16[48 * 520];
    const int tid = threadIdx.x;
    const int lane = tid & 63, wid = tid >> 6;
    const int g = blockIdx.x;
    const int grp = g & 7, cu = g >> 3;
    const int r0 = grp * 32;
    const int hc0 = cu * 16;
    const int fr = lane & 15, fq = lane >> 4;
    const int hcol = hc0 + fr;
    const int rw0 = r0 + wid * 16;       // wave's 16-row base
    const int row0 = rw0 + fq * 4;       // lane's 4 C-rows

    for (int i = tid; i < 6144; i += 128) {
        int flat = i * 4;
        int r = flat >> 9, c = flat & 511;
        int wr = (r >> 4) * 512 + hc0 + (r & 15);
        float4 v = *(const float4*)(Whh + (size_t)wr * 512 + c);
        half2v p0; p0[0] = (_Float16)v.x; p0[1] = (_Float16)v.y;
        half2v p1; p1[0] = (_Float16)v.z; p1[1] = (_Float16)v.w;
        *(uint32_t*)&ws16[r * 520 + c]     = __builtin_bit_cast(uint32_t, p0);
        *(uint32_t*)&ws16[r * 520 + c + 2] = __builtin_bit_cast(uint32_t, p1);
    }

    const float bhr = bhh[hcol], bhz = bhh[512 + hcol], bhn = bhh[1024 + hcol];

    float hp[4];
    #pragma unroll
    for (int r = 0; r < 4; ++r)
        hp[r] = h0[(size_t)(row0 + r) * 512 + hcol];

    __syncthreads();   // w staged

    GiR gc = load_gi(gi2, smask, 0, row0, hcol);

    for (int t = 0; t < 64; ++t) {
        const _Float16* hsrc = (t & 1) ? hb : ha;
        _Float16*       hdst = (t & 1) ? ha : hb;

        half8 aA[16];
        {
            const unsigned long long* ap = (const unsigned long long*)
                (hsrc + (size_t)(rw0 + fr) * 512 + fq * 8);
            #pragma unroll
            for (int ks = 0; ks < 16; ++ks) {
                unsigned long long lo = __hip_atomic_load(ap + ks * 8,
                    __ATOMIC_RELAXED, __HIP_MEMORY_SCOPE_AGENT);
                unsigned long long hi = __hip_atomic_load(ap + ks * 8 + 1,
                    __ATOMIC_RELAXED, __HIP_MEMORY_SCOPE_AGENT);
                aA[ks] = h8_from(lo, hi);
            }
        }
        GiR gn2;
        if (t != 63) gn2 = load_gi(gi2, smask, t + 1, row0, hcol);

        f32x4 acc[3] = {};
        #pragma unroll
        for (int ks = 0; ks < 16; ++ks) {
            const _Float16* bbase = &ws16[fr * 520 + ks * 32 + fq * 8];
            half8 b0 = *(const half8*)(bbase);
            half8 b1 = *(const half8*)(bbase + 16 * 520);
            half8 b2 = *(const half8*)(bbase + 32 * 520);
            acc[0] = __builtin_amdgcn_mfma_f32_16x16x32_f16(aA[ks], b0, acc[0], 0, 0, 0);
            acc[1] = __builtin_amdgcn_mfma_f32_16x16x32_f16(aA[ks], b1, acc[1], 0, 0, 0);
            acc[2] = __builtin_amdgcn_mfma_f32_16x16x32_f16(aA[ks], b2, acc[2], 0, 0, 0);
        }

        float grA[4] = {gc.r.x, gc.r.y, gc.r.z, gc.r.w};
        float gzA[4] = {gc.z.x, gc.z.y, gc.z.z, gc.z.w};
        float gnA[4] = {gc.n.x, gc.n.y, gc.n.z, gc.n.w};
        float hnv[4];
        #pragma unroll
        for (int r = 0; r < 4; ++r) {
            float rg = fsig(grA[r] + acc[0][r] + bhr);
            float zg = fsig(gzA[r] + acc[1][r] + bhz);
            float ng = ftanh(gnA[r] + rg * (acc[2][r] + bhn));
            float hn = (1.f - zg) * ng + zg * hp[r];
            hp[r] = hn;
            hnv[r] = hn;
            unsigned short hbits = __builtin_bit_cast(unsigned short, (_Float16)hn);
            __hip_atomic_store((unsigned short*)(hdst + (size_t)(row0 + r) * 512 + hcol),
                               hbits, __ATOMIC_RELAXED, __HIP_MEMORY_SCOPE_AGENT);
        }

        if (t != 63) {
            asm volatile("s_waitcnt vmcnt(0)" ::: "memory");   // drain this wave's h-stores
            __builtin_amdgcn_sched_barrier(0);
            __syncthreads();                                    // both waves drained
            if (tid == 0)
                __hip_atomic_store(flags + ((size_t)grp * 64 + t) * 32 + cu, 1,
                                   __ATOMIC_RELAXED, __HIP_MEMORY_SCOPE_AGENT);
            #pragma unroll
            for (int r = 0; r < 4; ++r) {
                int row = row0 + r;
                int b_ = row >> 3, a_ = row & 7;
                hs_out[((size_t)((b_ << 6) + t) * 8 + a_) * 512 + hcol] =
                    gc.m[r] ? 0.f : hnv[r];
            }
            const int* fp = flags + ((size_t)grp * 64 + t) * 32 + (lane & 31);
            long it = 0;
            for (;;) {
                int f = __hip_atomic_load(fp, __ATOMIC_RELAXED, __HIP_MEMORY_SCOPE_AGENT);
                if (__all(f != 0) || it > 100000000L) break;
                __builtin_amdgcn_s_sleep(1);
                ++it;
            }
            __builtin_amdgcn_sched_barrier(0);
            gc = gn2;
        } else {
            #pragma unroll
            for (int r = 0; r < 4; ++r) {
                int row = row0 + r;
                int b_ = row >> 3, a_ = row & 7;
                hs_out[((size_t)((b_ << 6) + t) * 8 + a_) * 512 + hcol] =
                    gc.m[r] ? 0.f : hnv[r];
            }
        }
    }
}

// ---------- launch ----------
extern "C" void kernel_launch(void* const* d_in, const int* in_sizes, int n_in,
                              void* d_out, int out_size, void* d_ws, size_t ws_size,
                              hipStream_t stream)
{
    const float* inputs = (const float*)d_in[0];
    const int*   obs    = (const int*)d_in[1];
    const int*   smask  = (const int*)d_in[2];
    const float* h0     = (const float*)d_in[3];
    const float* W1  = (const float*)d_in[4];  const float* b1  = (const float*)d_in[5];
    const float* Wq  = (const float*)d_in[6];  const float* bq  = (const float*)d_in[7];
    const float* Wk  = (const float*)d_in[8];  const float* bk  = (const float*)d_in[9];
    const float* Wv  = (const float*)d_in[10]; const float* bv  = (const float*)d_in[11];
    const float* Wih = (const float*)d_in[12]; const float* bih = (const float*)d_in[13];
    const float* Whh = (const float*)d_in[14]; const float* bhh = (const float*)d_in[15];
    const float* Wo  = (const float*)d_in[16]; const float* bo  = (const float*)d_in[17];

    char* ws = (char*)d_ws;
    // x [0,64M) -> xs [0,16M); qb [64,80M); kv [80,208M) (k|v packed, stride 1024);
    // gi2 [16,112M) (kv dead after attn); Wihb [113.5,115M) — inside kv span, so
    // converted AFTER attn (round-10 bug fix); W1t/Wqt/Wkvt [208,209.7M);
    // ha/hb [209.7,210.3M); flags; bkv.
    bf16*  x    = (bf16*)(ws + 0);
    bf16*  xs   = (bf16*)(ws + 0);
    bf16*  qb   = (bf16*)(ws + 67108864ull);
    bf16*  kv   = (bf16*)(ws + 83886080ull);       // 128 MB
    float* gi2  = (float*)(ws + 16777216ull);
    bf16*  Wihb = (bf16*)(ws + 119013376ull);
    bf16*  W1t  = (bf16*)(ws + 218103808ull);      // 128 KB
    bf16*  Wqt  = (bf16*)(ws + 218234880ull);      // 512 KB
    bf16*  Wkvt = (bf16*)(ws + 218759168ull);      // 1 MB
    _Float16* ha = (_Float16*)(ws + 219807744ull); // 256 KB
    _Float16* hb = (_Float16*)(ws + 220069888ull); // 256 KB
    int*   flags = (int*)(ws + 220332032ull);      // 64 KB
    float* bkv   = (float*)(ws + 220397568ull);    // 4 KB

    float* out    = (float*)d_out;
    float* hs_out = out + 524288;

    hipMemsetAsync(flags, 0, 65536, stream);

    // 0. merged prep (984,064 items; Wihb excluded — its region overlaps kv)
    prep_all_k<<<dim3(3844), 256, 0, stream>>>(
        W1, Wq, Wk, Wv, h0, bk, bv, W1t, Wqt, Wkvt, ha, bkv);
    // 1. fc1
    mfma_gemm_k<1, false, false, float, bf16><<<dim3(4, 512), 256, 0, stream>>>(
        inputs, W1t, b1, x, 65536, 512, 128);
    // 2. q (gathered agent rows)
    mfma_gemm_k<0, true, false, bf16, bf16><<<dim3(4, 128), 256, 0, stream>>>(
        x, Wqt, bq, qb, 16384, 512, 512);
    // 3. fused k|v (relu on v-half)
    mfma_gemm_k<2, false, false, bf16, bf16><<<dim3(8, 512), 256, 0, stream>>>(
        x, Wkvt, bkv, kv, 65536, 1024, 512);
    // 4. attention -> xs bf16 (x dead); k/v stride 1024
    attn_k<<<dim3(16384), 64, 0, stream>>>(qb, kv, kv + 512, obs, smask, xs, 1024);
    // 4b. Wih -> bf16 (AFTER attn: kv dead, Wihb region safe now)
    conv_k<<<dim3(3072), 256, 0, stream>>>(Wih, Wihb, 1536 * 512);
    // 5. gi2 = (xs @ Wih^T + bih), transposed store
    mfma_gemm_k<0, false, true, bf16, float><<<dim3(12, 128), 256, 0, stream>>>(
        xs, Wihb, bih, gi2, 16384, 1536, 512);
    // 6. GRU v7: 2-wave WGs, fast gates
    gru_xcd_k<<<dim3(256), 128, 0, stream>>>(
        gi2, Whh, bhh, h0, smask, hs_out, ha, hb, flags);
    // 7. qout
    gemm_k<0, false, false, true><<<dim3(1, 256), 256, 0, stream>>>(
        hs_out, Wo, bo, out, 16384, 32, 512, smask);
}

// Round 12
// 774.513 us; speedup vs baseline: 9.1422x; 1.0326x over previous
//
#include <hip/hip_runtime.h>
#include <hip/hip_bf16.h>
#include <cstddef>
#include <cstdint>

typedef __hip_bfloat16 bf16;
typedef __attribute__((ext_vector_type(2))) _Float16 half2v;
typedef __attribute__((ext_vector_type(8))) _Float16 half8;
typedef __attribute__((ext_vector_type(8))) short short8;
typedef __attribute__((ext_vector_type(4))) float f32x4;
typedef __attribute__((ext_vector_type(2))) unsigned long long u64x2;

// ---------- helpers ----------
__device__ inline float ldf(const float* p) { return *p; }
__device__ inline float ldf(const bf16* p) { return __bfloat162float(*p); }
__device__ inline void stf(float* p, float v) { *p = v; }
__device__ inline void stf(bf16* p, float v) { *p = __float2bfloat16(v); }
__device__ inline short bfb(float v) { return __builtin_bit_cast(short, __float2bfloat16(v)); }

__device__ inline half8 h8_from(unsigned long long lo, unsigned long long hi) {
    u64x2 t; t.x = lo; t.y = hi;
    return __builtin_bit_cast(half8, t);
}
// fast gates: v_exp_f32 path, clamped
__device__ inline float fsig(float x) {
    x = fminf(fmaxf(x, -60.f), 60.f);
    return 1.f / (1.f + __expf(-x));
}
__device__ inline float ftanh(float x) {
    x = fminf(fmaxf(x, -15.f), 15.f);
    float e = __expf(2.f * x);
    return 1.f - 2.f / (e + 1.f);
}

// Problem constants: BS=32, T=64, NE=32, NA=8, ED=128, H=512, A=512, NH=8, HD=64, NACT=32

// ---------- MFMA bf16 GEMM: C[M,N] = act(A[M,K] @ Bt[N,K]^T + bias) ----------
// ACT: 0 none, 1 relu, 2 relu iff col>=512 (fused k|v).
template<int ACT, bool QG, typename TA, typename TC>
__global__ __launch_bounds__(256) void mfma_gemm_k(
    const TA* __restrict__ A, const bf16* __restrict__ Bt,
    const float* __restrict__ bias, TC* __restrict__ C,
    int M, int N, int K)
{
    __shared__ short As[4096];   // [128][32] linear
    __shared__ short Bs[4096];
    const int tid = threadIdx.x;
    const int lane = tid & 63, wid = tid >> 6;
    const int wm = wid >> 1, wn = wid & 1;
    const int bm = blockIdx.y * 128, bn = blockIdx.x * 128;
    const int fr = lane & 15, fq = lane >> 4;

    f32x4 acc[4][4] = {};

    for (int k0 = 0; k0 < K; k0 += 32) {
#if __has_builtin(__builtin_amdgcn_global_load_lds)
        #pragma unroll
        for (int j = 0; j < 2; ++j) {
            int jj = wid * 2 + j;
            int row = jj * 16 + (lane >> 2);
            const short* src = (const short*)Bt + (size_t)(bn + row) * K + k0 + (lane & 3) * 8;
            __builtin_amdgcn_global_load_lds(
                (const __attribute__((address_space(1))) void*)src,
                (__attribute__((address_space(3))) void*)&Bs[jj * 512], 16, 0, 0);
        }
        if constexpr (sizeof(TA) == 2) {
            #pragma unroll
            for (int j = 0; j < 2; ++j) {
                int jj = wid * 2 + j;
                int row = jj * 16 + (lane >> 2);
                int gm = bm + row;
                int ar = QG ? (((gm >> 3) << 5) | (gm & 7)) : gm;
                const short* src = (const short*)A + (size_t)ar * K + k0 + (lane & 3) * 8;
                __builtin_amdgcn_global_load_lds(
                    (const __attribute__((address_space(1))) void*)src,
                    (__attribute__((address_space(3))) void*)&As[jj * 512], 16, 0, 0);
            }
        } else {
            int sr = tid >> 1, sk = (tid & 1) * 16;
            int gm = bm + sr;
            int ar = QG ? (((gm >> 3) << 5) | (gm & 7)) : gm;
            const float* ap = (const float*)A + (size_t)ar * K + k0 + sk;
            short tmp[16];
            #pragma unroll
            for (int j = 0; j < 16; ++j) tmp[j] = bfb(ap[j]);
            *(uint4*)&As[sr * 32 + sk]     = *(const uint4*)&tmp[0];
            *(uint4*)&As[sr * 32 + sk + 8] = *(const uint4*)&tmp[8];
        }
#else
        {
            int sr = tid >> 1, sk = (tid & 1) * 16;
            int gm = bm + sr;
            int ar = QG ? (((gm >> 3) << 5) | (gm & 7)) : gm;
            if constexpr (sizeof(TA) == 4) {
                const float* ap = (const float*)A + (size_t)ar * K + k0 + sk;
                short tmp[16];
                #pragma unroll
                for (int j = 0; j < 16; ++j) tmp[j] = bfb(ap[j]);
                *(uint4*)&As[sr * 32 + sk]     = *(const uint4*)&tmp[0];
                *(uint4*)&As[sr * 32 + sk + 8] = *(const uint4*)&tmp[8];
            } else {
                const short* ap = (const short*)A + (size_t)ar * K + k0 + sk;
                *(uint4*)&As[sr * 32 + sk]     = *(const uint4*)(ap);
                *(uint4*)&As[sr * 32 + sk + 8] = *(const uint4*)(ap + 8);
            }
            const short* bp = (const short*)Bt + (size_t)(bn + sr) * K + k0 + sk;
            *(uint4*)&Bs[sr * 32 + sk]     = *(const uint4*)(bp);
            *(uint4*)&Bs[sr * 32 + sk + 8] = *(const uint4*)(bp + 8);
        }
#endif
        __syncthreads();

        short8 af[4], bg[4];
        #pragma unroll
        for (int m = 0; m < 4; ++m)
            af[m] = *(const short8*)&As[(wm * 64 + m * 16 + fr) * 32 + fq * 8];
        #pragma unroll
        for (int n = 0; n < 4; ++n)
            bg[n] = *(const short8*)&Bs[(wn * 64 + n * 16 + fr) * 32 + fq * 8];
        #pragma unroll
        for (int m = 0; m < 4; ++m)
            #pragma unroll
            for (int n = 0; n < 4; ++n)
                acc[m][n] = __builtin_amdgcn_mfma_f32_16x16x32_bf16(
                    af[m], bg[n], acc[m][n], 0, 0, 0);
        __syncthreads();
    }

    #pragma unroll
    for (int m = 0; m < 4; ++m) {
        #pragma unroll
        for (int n = 0; n < 4; ++n) {
            int col = bn + wn * 64 + n * 16 + fr;
            float bv = bias[col];
            #pragma unroll
            for (int r = 0; r < 4; ++r) {
                int row = bm + wm * 64 + m * 16 + fq * 4 + r;
                float v = acc[m][n][r] + bv;
                if (ACT == 1) v = fmaxf(v, 0.f);
                if (ACT == 2 && col >= 512) v = fmaxf(v, 0.f);
                stf(&C[(size_t)row * N + col], v);
            }
        }
    }
}

// ---------- merged prep ----------
__global__ __launch_bounds__(256) void prep_all_k(
    const float* __restrict__ W1, const float* __restrict__ Wq,
    const float* __restrict__ Wk, const float* __restrict__ Wv,
    const float* __restrict__ h0,
    const float* __restrict__ bk, const float* __restrict__ bv,
    bf16* __restrict__ W1t, bf16* __restrict__ Wqt, bf16* __restrict__ Wkvt,
    _Float16* __restrict__ ha, float* __restrict__ bkv)
{
    int idx = blockIdx.x * 256 + threadIdx.x;
    if (idx < 65536) {                       // W1t[n][k] = W1[k][n], K=128
        int n = idx >> 7, k = idx & 127;
        W1t[idx] = __float2bfloat16(W1[(size_t)k * 512 + n]); return;
    }
    idx -= 65536;
    if (idx < 262144) {                      // Wqt[n][k] = Wq[k][n]
        int n = idx >> 9, k = idx & 511;
        Wqt[idx] = __float2bfloat16(Wq[(size_t)k * 512 + n]); return;
    }
    idx -= 262144;
    if (idx < 524288) {                      // Wkvt[n][k]: n<512 from Wk, else Wv
        int n = idx >> 9, k = idx & 511;
        float v = (n < 512) ? Wk[(size_t)k * 512 + n] : Wv[(size_t)k * 512 + (n - 512)];
        Wkvt[idx] = __float2bfloat16(v); return;
    }
    idx -= 524288;
    if (idx < 131072) { ha[idx] = (_Float16)h0[idx]; return; }
    idx -= 131072;
    if (idx < 1024) { bkv[idx] = (idx < 512) ? bk[idx] : bv[idx - 512]; return; }
}

// ---------- legacy VALU GEMM (qout only: N=32) ----------
template<int ACT, bool BT, bool QG, bool MASKQ, typename TA, typename TB, typename TC>
__global__ __launch_bounds__(256) void gemm_k(
    const TA* __restrict__ A, const TB* __restrict__ B,
    const float* __restrict__ bias, TC* __restrict__ C,
    int M, int N, int K, const int* __restrict__ smask)
{
    const int BM = 64, BN = 64, BK = 16;
    __shared__ float Asl[BM][BK + 1];
    __shared__ float Bsl[BK][BN + 1];
    int tid = threadIdx.x;
    int n0 = blockIdx.x * BN;
    int m0 = blockIdx.y * BM;
    int ty = tid >> 4, tx = tid & 15;
    float acc[4][4] = {};

    for (int k0 = 0; k0 < K; k0 += BK) {
        #pragma unroll
        for (int i = 0; i < 4; ++i) {
            int l = tid * 4 + i;
            int r = l >> 4, c = l & 15;
            int gm = m0 + r;
            int ar = QG ? (((gm >> 3) << 5) | (gm & 7)) : gm;
            Asl[r][c] = ldf(&A[(size_t)ar * K + k0 + c]);
        }
        #pragma unroll
        for (int i = 0; i < 4; ++i) {
            int l = tid * 4 + i;
            if (BT) {
                int n = l >> 4, kk = l & 15;
                int gn = n0 + n;
                Bsl[kk][n] = (gn < N) ? ldf(&B[(size_t)gn * K + k0 + kk]) : 0.f;
            } else {
                int r = l >> 6, c = l & 63;
                int gn = n0 + c;
                Bsl[r][c] = (gn < N) ? ldf(&B[(size_t)(k0 + r) * N + gn]) : 0.f;
            }
        }
        __syncthreads();
        #pragma unroll
        for (int kk = 0; kk < BK; ++kk) {
            float a[4], b[4];
            #pragma unroll
            for (int i = 0; i < 4; ++i) a[i] = Asl[ty + i * 16][kk];
            #pragma unroll
            for (int j = 0; j < 4; ++j) b[j] = Bsl[kk][tx + j * 16];
            #pragma unroll
            for (int i = 0; i < 4; ++i)
                #pragma unroll
                for (int j = 0; j < 4; ++j) acc[i][j] += a[i] * b[j];
        }
        __syncthreads();
    }

    #pragma unroll
    for (int i = 0; i < 4; ++i) {
        int gm = m0 + ty + i * 16;
        bool mz = false;
        if (MASKQ) {
            int a_ = gm & 7, t_ = (gm >> 3) & 63, b_ = gm >> 9;
            mz = smask[((b_ << 6) + t_) * 32 + a_] != 0;
        }
        #pragma unroll
        for (int j = 0; j < 4; ++j) {
            int gn = n0 + tx + j * 16;
            if (gn < N) {
                float v = acc[i][j] + bias[gn];
                if (ACT == 1) v = fmaxf(v, 0.f);
                if (MASKQ && mz) v = 0.f;
                stf(&C[(size_t)gm * N + gn], v);
            }
        }
    }
}

// ---------- attention: one wave per (b,t,h); k/v row-stride parameterized ----------
__global__ __launch_bounds__(64) void attn_k(
    const bf16* __restrict__ qb, const bf16* __restrict__ kb, const bf16* __restrict__ vb,
    const int* __restrict__ obs, const int* __restrict__ smask, bf16* __restrict__ xs,
    int kvstride)
{
    __shared__ float qs[8 * 64], ks[32 * 64], vs[32 * 64], wsm[8 * 32];
    int bid = blockIdx.x;
    int h = bid & 7;
    int bt = bid >> 3;
    int t = bt & 63, b = bt >> 6;
    int tid = threadIdx.x;

    #pragma unroll
    for (int i = 0; i < 8; ++i) {
        int l = tid + i * 64;
        int e = l >> 6, d = l & 63;
        qs[l] = __bfloat162float(qb[((size_t)bt * 8 + e) * 512 + h * 64 + d]);
    }
    #pragma unroll
    for (int i = 0; i < 32; ++i) {
        int l = tid + i * 64;
        int e = l >> 6, d = l & 63;
        ks[l] = __bfloat162float(kb[((size_t)bt * 32 + e) * kvstride + h * 64 + d]);
        vs[l] = __bfloat162float(vb[((size_t)bt * 32 + e) * kvstride + h * 64 + d]);
    }
    __syncthreads();

    int ql = tid >> 3, jl = tid & 7;
    float s[4];
    #pragma unroll
    for (int c = 0; c < 4; ++c) {
        int kl = jl + c * 8;
        float acc = 0.f;
        for (int d = 0; d < 64; ++d) acc += qs[ql * 64 + d] * ks[kl * 64 + d];
        acc *= 0.125f;
        bool m = obs[(((size_t)bt * 32) + ql) * 32 + kl] != 0;
        s[c] = m ? -__builtin_inff() : acc;
    }
    float mx = fmaxf(fmaxf(s[0], s[1]), fmaxf(s[2], s[3]));
    for (int off = 1; off < 8; off <<= 1) mx = fmaxf(mx, __shfl_xor(mx, off));
    float e4[4]; float sum = 0.f;
    bool allmasked = (mx == -__builtin_inff());
    #pragma unroll
    for (int c = 0; c < 4; ++c) {
        e4[c] = (allmasked || s[c] == -__builtin_inff()) ? 0.f : expf(s[c] - mx);
        sum += e4[c];
    }
    for (int off = 1; off < 8; off <<= 1) sum += __shfl_xor(sum, off);
    float inv = (sum > 0.f) ? 1.f / sum : 0.f;
    #pragma unroll
    for (int c = 0; c < 4; ++c) wsm[ql * 32 + jl + c * 8] = e4[c] * inv;
    __syncthreads();

    bool amask = smask[(size_t)bt * 32 + ql] != 0;
    #pragma unroll
    for (int dd = 0; dd < 8; ++dd) {
        int d = jl + dd * 8;
        float acc = 0.f;
        for (int kl = 0; kl < 32; ++kl) acc += wsm[ql * 32 + kl] * vs[kl * 64 + d];
        if (amask) acc = 0.f;
        xs[((size_t)(t * 256 + b * 8 + ql)) * 512 + h * 64 + d] = __float2bfloat16(acc);
    }
}

// ---------- GRU v8: gi fused into the poll window ----------
// 256 WGs x 128 thr (2 waves). WG g: grp=g&7 (rows grp*32..+32), cu=g>>3
// (cols cu*16..+16). LDS: Whh slice (f16) + Wih slice (bf16), each 48x520.
// Per step: h A-loads (agent-scope) -> 48 hh-MFMA -> gates (gi from regs,
// computed LAST step in the poll shadow) -> h-store/flag -> compute gi(t+1)
// via xs loads + 48 bf16-MFMA -> poll. No gi2 buffer, no Wih conv kernel.
__global__ __launch_bounds__(128, 1) void gru_xcd_k(
    const bf16* __restrict__ xs, const float* __restrict__ Wih,
    const float* __restrict__ bih,
    const float* __restrict__ Whh, const float* __restrict__ bhh,
    const float* __restrict__ h0,
    const int* __restrict__ smask, float* __restrict__ hs_out,
    _Float16* __restrict__ ha, _Float16* __restrict__ hb, int* __restrict__ flags)
{
    __shared__ _Float16 wh16[48 * 520];   // Whh slice, f16
    __shared__ short    wi16[48 * 520];   // Wih slice, bf16
    const int tid = threadIdx.x;
    const int lane = tid & 63, wid = tid >> 6;
    const int g = blockIdx.x;
    const int grp = g & 7, cu = g >> 3;
    const int r0 = grp * 32;
    const int hc0 = cu * 16;
    const int fr = lane & 15, fq = lane >> 4;
    const int hcol = hc0 + fr;
    const int rw0 = r0 + wid * 16;       // wave's 16-row base
    const int row0 = rw0 + fq * 4;       // lane's 4 C-rows

    // stage w slices: LDS row j (0..47) = W[(j>>4)*512 + hc0 + (j&15)][0..512)
    for (int i = tid; i < 6144; i += 128) {
        int flat = i * 4;
        int r = flat >> 9, c = flat & 511;
        int wr = (r >> 4) * 512 + hc0 + (r & 15);
        float4 v = *(const float4*)(Whh + (size_t)wr * 512 + c);
        half2v p0; p0[0] = (_Float16)v.x; p0[1] = (_Float16)v.y;
        half2v p1; p1[0] = (_Float16)v.z; p1[1] = (_Float16)v.w;
        *(uint32_t*)&wh16[r * 520 + c]     = __builtin_bit_cast(uint32_t, p0);
        *(uint32_t*)&wh16[r * 520 + c + 2] = __builtin_bit_cast(uint32_t, p1);
        float4 u = *(const float4*)(Wih + (size_t)wr * 512 + c);
        uint32_t w0 = (uint32_t)(uint16_t)bfb(u.x) | ((uint32_t)(uint16_t)bfb(u.y) << 16);
        uint32_t w1 = (uint32_t)(uint16_t)bfb(u.z) | ((uint32_t)(uint16_t)bfb(u.w) << 16);
        *(uint32_t*)&wi16[r * 520 + c]     = w0;
        *(uint32_t*)&wi16[r * 520 + c + 2] = w1;
    }

    const float bhr = bhh[hcol], bhz = bhh[512 + hcol], bhn = bhh[1024 + hcol];
    const float bir = bih[hcol], biz = bih[512 + hcol], bin_ = bih[1024 + hcol];

    float hp[4];
    #pragma unroll
    for (int r = 0; r < 4; ++r)
        hp[r] = h0[(size_t)(row0 + r) * 512 + hcol];

    __syncthreads();   // w staged

    // gi(0) + smask(0)
    f32x4 gcur[3] = {};
    int mcur[4];
    {
        const short* xp = (const short*)xs + ((size_t)0 * 256 + rw0 + fr) * 512 + fq * 8;
        short8 ax[16];
        #pragma unroll
        for (int ks = 0; ks < 16; ++ks) ax[ks] = *(const short8*)(xp + ks * 32);
        #pragma unroll
        for (int ks = 0; ks < 16; ++ks) {
            const short* bb = &wi16[fr * 520 + ks * 32 + fq * 8];
            short8 b0 = *(const short8*)(bb);
            short8 b1 = *(const short8*)(bb + 16 * 520);
            short8 b2 = *(const short8*)(bb + 32 * 520);
            gcur[0] = __builtin_amdgcn_mfma_f32_16x16x32_bf16(ax[ks], b0, gcur[0], 0, 0, 0);
            gcur[1] = __builtin_amdgcn_mfma_f32_16x16x32_bf16(ax[ks], b1, gcur[1], 0, 0, 0);
            gcur[2] = __builtin_amdgcn_mfma_f32_16x16x32_bf16(ax[ks], b2, gcur[2], 0, 0, 0);
        }
        #pragma unroll
        for (int r = 0; r < 4; ++r) {
            int row = row0 + r;
            mcur[r] = smask[(((row >> 3) << 6) + 0) * 32 + (row & 7)];
        }
    }

    for (int t = 0; t < 64; ++t) {
        const _Float16* hsrc = (t & 1) ? hb : ha;
        _Float16*       hdst = (t & 1) ? ha : hb;

        // wave's h A-slab: agent-scope 8B loads (bypass stale L1/L2)
        half8 aA[16];
        {
            const unsigned long long* ap = (const unsigned long long*)
                (hsrc + (size_t)(rw0 + fr) * 512 + fq * 8);
            #pragma unroll
            for (int ks = 0; ks < 16; ++ks) {
                unsigned long long lo = __hip_atomic_load(ap + ks * 8,
                    __ATOMIC_RELAXED, __HIP_MEMORY_SCOPE_AGENT);
                unsigned long long hi = __hip_atomic_load(ap + ks * 8 + 1,
                    __ATOMIC_RELAXED, __HIP_MEMORY_SCOPE_AGENT);
                aA[ks] = h8_from(lo, hi);
            }
        }

        f32x4 acc[3] = {};
        #pragma unroll
        for (int ks = 0; ks < 16; ++ks) {
            const _Float16* bbase = &wh16[fr * 520 + ks * 32 + fq * 8];
            half8 b0 = *(const half8*)(bbase);
            half8 b1 = *(const half8*)(bbase + 16 * 520);
            half8 b2 = *(const half8*)(bbase + 32 * 520);
            acc[0] = __builtin_amdgcn_mfma_f32_16x16x32_f16(aA[ks], b0, acc[0], 0, 0, 0);
            acc[1] = __builtin_amdgcn_mfma_f32_16x16x32_f16(aA[ks], b1, acc[1], 0, 0, 0);
            acc[2] = __builtin_amdgcn_mfma_f32_16x16x32_f16(aA[ks], b2, acc[2], 0, 0, 0);
        }

        float hnv[4];
        #pragma unroll
        for (int r = 0; r < 4; ++r) {
            float rg = fsig(gcur[0][r] + bir + acc[0][r] + bhr);
            float zg = fsig(gcur[1][r] + biz + acc[1][r] + bhz);
            float ng = ftanh(gcur[2][r] + bin_ + rg * (acc[2][r] + bhn));
            float hn = (1.f - zg) * ng + zg * hp[r];
            hp[r] = hn;
            hnv[r] = hn;
            unsigned short hbits = __builtin_bit_cast(unsigned short, (_Float16)hn);
            __hip_atomic_store((unsigned short*)(hdst + (size_t)(row0 + r) * 512 + hcol),
                               hbits, __ATOMIC_RELAXED, __HIP_MEMORY_SCOPE_AGENT);
        }

        if (t != 63) {
            asm volatile("s_waitcnt vmcnt(0)" ::: "memory");   // drain h-stores
            __builtin_amdgcn_sched_barrier(0);
            __syncthreads();                                    // both waves drained
            if (tid == 0)
                __hip_atomic_store(flags + ((size_t)grp * 64 + t) * 32 + cu, 1,
                                   __ATOMIC_RELAXED, __HIP_MEMORY_SCOPE_AGENT);
            // --- poll-shadow work: hs_out stores + gi(t+1) + smask(t+1) ---
            #pragma unroll
            for (int r = 0; r < 4; ++r) {
                int row = row0 + r;
                int b_ = row >> 3, a_ = row & 7;
                hs_out[((size_t)((b_ << 6) + t) * 8 + a_) * 512 + hcol] =
                    mcur[r] ? 0.f : hnv[r];
            }
            f32x4 gnx[3] = {};
            {
                const short* xp = (const short*)xs +
                    ((size_t)(t + 1) * 256 + rw0 + fr) * 512 + fq * 8;
                short8 ax[16];
                #pragma unroll
                for (int ks = 0; ks < 16; ++ks) ax[ks] = *(const short8*)(xp + ks * 32);
                #pragma unroll
                for (int ks = 0; ks < 16; ++ks) {
                    const short* bb = &wi16[fr * 520 + ks * 32 + fq * 8];
                    short8 b0 = *(const short8*)(bb);
                    short8 b1 = *(const short8*)(bb + 16 * 520);
                    short8 b2 = *(const short8*)(bb + 32 * 520);
                    gnx[0] = __builtin_amdgcn_mfma_f32_16x16x32_bf16(ax[ks], b0, gnx[0], 0, 0, 0);
                    gnx[1] = __builtin_amdgcn_mfma_f32_16x16x32_bf16(ax[ks], b1, gnx[1], 0, 0, 0);
                    gnx[2] = __builtin_amdgcn_mfma_f32_16x16x32_bf16(ax[ks], b2, gnx[2], 0, 0, 0);
                }
            }
            int mnx[4];
            #pragma unroll
            for (int r = 0; r < 4; ++r) {
                int row = row0 + r;
                mnx[r] = smask[(((row >> 3) << 6) + (t + 1)) * 32 + (row & 7)];
            }
            // poll the 32 flags
            const int* fp = flags + ((size_t)grp * 64 + t) * 32 + (lane & 31);
            long it = 0;
            for (;;) {
                int f = __hip_atomic_load(fp, __ATOMIC_RELAXED, __HIP_MEMORY_SCOPE_AGENT);
                if (__all(f != 0) || it > 100000000L) break;
                __builtin_amdgcn_s_sleep(1);
                ++it;
            }
            __builtin_amdgcn_sched_barrier(0);
            gcur[0] = gnx[0]; gcur[1] = gnx[1]; gcur[2] = gnx[2];
            mcur[0] = mnx[0]; mcur[1] = mnx[1]; mcur[2] = mnx[2]; mcur[3] = mnx[3];
        } else {
            #pragma unroll
            for (int r = 0; r < 4; ++r) {
                int row = row0 + r;
                int b_ = row >> 3, a_ = row & 7;
                hs_out[((size_t)((b_ << 6) + t) * 8 + a_) * 512 + hcol] =
                    mcur[r] ? 0.f : hnv[r];
            }
        }
    }
}

// ---------- launch ----------
extern "C" void kernel_launch(void* const* d_in, const int* in_sizes, int n_in,
                              void* d_out, int out_size, void* d_ws, size_t ws_size,
                              hipStream_t stream)
{
    const float* inputs = (const float*)d_in[0];
    const int*   obs    = (const int*)d_in[1];
    const int*   smask  = (const int*)d_in[2];
    const float* h0     = (const float*)d_in[3];
    const float* W1  = (const float*)d_in[4];  const float* b1  = (const float*)d_in[5];
    const float* Wq  = (const float*)d_in[6];  const float* bq  = (const float*)d_in[7];
    const float* Wk  = (const float*)d_in[8];  const float* bk  = (const float*)d_in[9];
    const float* Wv  = (const float*)d_in[10]; const float* bv  = (const float*)d_in[11];
    const float* Wih = (const float*)d_in[12]; const float* bih = (const float*)d_in[13];
    const float* Whh = (const float*)d_in[14]; const float* bhh = (const float*)d_in[15];
    const float* Wo  = (const float*)d_in[16]; const float* bo  = (const float*)d_in[17];

    char* ws = (char*)d_ws;
    // x [0,64M) -> xs [0,16M) (xs lives through the GRU now);
    // qb [64,80M); kv [80,208M); W1t/Wqt/Wkvt [208,209.7M);
    // ha/hb [209.7,210.3M); flags; bkv.
    bf16*  x    = (bf16*)(ws + 0);
    bf16*  xs   = (bf16*)(ws + 0);
    bf16*  qb   = (bf16*)(ws + 67108864ull);
    bf16*  kv   = (bf16*)(ws + 83886080ull);       // 128 MB
    bf16*  W1t  = (bf16*)(ws + 218103808ull);      // 128 KB
    bf16*  Wqt  = (bf16*)(ws + 218234880ull);      // 512 KB
    bf16*  Wkvt = (bf16*)(ws + 218759168ull);      // 1 MB
    _Float16* ha = (_Float16*)(ws + 219807744ull); // 256 KB
    _Float16* hb = (_Float16*)(ws + 220069888ull); // 256 KB
    int*   flags = (int*)(ws + 220332032ull);      // 64 KB
    float* bkv   = (float*)(ws + 220397568ull);    // 4 KB

    float* out    = (float*)d_out;
    float* hs_out = out + 524288;

    hipMemsetAsync(flags, 0, 65536, stream);

    // 0. merged prep (984,064 items)
    prep_all_k<<<dim3(3844), 256, 0, stream>>>(
        W1, Wq, Wk, Wv, h0, bk, bv, W1t, Wqt, Wkvt, ha, bkv);
    // 1. fc1
    mfma_gemm_k<1, false, float, bf16><<<dim3(4, 512), 256, 0, stream>>>(
        inputs, W1t, b1, x, 65536, 512, 128);
    // 2. q (gathered agent rows)
    mfma_gemm_k<0, true, bf16, bf16><<<dim3(4, 128), 256, 0, stream>>>(
        x, Wqt, bq, qb, 16384, 512, 512);
    // 3. fused k|v (relu on v-half)
    mfma_gemm_k<2, false, bf16, bf16><<<dim3(8, 512), 256, 0, stream>>>(
        x, Wkvt, bkv, kv, 65536, 1024, 512);
    // 4. attention -> xs bf16 (x dead); k/v stride 1024
    attn_k<<<dim3(16384), 64, 0, stream>>>(qb, kv, kv + 512, obs, smask, xs, 1024);
    // 5. GRU v8: gi fused in poll shadow (no gi2 GEMM, no Wih conv)
    gru_xcd_k<<<dim3(256), 128, 0, stream>>>(
        xs, Wih, bih, Whh, bhh, h0, smask, hs_out, ha, hb, flags);
    // 6. qout
    gemm_k<0, false, false, true><<<dim3(1, 256), 256, 0, stream>>>(
        hs_out, Wo, bo, out, 16384, 32, 512, smask);
}

// Round 13
// 755.056 us; speedup vs baseline: 9.3777x; 1.0258x over previous
//
#include <hip/hip_runtime.h>
#include <hip/hip_bf16.h>
#include <cstddef>
#include <cstdint>

typedef __hip_bfloat16 bf16;
typedef __attribute__((ext_vector_type(2))) _Float16 half2v;
typedef __attribute__((ext_vector_type(8))) _Float16 half8;
typedef __attribute__((ext_vector_type(8))) short short8;
typedef __attribute__((ext_vector_type(4))) float f32x4;
typedef __attribute__((ext_vector_type(2))) unsigned long long u64x2;

// ---------- helpers ----------
__device__ inline float ldf(const float* p) { return *p; }
__device__ inline float ldf(const bf16* p) { return __bfloat162float(*p); }
__device__ inline void stf(float* p, float v) { *p = v; }
__device__ inline void stf(bf16* p, float v) { *p = __float2bfloat16(v); }
__device__ inline short bfb(float v) { return __builtin_bit_cast(short, __float2bfloat16(v)); }

__device__ inline half8 h8_from(unsigned long long lo, unsigned long long hi) {
    u64x2 t; t.x = lo; t.y = hi;
    return __builtin_bit_cast(half8, t);
}
// fast gates: v_exp_f32 path, clamped
__device__ inline float fsig(float x) {
    x = fminf(fmaxf(x, -60.f), 60.f);
    return 1.f / (1.f + __expf(-x));
}
__device__ inline float ftanh(float x) {
    x = fminf(fmaxf(x, -15.f), 15.f);
    float e = __expf(2.f * x);
    return 1.f - 2.f / (e + 1.f);
}
// unpack 8 bf16 (uint4) -> two float4 (bf16 bits << 16)
__device__ inline void unpack8(uint4 u, float4& lo, float4& hi) {
    uint32_t w0 = u.x, w1 = u.y, w2 = u.z, w3 = u.w;
    lo.x = __builtin_bit_cast(float, (w0 & 0xffffu) << 16);
    lo.y = __builtin_bit_cast(float, w0 & 0xffff0000u);
    lo.z = __builtin_bit_cast(float, (w1 & 0xffffu) << 16);
    lo.w = __builtin_bit_cast(float, w1 & 0xffff0000u);
    hi.x = __builtin_bit_cast(float, (w2 & 0xffffu) << 16);
    hi.y = __builtin_bit_cast(float, w2 & 0xffff0000u);
    hi.z = __builtin_bit_cast(float, (w3 & 0xffffu) << 16);
    hi.w = __builtin_bit_cast(float, w3 & 0xffff0000u);
}

// Problem constants: BS=32, T=64, NE=32, NA=8, ED=128, H=512, A=512, NH=8, HD=64, NACT=32

// ---------- MFMA bf16 GEMM: C[M,N] = act(A[M,K] @ Bt[N,K]^T + bias) ----------
// ACT: 0 none, 1 relu, 2 relu iff col>=512 (fused k|v).
template<int ACT, bool QG, typename TA, typename TC>
__global__ __launch_bounds__(256) void mfma_gemm_k(
    const TA* __restrict__ A, const bf16* __restrict__ Bt,
    const float* __restrict__ bias, TC* __restrict__ C,
    int M, int N, int K)
{
    __shared__ short As[4096];   // [128][32] linear
    __shared__ short Bs[4096];
    const int tid = threadIdx.x;
    const int lane = tid & 63, wid = tid >> 6;
    const int wm = wid >> 1, wn = wid & 1;
    const int bm = blockIdx.y * 128, bn = blockIdx.x * 128;
    const int fr = lane & 15, fq = lane >> 4;

    f32x4 acc[4][4] = {};

    for (int k0 = 0; k0 < K; k0 += 32) {
#if __has_builtin(__builtin_amdgcn_global_load_lds)
        #pragma unroll
        for (int j = 0; j < 2; ++j) {
            int jj = wid * 2 + j;
            int row = jj * 16 + (lane >> 2);
            const short* src = (const short*)Bt + (size_t)(bn + row) * K + k0 + (lane & 3) * 8;
            __builtin_amdgcn_global_load_lds(
                (const __attribute__((address_space(1))) void*)src,
                (__attribute__((address_space(3))) void*)&Bs[jj * 512], 16, 0, 0);
        }
        if constexpr (sizeof(TA) == 2) {
            #pragma unroll
            for (int j = 0; j < 2; ++j) {
                int jj = wid * 2 + j;
                int row = jj * 16 + (lane >> 2);
                int gm = bm + row;
                int ar = QG ? (((gm >> 3) << 5) | (gm & 7)) : gm;
                const short* src = (const short*)A + (size_t)ar * K + k0 + (lane & 3) * 8;
                __builtin_amdgcn_global_load_lds(
                    (const __attribute__((address_space(1))) void*)src,
                    (__attribute__((address_space(3))) void*)&As[jj * 512], 16, 0, 0);
            }
        } else {
            int sr = tid >> 1, sk = (tid & 1) * 16;
            int gm = bm + sr;
            int ar = QG ? (((gm >> 3) << 5) | (gm & 7)) : gm;
            const float* ap = (const float*)A + (size_t)ar * K + k0 + sk;
            float4 f0 = *(const float4*)(ap);
            float4 f1 = *(const float4*)(ap + 4);
            float4 f2 = *(const float4*)(ap + 8);
            float4 f3 = *(const float4*)(ap + 12);
            short tmp[16] = {bfb(f0.x), bfb(f0.y), bfb(f0.z), bfb(f0.w),
                             bfb(f1.x), bfb(f1.y), bfb(f1.z), bfb(f1.w),
                             bfb(f2.x), bfb(f2.y), bfb(f2.z), bfb(f2.w),
                             bfb(f3.x), bfb(f3.y), bfb(f3.z), bfb(f3.w)};
            *(uint4*)&As[sr * 32 + sk]     = *(const uint4*)&tmp[0];
            *(uint4*)&As[sr * 32 + sk + 8] = *(const uint4*)&tmp[8];
        }
#else
        {
            int sr = tid >> 1, sk = (tid & 1) * 16;
            int gm = bm + sr;
            int ar = QG ? (((gm >> 3) << 5) | (gm & 7)) : gm;
            if constexpr (sizeof(TA) == 4) {
                const float* ap = (const float*)A + (size_t)ar * K + k0 + sk;
                short tmp[16];
                #pragma unroll
                for (int j = 0; j < 16; ++j) tmp[j] = bfb(ap[j]);
                *(uint4*)&As[sr * 32 + sk]     = *(const uint4*)&tmp[0];
                *(uint4*)&As[sr * 32 + sk + 8] = *(const uint4*)&tmp[8];
            } else {
                const short* ap = (const short*)A + (size_t)ar * K + k0 + sk;
                *(uint4*)&As[sr * 32 + sk]     = *(const uint4*)(ap);
                *(uint4*)&As[sr * 32 + sk + 8] = *(const uint4*)(ap + 8);
            }
            const short* bp = (const short*)Bt + (size_t)(bn + sr) * K + k0 + sk;
            *(uint4*)&Bs[sr * 32 + sk]     = *(const uint4*)(bp);
            *(uint4*)&Bs[sr * 32 + sk + 8] = *(const uint4*)(bp + 8);
        }
#endif
        __syncthreads();

        short8 af[4], bg[4];
        #pragma unroll
        for (int m = 0; m < 4; ++m)
            af[m] = *(const short8*)&As[(wm * 64 + m * 16 + fr) * 32 + fq * 8];
        #pragma unroll
        for (int n = 0; n < 4; ++n)
            bg[n] = *(const short8*)&Bs[(wn * 64 + n * 16 + fr) * 32 + fq * 8];
        #pragma unroll
        for (int m = 0; m < 4; ++m)
            #pragma unroll
            for (int n = 0; n < 4; ++n)
                acc[m][n] = __builtin_amdgcn_mfma_f32_16x16x32_bf16(
                    af[m], bg[n], acc[m][n], 0, 0, 0);
        __syncthreads();
    }

    #pragma unroll
    for (int m = 0; m < 4; ++m) {
        #pragma unroll
        for (int n = 0; n < 4; ++n) {
            int col = bn + wn * 64 + n * 16 + fr;
            float bv = bias[col];
            #pragma unroll
            for (int r = 0; r < 4; ++r) {
                int row = bm + wm * 64 + m * 16 + fq * 4 + r;
                float v = acc[m][n][r] + bv;
                if (ACT == 1) v = fmaxf(v, 0.f);
                if (ACT == 2 && col >= 512) v = fmaxf(v, 0.f);
                stf(&C[(size_t)row * N + col], v);
            }
        }
    }
}

// ---------- merged prep ----------
__global__ __launch_bounds__(256) void prep_all_k(
    const float* __restrict__ W1, const float* __restrict__ Wq,
    const float* __restrict__ Wk, const float* __restrict__ Wv,
    const float* __restrict__ h0,
    const float* __restrict__ bk, const float* __restrict__ bv,
    bf16* __restrict__ W1t, bf16* __restrict__ Wqt, bf16* __restrict__ Wkvt,
    _Float16* __restrict__ ha, float* __restrict__ bkv)
{
    int idx = blockIdx.x * 256 + threadIdx.x;
    if (idx < 65536) {                       // W1t[n][k] = W1[k][n], K=128
        int n = idx >> 7, k = idx & 127;
        W1t[idx] = __float2bfloat16(W1[(size_t)k * 512 + n]); return;
    }
    idx -= 65536;
    if (idx < 262144) {                      // Wqt[n][k] = Wq[k][n]
        int n = idx >> 9, k = idx & 511;
        Wqt[idx] = __float2bfloat16(Wq[(size_t)k * 512 + n]); return;
    }
    idx -= 262144;
    if (idx < 524288) {                      // Wkvt[n][k]: n<512 from Wk, else Wv
        int n = idx >> 9, k = idx & 511;
        float v = (n < 512) ? Wk[(size_t)k * 512 + n] : Wv[(size_t)k * 512 + (n - 512)];
        Wkvt[idx] = __float2bfloat16(v); return;
    }
    idx -= 524288;
    if (idx < 131072) { ha[idx] = (_Float16)h0[idx]; return; }
    idx -= 131072;
    if (idx < 1024) { bkv[idx] = (idx < 512) ? bk[idx] : bv[idx - 512]; return; }
}

// ---------- legacy VALU GEMM (qout only: N=32) ----------
template<int ACT, bool BT, bool QG, bool MASKQ, typename TA, typename TB, typename TC>
__global__ __launch_bounds__(256) void gemm_k(
    const TA* __restrict__ A, const TB* __restrict__ B,
    const float* __restrict__ bias, TC* __restrict__ C,
    int M, int N, int K, const int* __restrict__ smask)
{
    const int BM = 64, BN = 64, BK = 16;
    __shared__ float Asl[BM][BK + 1];
    __shared__ float Bsl[BK][BN + 1];
    int tid = threadIdx.x;
    int n0 = blockIdx.x * BN;
    int m0 = blockIdx.y * BM;
    int ty = tid >> 4, tx = tid & 15;
    float acc[4][4] = {};

    for (int k0 = 0; k0 < K; k0 += BK) {
        #pragma unroll
        for (int i = 0; i < 4; ++i) {
            int l = tid * 4 + i;
            int r = l >> 4, c = l & 15;
            int gm = m0 + r;
            int ar = QG ? (((gm >> 3) << 5) | (gm & 7)) : gm;
            Asl[r][c] = ldf(&A[(size_t)ar * K + k0 + c]);
        }
        #pragma unroll
        for (int i = 0; i < 4; ++i) {
            int l = tid * 4 + i;
            if (BT) {
                int n = l >> 4, kk = l & 15;
                int gn = n0 + n;
                Bsl[kk][n] = (gn < N) ? ldf(&B[(size_t)gn * K + k0 + kk]) : 0.f;
            } else {
                int r = l >> 6, c = l & 63;
                int gn = n0 + c;
                Bsl[r][c] = (gn < N) ? ldf(&B[(size_t)(k0 + r) * N + gn]) : 0.f;
            }
        }
        __syncthreads();
        #pragma unroll
        for (int kk = 0; kk < BK; ++kk) {
            float a[4], b[4];
            #pragma unroll
            for (int i = 0; i < 4; ++i) a[i] = Asl[ty + i * 16][kk];
            #pragma unroll
            for (int j = 0; j < 4; ++j) b[j] = Bsl[kk][tx + j * 16];
            #pragma unroll
            for (int i = 0; i < 4; ++i)
                #pragma unroll
                for (int j = 0; j < 4; ++j) acc[i][j] += a[i] * b[j];
        }
        __syncthreads();
    }

    #pragma unroll
    for (int i = 0; i < 4; ++i) {
        int gm = m0 + ty + i * 16;
        bool mz = false;
        if (MASKQ) {
            int a_ = gm & 7, t_ = (gm >> 3) & 63, b_ = gm >> 9;
            mz = smask[((b_ << 6) + t_) * 32 + a_] != 0;
        }
        #pragma unroll
        for (int j = 0; j < 4; ++j) {
            int gn = n0 + tx + j * 16;
            if (gn < N) {
                float v = acc[i][j] + bias[gn];
                if (ACT == 1) v = fmaxf(v, 0.f);
                if (MASKQ && mz) v = 0.f;
                stf(&C[(size_t)gm * N + gn], v);
            }
        }
    }
}

// ---------- attention: one wave per (b,t,h); vectorized uint4 staging ----------
__global__ __launch_bounds__(64) void attn_k(
    const bf16* __restrict__ qb, const bf16* __restrict__ kb, const bf16* __restrict__ vb,
    const int* __restrict__ obs, const int* __restrict__ smask, bf16* __restrict__ xs,
    int kvstride)
{
    __shared__ float qs[8 * 64], ks[32 * 64], vs[32 * 64], wsm[8 * 32];
    int bid = blockIdx.x;
    int h = bid & 7;
    int bt = bid >> 3;
    int t = bt & 63, b = bt >> 6;
    int tid = threadIdx.x;

    // staging: 16B loads, 8 bf16/lane/issue
    {
        int srow = tid >> 3, c0 = (tid & 7) * 8;
        float4 lo, hi;
        uint4 qv = *(const uint4*)&qb[((size_t)bt * 8 + srow) * 512 + h * 64 + c0];
        unpack8(qv, lo, hi);
        *(float4*)&qs[srow * 64 + c0] = lo;
        *(float4*)&qs[srow * 64 + c0 + 4] = hi;
        #pragma unroll
        for (int i = 0; i < 4; ++i) {
            int row = srow + i * 8;
            uint4 kv4 = *(const uint4*)&kb[((size_t)bt * 32 + row) * kvstride + h * 64 + c0];
            unpack8(kv4, lo, hi);
            *(float4*)&ks[row * 64 + c0] = lo;
            *(float4*)&ks[row * 64 + c0 + 4] = hi;
            uint4 vv4 = *(const uint4*)&vb[((size_t)bt * 32 + row) * kvstride + h * 64 + c0];
            unpack8(vv4, lo, hi);
            *(float4*)&vs[row * 64 + c0] = lo;
            *(float4*)&vs[row * 64 + c0 + 4] = hi;
        }
    }
    __syncthreads();

    int ql = tid >> 3, jl = tid & 7;
    float s[4];
    #pragma unroll
    for (int c = 0; c < 4; ++c) {
        int kl = jl + c * 8;
        float acc = 0.f;
        for (int d = 0; d < 64; ++d) acc += qs[ql * 64 + d] * ks[kl * 64 + d];
        acc *= 0.125f;
        bool m = obs[(((size_t)bt * 32) + ql) * 32 + kl] != 0;
        s[c] = m ? -__builtin_inff() : acc;
    }
    float mx = fmaxf(fmaxf(s[0], s[1]), fmaxf(s[2], s[3]));
    for (int off = 1; off < 8; off <<= 1) mx = fmaxf(mx, __shfl_xor(mx, off));
    float e4[4]; float sum = 0.f;
    bool allmasked = (mx == -__builtin_inff());
    #pragma unroll
    for (int c = 0; c < 4; ++c) {
        e4[c] = (allmasked || s[c] == -__builtin_inff()) ? 0.f : expf(s[c] - mx);
        sum += e4[c];
    }
    for (int off = 1; off < 8; off <<= 1) sum += __shfl_xor(sum, off);
    float inv = (sum > 0.f) ? 1.f / sum : 0.f;
    #pragma unroll
    for (int c = 0; c < 4; ++c) wsm[ql * 32 + jl + c * 8] = e4[c] * inv;
    __syncthreads();

    bool amask = smask[(size_t)bt * 32 + ql] != 0;
    #pragma unroll
    for (int dd = 0; dd < 8; ++dd) {
        int d = jl + dd * 8;
        float acc = 0.f;
        for (int kl = 0; kl < 32; ++kl) acc += wsm[ql * 32 + kl] * vs[kl * 64 + d];
        if (amask) acc = 0.f;
        xs[((size_t)(t * 256 + b * 8 + ql)) * 512 + h * 64 + d] = __float2bfloat16(acc);
    }
}

// ---------- GRU v9: per-wave flags, no __syncthreads in loop, gi in poll shadow ----------
// 256 WGs x 128 thr (2 waves). WG g: grp=g&7 (rows grp*32..+32), cu=g>>3
// (cols cu*16..+16). 64 flags/(group,t): each wave signals after its own
// vmcnt drain; poll is lane-per-flag __all over 64. Safety: a wave's flag
// follows its h-stores; its h-reads precede them, so all-64-flags => both
// "stores visible" and "buffer free for reuse".
__global__ __launch_bounds__(128, 1) void gru_xcd_k(
    const bf16* __restrict__ xs, const float* __restrict__ Wih,
    const float* __restrict__ bih,
    const float* __restrict__ Whh, const float* __restrict__ bhh,
    const float* __restrict__ h0,
    const int* __restrict__ smask, float* __restrict__ hs_out,
    _Float16* __restrict__ ha, _Float16* __restrict__ hb, int* __restrict__ flags)
{
    __shared__ _Float16 wh16[48 * 520];   // Whh slice, f16
    __shared__ short    wi16[48 * 520];   // Wih slice, bf16
    const int tid = threadIdx.x;
    const int lane = tid & 63, wid = tid >> 6;
    const int g = blockIdx.x;
    const int grp = g & 7, cu = g >> 3;
    const int r0 = grp * 32;
    const int hc0 = cu * 16;
    const int fr = lane & 15, fq = lane >> 4;
    const int hcol = hc0 + fr;
    const int rw0 = r0 + wid * 16;       // wave's 16-row base
    const int row0 = rw0 + fq * 4;       // lane's 4 C-rows

    // stage w slices: LDS row j (0..47) = W[(j>>4)*512 + hc0 + (j&15)][0..512)
    for (int i = tid; i < 6144; i += 128) {
        int flat = i * 4;
        int r = flat >> 9, c = flat & 511;
        int wr = (r >> 4) * 512 + hc0 + (r & 15);
        float4 v = *(const float4*)(Whh + (size_t)wr * 512 + c);
        half2v p0; p0[0] = (_Float16)v.x; p0[1] = (_Float16)v.y;
        half2v p1; p1[0] = (_Float16)v.z; p1[1] = (_Float16)v.w;
        *(uint32_t*)&wh16[r * 520 + c]     = __builtin_bit_cast(uint32_t, p0);
        *(uint32_t*)&wh16[r * 520 + c + 2] = __builtin_bit_cast(uint32_t, p1);
        float4 u = *(const float4*)(Wih + (size_t)wr * 512 + c);
        uint32_t w0 = (uint32_t)(uint16_t)bfb(u.x) | ((uint32_t)(uint16_t)bfb(u.y) << 16);
        uint32_t w1 = (uint32_t)(uint16_t)bfb(u.z) | ((uint32_t)(uint16_t)bfb(u.w) << 16);
        *(uint32_t*)&wi16[r * 520 + c]     = w0;
        *(uint32_t*)&wi16[r * 520 + c + 2] = w1;
    }

    const float bhr = bhh[hcol], bhz = bhh[512 + hcol], bhn = bhh[1024 + hcol];
    const float bir = bih[hcol], biz = bih[512 + hcol], bin_ = bih[1024 + hcol];

    float hp[4];
    #pragma unroll
    for (int r = 0; r < 4; ++r)
        hp[r] = h0[(size_t)(row0 + r) * 512 + hcol];

    __syncthreads();   // w staged (only barrier in the kernel)

    // gi(0) + smask(0)
    f32x4 gcur[3] = {};
    int mcur[4];
    {
        const short* xp = (const short*)xs + ((size_t)0 * 256 + rw0 + fr) * 512 + fq * 8;
        short8 ax[16];
        #pragma unroll
        for (int ks = 0; ks < 16; ++ks) ax[ks] = *(const short8*)(xp + ks * 32);
        #pragma unroll
        for (int ks = 0; ks < 16; ++ks) {
            const short* bb = &wi16[fr * 520 + ks * 32 + fq * 8];
            short8 b0 = *(const short8*)(bb);
            short8 b1 = *(const short8*)(bb + 16 * 520);
            short8 b2 = *(const short8*)(bb + 32 * 520);
            gcur[0] = __builtin_amdgcn_mfma_f32_16x16x32_bf16(ax[ks], b0, gcur[0], 0, 0, 0);
            gcur[1] = __builtin_amdgcn_mfma_f32_16x16x32_bf16(ax[ks], b1, gcur[1], 0, 0, 0);
            gcur[2] = __builtin_amdgcn_mfma_f32_16x16x32_bf16(ax[ks], b2, gcur[2], 0, 0, 0);
        }
        #pragma unroll
        for (int r = 0; r < 4; ++r) {
            int row = row0 + r;
            mcur[r] = smask[(((row >> 3) << 6) + 0) * 32 + (row & 7)];
        }
    }

    for (int t = 0; t < 64; ++t) {
        const _Float16* hsrc = (t & 1) ? hb : ha;
        _Float16*       hdst = (t & 1) ? ha : hb;

        // wave's h A-slab: agent-scope 8B loads (bypass stale L1/L2)
        half8 aA[16];
        {
            const unsigned long long* ap = (const unsigned long long*)
                (hsrc + (size_t)(rw0 + fr) * 512 + fq * 8);
            #pragma unroll
            for (int ks = 0; ks < 16; ++ks) {
                unsigned long long lo = __hip_atomic_load(ap + ks * 8,
                    __ATOMIC_RELAXED, __HIP_MEMORY_SCOPE_AGENT);
                unsigned long long hi = __hip_atomic_load(ap + ks * 8 + 1,
                    __ATOMIC_RELAXED, __HIP_MEMORY_SCOPE_AGENT);
                aA[ks] = h8_from(lo, hi);
            }
        }

        f32x4 acc[3] = {};
        #pragma unroll
        for (int ks = 0; ks < 16; ++ks) {
            const _Float16* bbase = &wh16[fr * 520 + ks * 32 + fq * 8];
            half8 b0 = *(const half8*)(bbase);
            half8 b1 = *(const half8*)(bbase + 16 * 520);
            half8 b2 = *(const half8*)(bbase + 32 * 520);
            acc[0] = __builtin_amdgcn_mfma_f32_16x16x32_f16(aA[ks], b0, acc[0], 0, 0, 0);
            acc[1] = __builtin_amdgcn_mfma_f32_16x16x32_f16(aA[ks], b1, acc[1], 0, 0, 0);
            acc[2] = __builtin_amdgcn_mfma_f32_16x16x32_f16(aA[ks], b2, acc[2], 0, 0, 0);
        }

        float hnv[4];
        #pragma unroll
        for (int r = 0; r < 4; ++r) {
            float rg = fsig(gcur[0][r] + bir + acc[0][r] + bhr);
            float zg = fsig(gcur[1][r] + biz + acc[1][r] + bhz);
            float ng = ftanh(gcur[2][r] + bin_ + rg * (acc[2][r] + bhn));
            float hn = (1.f - zg) * ng + zg * hp[r];
            hp[r] = hn;
            hnv[r] = hn;
            unsigned short hbits = __builtin_bit_cast(unsigned short, (_Float16)hn);
            __hip_atomic_store((unsigned short*)(hdst + (size_t)(row0 + r) * 512 + hcol),
                               hbits, __ATOMIC_RELAXED, __HIP_MEMORY_SCOPE_AGENT);
        }

        if (t != 63) {
            asm volatile("s_waitcnt vmcnt(0)" ::: "memory");   // drain THIS wave's h-stores
            __builtin_amdgcn_sched_barrier(0);
            if (lane == 0)      // each wave signals its own flag
                __hip_atomic_store(flags + ((size_t)grp * 64 + t) * 64 + cu * 2 + wid, 1,
                                   __ATOMIC_RELAXED, __HIP_MEMORY_SCOPE_AGENT);
            // --- poll-shadow work: hs_out stores + gi(t+1) + smask(t+1) ---
            #pragma unroll
            for (int r = 0; r < 4; ++r) {
                int row = row0 + r;
                int b_ = row >> 3, a_ = row & 7;
                hs_out[((size_t)((b_ << 6) + t) * 8 + a_) * 512 + hcol] =
                    mcur[r] ? 0.f : hnv[r];
            }
            f32x4 gnx[3] = {};
            {
                const short* xp = (const short*)xs +
                    ((size_t)(t + 1) * 256 + rw0 + fr) * 512 + fq * 8;
                short8 ax[16];
                #pragma unroll
                for (int ks = 0; ks < 16; ++ks) ax[ks] = *(const short8*)(xp + ks * 32);
                #pragma unroll
                for (int ks = 0; ks < 16; ++ks) {
                    const short* bb = &wi16[fr * 520 + ks * 32 + fq * 8];
                    short8 b0 = *(const short8*)(bb);
                    short8 b1 = *(const short8*)(bb + 16 * 520);
                    short8 b2 = *(const short8*)(bb + 32 * 520);
                    gnx[0] = __builtin_amdgcn_mfma_f32_16x16x32_bf16(ax[ks], b0, gnx[0], 0, 0, 0);
                    gnx[1] = __builtin_amdgcn_mfma_f32_16x16x32_bf16(ax[ks], b1, gnx[1], 0, 0, 0);
                    gnx[2] = __builtin_amdgcn_mfma_f32_16x16x32_bf16(ax[ks], b2, gnx[2], 0, 0, 0);
                }
            }
            int mnx[4];
            #pragma unroll
            for (int r = 0; r < 4; ++r) {
                int row = row0 + r;
                mnx[r] = smask[(((row >> 3) << 6) + (t + 1)) * 32 + (row & 7)];
            }
            // poll the 64 per-wave flags (lane i watches flag i)
            const int* fp = flags + ((size_t)grp * 64 + t) * 64 + lane;
            long it = 0;
            for (;;) {
                int f = __hip_atomic_load(fp, __ATOMIC_RELAXED, __HIP_MEMORY_SCOPE_AGENT);
                if (__all(f != 0) || it > 100000000L) break;
                __builtin_amdgcn_s_sleep(1);
                ++it;
            }
            __builtin_amdgcn_sched_barrier(0);
            gcur[0] = gnx[0]; gcur[1] = gnx[1]; gcur[2] = gnx[2];
            mcur[0] = mnx[0]; mcur[1] = mnx[1]; mcur[2] = mnx[2]; mcur[3] = mnx[3];
        } else {
            #pragma unroll
            for (int r = 0; r < 4; ++r) {
                int row = row0 + r;
                int b_ = row >> 3, a_ = row & 7;
                hs_out[((size_t)((b_ << 6) + t) * 8 + a_) * 512 + hcol] =
                    mcur[r] ? 0.f : hnv[r];
            }
        }
    }
}

// ---------- launch ----------
extern "C" void kernel_launch(void* const* d_in, const int* in_sizes, int n_in,
                              void* d_out, int out_size, void* d_ws, size_t ws_size,
                              hipStream_t stream)
{
    const float* inputs = (const float*)d_in[0];
    const int*   obs    = (const int*)d_in[1];
    const int*   smask  = (const int*)d_in[2];
    const float* h0     = (const float*)d_in[3];
    const float* W1  = (const float*)d_in[4];  const float* b1  = (const float*)d_in[5];
    const float* Wq  = (const float*)d_in[6];  const float* bq  = (const float*)d_in[7];
    const float* Wk  = (const float*)d_in[8];  const float* bk  = (const float*)d_in[9];
    const float* Wv  = (const float*)d_in[10]; const float* bv  = (const float*)d_in[11];
    const float* Wih = (const float*)d_in[12]; const float* bih = (const float*)d_in[13];
    const float* Whh = (const float*)d_in[14]; const float* bhh = (const float*)d_in[15];
    const float* Wo  = (const float*)d_in[16]; const float* bo  = (const float*)d_in[17];

    char* ws = (char*)d_ws;
    // x [0,64M) -> xs [0,16M) (xs lives through the GRU);
    // qb [64,80M); kv [80,208M); W1t/Wqt/Wkvt [208,209.7M);
    // ha/hb [209.7,210.3M); flags 128K; bkv.
    bf16*  x    = (bf16*)(ws + 0);
    bf16*  xs   = (bf16*)(ws + 0);
    bf16*  qb   = (bf16*)(ws + 67108864ull);
    bf16*  kv   = (bf16*)(ws + 83886080ull);       // 128 MB
    bf16*  W1t  = (bf16*)(ws + 218103808ull);      // 128 KB
    bf16*  Wqt  = (bf16*)(ws + 218234880ull);      // 512 KB
    bf16*  Wkvt = (bf16*)(ws + 218759168ull);      // 1 MB
    _Float16* ha = (_Float16*)(ws + 219807744ull); // 256 KB
    _Float16* hb = (_Float16*)(ws + 220069888ull); // 256 KB
    int*   flags = (int*)(ws + 220332032ull);      // 8 grp x 64 t x 64 waves = 128 KB
    float* bkv   = (float*)(ws + 220463104ull);    // 4 KB

    float* out    = (float*)d_out;
    float* hs_out = out + 524288;

    hipMemsetAsync(flags, 0, 131072, stream);

    // 0. merged prep (984,064 items)
    prep_all_k<<<dim3(3844), 256, 0, stream>>>(
        W1, Wq, Wk, Wv, h0, bk, bv, W1t, Wqt, Wkvt, ha, bkv);
    // 1. fc1
    mfma_gemm_k<1, false, float, bf16><<<dim3(4, 512), 256, 0, stream>>>(
        inputs, W1t, b1, x, 65536, 512, 128);
    // 2. q (gathered agent rows)
    mfma_gemm_k<0, true, bf16, bf16><<<dim3(4, 128), 256, 0, stream>>>(
        x, Wqt, bq, qb, 16384, 512, 512);
    // 3. fused k|v (relu on v-half)
    mfma_gemm_k<2, false, bf16, bf16><<<dim3(8, 512), 256, 0, stream>>>(
        x, Wkvt, bkv, kv, 65536, 1024, 512);
    // 4. attention -> xs bf16 (x dead); k/v stride 1024
    attn_k<<<dim3(16384), 64, 0, stream>>>(qb, kv, kv + 512, obs, smask, xs, 1024);
    // 5. GRU v9: per-wave flags, gi fused in poll shadow
    gru_xcd_k<<<dim3(256), 128, 0, stream>>>(
        xs, Wih, bih, Whh, bhh, h0, smask, hs_out, ha, hb, flags);
    // 6. qout
    gemm_k<0, false, false, true><<<dim3(1, 256), 256, 0, stream>>>(
        hs_out, Wo, bo, out, 16384, 32, 512, smask);
}

// Round 14
// 660.940 us; speedup vs baseline: 10.7131x; 1.1424x over previous
//
#include <hip/hip_runtime.h>
#include <hip/hip_bf16.h>
#include <cstddef>
#include <cstdint>

typedef __hip_bfloat16 bf16;
typedef __attribute__((ext_vector_type(2))) _Float16 half2v;
typedef __attribute__((ext_vector_type(8))) _Float16 half8;
typedef __attribute__((ext_vector_type(8))) short short8;
typedef __attribute__((ext_vector_type(4))) float f32x4;
typedef __attribute__((ext_vector_type(2))) unsigned long long u64x2;

// ---------- helpers ----------
__device__ inline float ldf(const float* p) { return *p; }
__device__ inline float ldf(const bf16* p) { return __bfloat162float(*p); }
__device__ inline void stf(float* p, float v) { *p = v; }
__device__ inline void stf(bf16* p, float v) { *p = __float2bfloat16(v); }
__device__ inline short bfb(float v) { return __builtin_bit_cast(short, __float2bfloat16(v)); }

__device__ inline half8 h8_from(unsigned long long lo, unsigned long long hi) {
    u64x2 t; t.x = lo; t.y = hi;
    return __builtin_bit_cast(half8, t);
}
// fast gates: v_exp_f32 path, clamped
__device__ inline float fsig(float x) {
    x = fminf(fmaxf(x, -60.f), 60.f);
    return 1.f / (1.f + __expf(-x));
}
__device__ inline float ftanh(float x) {
    x = fminf(fmaxf(x, -15.f), 15.f);
    float e = __expf(2.f * x);
    return 1.f - 2.f / (e + 1.f);
}
// unpack 8 bf16 (uint4) -> two float4 (bf16 bits << 16)
__device__ inline void unpack8(uint4 u, float4& lo, float4& hi) {
    uint32_t w0 = u.x, w1 = u.y, w2 = u.z, w3 = u.w;
    lo.x = __builtin_bit_cast(float, (w0 & 0xffffu) << 16);
    lo.y = __builtin_bit_cast(float, w0 & 0xffff0000u);
    lo.z = __builtin_bit_cast(float, (w1 & 0xffffu) << 16);
    lo.w = __builtin_bit_cast(float, w1 & 0xffff0000u);
    hi.x = __builtin_bit_cast(float, (w2 & 0xffffu) << 16);
    hi.y = __builtin_bit_cast(float, w2 & 0xffff0000u);
    hi.z = __builtin_bit_cast(float, (w3 & 0xffffu) << 16);
    hi.w = __builtin_bit_cast(float, w3 & 0xffff0000u);
}

// Problem constants: BS=32, T=64, NE=32, NA=8, ED=128, H=512, A=512, NH=8, HD=64, NACT=32

// ---------- MFMA bf16 GEMM: C[M,N] = act(A[M,K] @ Bt[N,K]^T + bias) ----------
// ACT: 0 none, 1 relu, 2 relu iff col>=512 (fused k|v).
template<int ACT, bool QG, typename TA, typename TC>
__global__ __launch_bounds__(256) void mfma_gemm_k(
    const TA* __restrict__ A, const bf16* __restrict__ Bt,
    const float* __restrict__ bias, TC* __restrict__ C,
    int M, int N, int K)
{
    __shared__ short As[4096];   // [128][32] linear
    __shared__ short Bs[4096];
    const int tid = threadIdx.x;
    const int lane = tid & 63, wid = tid >> 6;
    const int wm = wid >> 1, wn = wid & 1;
    const int bm = blockIdx.y * 128, bn = blockIdx.x * 128;
    const int fr = lane & 15, fq = lane >> 4;

    f32x4 acc[4][4] = {};

    for (int k0 = 0; k0 < K; k0 += 32) {
#if __has_builtin(__builtin_amdgcn_global_load_lds)
        #pragma unroll
        for (int j = 0; j < 2; ++j) {
            int jj = wid * 2 + j;
            int row = jj * 16 + (lane >> 2);
            const short* src = (const short*)Bt + (size_t)(bn + row) * K + k0 + (lane & 3) * 8;
            __builtin_amdgcn_global_load_lds(
                (const __attribute__((address_space(1))) void*)src,
                (__attribute__((address_space(3))) void*)&Bs[jj * 512], 16, 0, 0);
        }
        if constexpr (sizeof(TA) == 2) {
            #pragma unroll
            for (int j = 0; j < 2; ++j) {
                int jj = wid * 2 + j;
                int row = jj * 16 + (lane >> 2);
                int gm = bm + row;
                int ar = QG ? (((gm >> 3) << 5) | (gm & 7)) : gm;
                const short* src = (const short*)A + (size_t)ar * K + k0 + (lane & 3) * 8;
                __builtin_amdgcn_global_load_lds(
                    (const __attribute__((address_space(1))) void*)src,
                    (__attribute__((address_space(3))) void*)&As[jj * 512], 16, 0, 0);
            }
        } else {
            int sr = tid >> 1, sk = (tid & 1) * 16;
            int gm = bm + sr;
            int ar = QG ? (((gm >> 3) << 5) | (gm & 7)) : gm;
            const float* ap = (const float*)A + (size_t)ar * K + k0 + sk;
            float4 f0 = *(const float4*)(ap);
            float4 f1 = *(const float4*)(ap + 4);
            float4 f2 = *(const float4*)(ap + 8);
            float4 f3 = *(const float4*)(ap + 12);
            short tmp[16] = {bfb(f0.x), bfb(f0.y), bfb(f0.z), bfb(f0.w),
                             bfb(f1.x), bfb(f1.y), bfb(f1.z), bfb(f1.w),
                             bfb(f2.x), bfb(f2.y), bfb(f2.z), bfb(f2.w),
                             bfb(f3.x), bfb(f3.y), bfb(f3.z), bfb(f3.w)};
            *(uint4*)&As[sr * 32 + sk]     = *(const uint4*)&tmp[0];
            *(uint4*)&As[sr * 32 + sk + 8] = *(const uint4*)&tmp[8];
        }
#else
        {
            int sr = tid >> 1, sk = (tid & 1) * 16;
            int gm = bm + sr;
            int ar = QG ? (((gm >> 3) << 5) | (gm & 7)) : gm;
            if constexpr (sizeof(TA) == 4) {
                const float* ap = (const float*)A + (size_t)ar * K + k0 + sk;
                short tmp[16];
                #pragma unroll
                for (int j = 0; j < 16; ++j) tmp[j] = bfb(ap[j]);
                *(uint4*)&As[sr * 32 + sk]     = *(const uint4*)&tmp[0];
                *(uint4*)&As[sr * 32 + sk + 8] = *(const uint4*)&tmp[8];
            } else {
                const short* ap = (const short*)A + (size_t)ar * K + k0 + sk;
                *(uint4*)&As[sr * 32 + sk]     = *(const uint4*)(ap);
                *(uint4*)&As[sr * 32 + sk + 8] = *(const uint4*)(ap + 8);
            }
            const short* bp = (const short*)Bt + (size_t)(bn + sr) * K + k0 + sk;
            *(uint4*)&Bs[sr * 32 + sk]     = *(const uint4*)(bp);
            *(uint4*)&Bs[sr * 32 + sk + 8] = *(const uint4*)(bp + 8);
        }
#endif
        __syncthreads();

        short8 af[4], bg[4];
        #pragma unroll
        for (int m = 0; m < 4; ++m)
            af[m] = *(const short8*)&As[(wm * 64 + m * 16 + fr) * 32 + fq * 8];
        #pragma unroll
        for (int n = 0; n < 4; ++n)
            bg[n] = *(const short8*)&Bs[(wn * 64 + n * 16 + fr) * 32 + fq * 8];
        #pragma unroll
        for (int m = 0; m < 4; ++m)
            #pragma unroll
            for (int n = 0; n < 4; ++n)
                acc[m][n] = __builtin_amdgcn_mfma_f32_16x16x32_bf16(
                    af[m], bg[n], acc[m][n], 0, 0, 0);
        __syncthreads();
    }

    #pragma unroll
    for (int m = 0; m < 4; ++m) {
        #pragma unroll
        for (int n = 0; n < 4; ++n) {
            int col = bn + wn * 64 + n * 16 + fr;
            float bv = bias[col];
            #pragma unroll
            for (int r = 0; r < 4; ++r) {
                int row = bm + wm * 64 + m * 16 + fq * 4 + r;
                float v = acc[m][n][r] + bv;
                if (ACT == 1) v = fmaxf(v, 0.f);
                if (ACT == 2 && col >= 512) v = fmaxf(v, 0.f);
                stf(&C[(size_t)row * N + col], v);
            }
        }
    }
}

// ---------- prep: tiled transposes (coalesced both sides) + ha/bkv tail ----------
// Tiles 0..63: W1->W1t (K=128); 64..319: Wq->Wqt (K=512); 320..575: Wk->Wkvt[0:512];
// 576..831: Wv->Wkvt[512:1024]. Blocks 832..1348: ha (f16 h0) + bkv elementwise.
__global__ __launch_bounds__(256) void prep_all_k(
    const float* __restrict__ W1, const float* __restrict__ Wq,
    const float* __restrict__ Wk, const float* __restrict__ Wv,
    const float* __restrict__ h0,
    const float* __restrict__ bk, const float* __restrict__ bv,
    bf16* __restrict__ W1t, bf16* __restrict__ Wqt, bf16* __restrict__ Wkvt,
    _Float16* __restrict__ ha, float* __restrict__ bkv)
{
    int blk = blockIdx.x;
    int tid = threadIdx.x;
    if (blk < 832) {
        const float* src; bf16* dst; int K, ti;
        if (blk < 64)       { src = W1; dst = W1t;  K = 128; ti = blk; }
        else if (blk < 320) { src = Wq; dst = Wqt;  K = 512; ti = blk - 64; }
        else if (blk < 576) { src = Wk; dst = Wkvt; K = 512; ti = blk - 320; }
        else                { src = Wv; dst = Wkvt + 512 * 512; K = 512; ti = blk - 576; }
        int kt = K >> 5;                  // k-tiles
        int tk = ti % kt, tn = ti / kt;   // tile coords
        int k0 = tk * 32, n0 = tn * 32;
        __shared__ float tile[32][33];
        int tx = tid & 31, ty = tid >> 5; // ty 0..7
        #pragma unroll
        for (int i = 0; i < 4; ++i) {
            int r = ty + i * 8;
            tile[r][tx] = src[(size_t)(k0 + r) * 512 + n0 + tx];
        }
        __syncthreads();
        #pragma unroll
        for (int i = 0; i < 4; ++i) {
            int r = ty + i * 8;
            dst[(size_t)(n0 + r) * K + k0 + tx] = __float2bfloat16(tile[tx][r]);
        }
        return;
    }
    int idx = (blk - 832) * 256 + tid;
    if (idx < 131072) { ha[idx] = (_Float16)h0[idx]; return; }
    idx -= 131072;
    if (idx < 1024) { bkv[idx] = (idx < 512) ? bk[idx] : bv[idx - 512]; return; }
}

// ---------- legacy VALU GEMM (qout only: N=32) ----------
template<int ACT, bool BT, bool QG, bool MASKQ, typename TA, typename TB, typename TC>
__global__ __launch_bounds__(256) void gemm_k(
    const TA* __restrict__ A, const TB* __restrict__ B,
    const float* __restrict__ bias, TC* __restrict__ C,
    int M, int N, int K, const int* __restrict__ smask)
{
    const int BM = 64, BN = 64, BK = 16;
    __shared__ float Asl[BM][BK + 1];
    __shared__ float Bsl[BK][BN + 1];
    int tid = threadIdx.x;
    int n0 = blockIdx.x * BN;
    int m0 = blockIdx.y * BM;
    int ty = tid >> 4, tx = tid & 15;
    float acc[4][4] = {};

    for (int k0 = 0; k0 < K; k0 += BK) {
        #pragma unroll
        for (int i = 0; i < 4; ++i) {
            int l = tid * 4 + i;
            int r = l >> 4, c = l & 15;
            int gm = m0 + r;
            int ar = QG ? (((gm >> 3) << 5) | (gm & 7)) : gm;
            Asl[r][c] = ldf(&A[(size_t)ar * K + k0 + c]);
        }
        #pragma unroll
        for (int i = 0; i < 4; ++i) {
            int l = tid * 4 + i;
            if (BT) {
                int n = l >> 4, kk = l & 15;
                int gn = n0 + n;
                Bsl[kk][n] = (gn < N) ? ldf(&B[(size_t)gn * K + k0 + kk]) : 0.f;
            } else {
                int r = l >> 6, c = l & 63;
                int gn = n0 + c;
                Bsl[r][c] = (gn < N) ? ldf(&B[(size_t)(k0 + r) * N + gn]) : 0.f;
            }
        }
        __syncthreads();
        #pragma unroll
        for (int kk = 0; kk < BK; ++kk) {
            float a[4], b[4];
            #pragma unroll
            for (int i = 0; i < 4; ++i) a[i] = Asl[ty + i * 16][kk];
            #pragma unroll
            for (int j = 0; j < 4; ++j) b[j] = Bsl[kk][tx + j * 16];
            #pragma unroll
            for (int i = 0; i < 4; ++i)
                #pragma unroll
                for (int j = 0; j < 4; ++j) acc[i][j] += a[i] * b[j];
        }
        __syncthreads();
    }

    #pragma unroll
    for (int i = 0; i < 4; ++i) {
        int gm = m0 + ty + i * 16;
        bool mz = false;
        if (MASKQ) {
            int a_ = gm & 7, t_ = (gm >> 3) & 63, b_ = gm >> 9;
            mz = smask[((b_ << 6) + t_) * 32 + a_] != 0;
        }
        #pragma unroll
        for (int j = 0; j < 4; ++j) {
            int gn = n0 + tx + j * 16;
            if (gn < N) {
                float v = acc[i][j] + bias[gn];
                if (ACT == 1) v = fmaxf(v, 0.f);
                if (MASKQ && mz) v = 0.f;
                stf(&C[(size_t)gm * N + gn], v);
            }
        }
    }
}

// ---------- attention: one wave per (b,t,h); stride-68 LDS (bank-conflict-free QK) ----------
#define AST 68   // padded row stride (floats): 68 % 32 = 4 -> rows spread over banks
__global__ __launch_bounds__(64) void attn_k(
    const bf16* __restrict__ qb, const bf16* __restrict__ kb, const bf16* __restrict__ vb,
    const int* __restrict__ obs, const int* __restrict__ smask, bf16* __restrict__ xs,
    int kvstride)
{
    __shared__ float qs[8 * AST], ks[32 * AST], vs[32 * AST], wsm[8 * 32];
    int bid = blockIdx.x;
    int h = bid & 7;
    int bt = bid >> 3;
    int t = bt & 63, b = bt >> 6;
    int tid = threadIdx.x;

    // staging: 16B loads, 8 bf16/lane/issue
    {
        int srow = tid >> 3, c0 = (tid & 7) * 8;
        float4 lo, hi;
        uint4 qv = *(const uint4*)&qb[((size_t)bt * 8 + srow) * 512 + h * 64 + c0];
        unpack8(qv, lo, hi);
        *(float4*)&qs[srow * AST + c0] = lo;
        *(float4*)&qs[srow * AST + c0 + 4] = hi;
        #pragma unroll
        for (int i = 0; i < 4; ++i) {
            int row = srow + i * 8;
            uint4 kv4 = *(const uint4*)&kb[((size_t)bt * 32 + row) * kvstride + h * 64 + c0];
            unpack8(kv4, lo, hi);
            *(float4*)&ks[row * AST + c0] = lo;
            *(float4*)&ks[row * AST + c0 + 4] = hi;
            uint4 vv4 = *(const uint4*)&vb[((size_t)bt * 32 + row) * kvstride + h * 64 + c0];
            unpack8(vv4, lo, hi);
            *(float4*)&vs[row * AST + c0] = lo;
            *(float4*)&vs[row * AST + c0 + 4] = hi;
        }
    }
    __syncthreads();

    int ql = tid >> 3, jl = tid & 7;
    float s[4];
    #pragma unroll
    for (int c = 0; c < 4; ++c) {
        int kl = jl + c * 8;
        float acc = 0.f;
        for (int d = 0; d < 64; ++d) acc += qs[ql * AST + d] * ks[kl * AST + d];
        acc *= 0.125f;
        bool m = obs[(((size_t)bt * 32) + ql) * 32 + kl] != 0;
        s[c] = m ? -__builtin_inff() : acc;
    }
    float mx = fmaxf(fmaxf(s[0], s[1]), fmaxf(s[2], s[3]));
    for (int off = 1; off < 8; off <<= 1) mx = fmaxf(mx, __shfl_xor(mx, off));
    float e4[4]; float sum = 0.f;
    bool allmasked = (mx == -__builtin_inff());
    #pragma unroll
    for (int c = 0; c < 4; ++c) {
        e4[c] = (allmasked || s[c] == -__builtin_inff()) ? 0.f : expf(s[c] - mx);
        sum += e4[c];
    }
    for (int off = 1; off < 8; off <<= 1) sum += __shfl_xor(sum, off);
    float inv = (sum > 0.f) ? 1.f / sum : 0.f;
    #pragma unroll
    for (int c = 0; c < 4; ++c) wsm[ql * 32 + jl + c * 8] = e4[c] * inv;
    __syncthreads();

    bool amask = smask[(size_t)bt * 32 + ql] != 0;
    #pragma unroll
    for (int dd = 0; dd < 8; ++dd) {
        int d = jl + dd * 8;
        float acc = 0.f;
        for (int kl = 0; kl < 32; ++kl) acc += wsm[ql * 32 + kl] * vs[kl * AST + d];
        if (amask) acc = 0.f;
        xs[((size_t)(t * 256 + b * 8 + ql)) * 512 + h * 64 + d] = __float2bfloat16(acc);
    }
}

// ---------- GRU v9: per-wave flags, gi in poll shadow (unchanged from r13) ----------
__global__ __launch_bounds__(128, 1) void gru_xcd_k(
    const bf16* __restrict__ xs, const float* __restrict__ Wih,
    const float* __restrict__ bih,
    const float* __restrict__ Whh, const float* __restrict__ bhh,
    const float* __restrict__ h0,
    const int* __restrict__ smask, float* __restrict__ hs_out,
    _Float16* __restrict__ ha, _Float16* __restrict__ hb, int* __restrict__ flags)
{
    __shared__ _Float16 wh16[48 * 520];   // Whh slice, f16
    __shared__ short    wi16[48 * 520];   // Wih slice, bf16
    const int tid = threadIdx.x;
    const int lane = tid & 63, wid = tid >> 6;
    const int g = blockIdx.x;
    const int grp = g & 7, cu = g >> 3;
    const int r0 = grp * 32;
    const int hc0 = cu * 16;
    const int fr = lane & 15, fq = lane >> 4;
    const int hcol = hc0 + fr;
    const int rw0 = r0 + wid * 16;
    const int row0 = rw0 + fq * 4;

    for (int i = tid; i < 6144; i += 128) {
        int flat = i * 4;
        int r = flat >> 9, c = flat & 511;
        int wr = (r >> 4) * 512 + hc0 + (r & 15);
        float4 v = *(const float4*)(Whh + (size_t)wr * 512 + c);
        half2v p0; p0[0] = (_Float16)v.x; p0[1] = (_Float16)v.y;
        half2v p1; p1[0] = (_Float16)v.z; p1[1] = (_Float16)v.w;
        *(uint32_t*)&wh16[r * 520 + c]     = __builtin_bit_cast(uint32_t, p0);
        *(uint32_t*)&wh16[r * 520 + c + 2] = __builtin_bit_cast(uint32_t, p1);
        float4 u = *(const float4*)(Wih + (size_t)wr * 512 + c);
        uint32_t w0 = (uint32_t)(uint16_t)bfb(u.x) | ((uint32_t)(uint16_t)bfb(u.y) << 16);
        uint32_t w1 = (uint32_t)(uint16_t)bfb(u.z) | ((uint32_t)(uint16_t)bfb(u.w) << 16);
        *(uint32_t*)&wi16[r * 520 + c]     = w0;
        *(uint32_t*)&wi16[r * 520 + c + 2] = w1;
    }

    const float bhr = bhh[hcol], bhz = bhh[512 + hcol], bhn = bhh[1024 + hcol];
    const float bir = bih[hcol], biz = bih[512 + hcol], bin_ = bih[1024 + hcol];

    float hp[4];
    #pragma unroll
    for (int r = 0; r < 4; ++r)
        hp[r] = h0[(size_t)(row0 + r) * 512 + hcol];

    __syncthreads();

    f32x4 gcur[3] = {};
    int mcur[4];
    {
        const short* xp = (const short*)xs + ((size_t)0 * 256 + rw0 + fr) * 512 + fq * 8;
        short8 ax[16];
        #pragma unroll
        for (int ks = 0; ks < 16; ++ks) ax[ks] = *(const short8*)(xp + ks * 32);
        #pragma unroll
        for (int ks = 0; ks < 16; ++ks) {
            const short* bb = &wi16[fr * 520 + ks * 32 + fq * 8];
            short8 b0 = *(const short8*)(bb);
            short8 b1 = *(const short8*)(bb + 16 * 520);
            short8 b2 = *(const short8*)(bb + 32 * 520);
            gcur[0] = __builtin_amdgcn_mfma_f32_16x16x32_bf16(ax[ks], b0, gcur[0], 0, 0, 0);
            gcur[1] = __builtin_amdgcn_mfma_f32_16x16x32_bf16(ax[ks], b1, gcur[1], 0, 0, 0);
            gcur[2] = __builtin_amdgcn_mfma_f32_16x16x32_bf16(ax[ks], b2, gcur[2], 0, 0, 0);
        }
        #pragma unroll
        for (int r = 0; r < 4; ++r) {
            int row = row0 + r;
            mcur[r] = smask[(((row >> 3) << 6) + 0) * 32 + (row & 7)];
        }
    }

    for (int t = 0; t < 64; ++t) {
        const _Float16* hsrc = (t & 1) ? hb : ha;
        _Float16*       hdst = (t & 1) ? ha : hb;

        half8 aA[16];
        {
            const unsigned long long* ap = (const unsigned long long*)
                (hsrc + (size_t)(rw0 + fr) * 512 + fq * 8);
            #pragma unroll
            for (int ks = 0; ks < 16; ++ks) {
                unsigned long long lo = __hip_atomic_load(ap + ks * 8,
                    __ATOMIC_RELAXED, __HIP_MEMORY_SCOPE_AGENT);
                unsigned long long hi = __hip_atomic_load(ap + ks * 8 + 1,
                    __ATOMIC_RELAXED, __HIP_MEMORY_SCOPE_AGENT);
                aA[ks] = h8_from(lo, hi);
            }
        }

        f32x4 acc[3] = {};
        #pragma unroll
        for (int ks = 0; ks < 16; ++ks) {
            const _Float16* bbase = &wh16[fr * 520 + ks * 32 + fq * 8];
            half8 b0 = *(const half8*)(bbase);
            half8 b1 = *(const half8*)(bbase + 16 * 520);
            half8 b2 = *(const half8*)(bbase + 32 * 520);
            acc[0] = __builtin_amdgcn_mfma_f32_16x16x32_f16(aA[ks], b0, acc[0], 0, 0, 0);
            acc[1] = __builtin_amdgcn_mfma_f32_16x16x32_f16(aA[ks], b1, acc[1], 0, 0, 0);
            acc[2] = __builtin_amdgcn_mfma_f32_16x16x32_f16(aA[ks], b2, acc[2], 0, 0, 0);
        }

        float hnv[4];
        #pragma unroll
        for (int r = 0; r < 4; ++r) {
            float rg = fsig(gcur[0][r] + bir + acc[0][r] + bhr);
            float zg = fsig(gcur[1][r] + biz + acc[1][r] + bhz);
            float ng = ftanh(gcur[2][r] + bin_ + rg * (acc[2][r] + bhn));
            float hn = (1.f - zg) * ng + zg * hp[r];
            hp[r] = hn;
            hnv[r] = hn;
            unsigned short hbits = __builtin_bit_cast(unsigned short, (_Float16)hn);
            __hip_atomic_store((unsigned short*)(hdst + (size_t)(row0 + r) * 512 + hcol),
                               hbits, __ATOMIC_RELAXED, __HIP_MEMORY_SCOPE_AGENT);
        }

        if (t != 63) {
            asm volatile("s_waitcnt vmcnt(0)" ::: "memory");
            __builtin_amdgcn_sched_barrier(0);
            if (lane == 0)
                __hip_atomic_store(flags + ((size_t)grp * 64 + t) * 64 + cu * 2 + wid, 1,
                                   __ATOMIC_RELAXED, __HIP_MEMORY_SCOPE_AGENT);
            #pragma unroll
            for (int r = 0; r < 4; ++r) {
                int row = row0 + r;
                int b_ = row >> 3, a_ = row & 7;
                hs_out[((size_t)((b_ << 6) + t) * 8 + a_) * 512 + hcol] =
                    mcur[r] ? 0.f : hnv[r];
            }
            f32x4 gnx[3] = {};
            {
                const short* xp = (const short*)xs +
                    ((size_t)(t + 1) * 256 + rw0 + fr) * 512 + fq * 8;
                short8 ax[16];
                #pragma unroll
                for (int ks = 0; ks < 16; ++ks) ax[ks] = *(const short8*)(xp + ks * 32);
                #pragma unroll
                for (int ks = 0; ks < 16; ++ks) {
                    const short* bb = &wi16[fr * 520 + ks * 32 + fq * 8];
                    short8 b0 = *(const short8*)(bb);
                    short8 b1 = *(const short8*)(bb + 16 * 520);
                    short8 b2 = *(const short8*)(bb + 32 * 520);
                    gnx[0] = __builtin_amdgcn_mfma_f32_16x16x32_bf16(ax[ks], b0, gnx[0], 0, 0, 0);
                    gnx[1] = __builtin_amdgcn_mfma_f32_16x16x32_bf16(ax[ks], b1, gnx[1], 0, 0, 0);
                    gnx[2] = __builtin_amdgcn_mfma_f32_16x16x32_bf16(ax[ks], b2, gnx[2], 0, 0, 0);
                }
            }
            int mnx[4];
            #pragma unroll
            for (int r = 0; r < 4; ++r) {
                int row = row0 + r;
                mnx[r] = smask[(((row >> 3) << 6) + (t + 1)) * 32 + (row & 7)];
            }
            const int* fp = flags + ((size_t)grp * 64 + t) * 64 + lane;
            long it = 0;
            for (;;) {
                int f = __hip_atomic_load(fp, __ATOMIC_RELAXED, __HIP_MEMORY_SCOPE_AGENT);
                if (__all(f != 0) || it > 100000000L) break;
                __builtin_amdgcn_s_sleep(1);
                ++it;
            }
            __builtin_amdgcn_sched_barrier(0);
            gcur[0] = gnx[0]; gcur[1] = gnx[1]; gcur[2] = gnx[2];
            mcur[0] = mnx[0]; mcur[1] = mnx[1]; mcur[2] = mnx[2]; mcur[3] = mnx[3];
        } else {
            #pragma unroll
            for (int r = 0; r < 4; ++r) {
                int row = row0 + r;
                int b_ = row >> 3, a_ = row & 7;
                hs_out[((size_t)((b_ << 6) + t) * 8 + a_) * 512 + hcol] =
                    mcur[r] ? 0.f : hnv[r];
            }
        }
    }
}

// ---------- launch ----------
extern "C" void kernel_launch(void* const* d_in, const int* in_sizes, int n_in,
                              void* d_out, int out_size, void* d_ws, size_t ws_size,
                              hipStream_t stream)
{
    const float* inputs = (const float*)d_in[0];
    const int*   obs    = (const int*)d_in[1];
    const int*   smask  = (const int*)d_in[2];
    const float* h0     = (const float*)d_in[3];
    const float* W1  = (const float*)d_in[4];  const float* b1  = (const float*)d_in[5];
    const float* Wq  = (const float*)d_in[6];  const float* bq  = (const float*)d_in[7];
    const float* Wk  = (const float*)d_in[8];  const float* bk  = (const float*)d_in[9];
    const float* Wv  = (const float*)d_in[10]; const float* bv  = (const float*)d_in[11];
    const float* Wih = (const float*)d_in[12]; const float* bih = (const float*)d_in[13];
    const float* Whh = (const float*)d_in[14]; const float* bhh = (const float*)d_in[15];
    const float* Wo  = (const float*)d_in[16]; const float* bo  = (const float*)d_in[17];

    char* ws = (char*)d_ws;
    bf16*  x    = (bf16*)(ws + 0);
    bf16*  xs   = (bf16*)(ws + 0);
    bf16*  qb   = (bf16*)(ws + 67108864ull);
    bf16*  kv   = (bf16*)(ws + 83886080ull);       // 128 MB
    bf16*  W1t  = (bf16*)(ws + 218103808ull);      // 128 KB
    bf16*  Wqt  = (bf16*)(ws + 218234880ull);      // 512 KB
    bf16*  Wkvt = (bf16*)(ws + 218759168ull);      // 1 MB
    _Float16* ha = (_Float16*)(ws + 219807744ull); // 256 KB
    _Float16* hb = (_Float16*)(ws + 220069888ull); // 256 KB
    int*   flags = (int*)(ws + 220332032ull);      // 128 KB
    float* bkv   = (float*)(ws + 220463104ull);    // 4 KB

    float* out    = (float*)d_out;
    float* hs_out = out + 524288;

    hipMemsetAsync(flags, 0, 131072, stream);

    // 0. prep: tiled transposes + ha/bkv (832 transpose tiles + 517 tail blocks)
    prep_all_k<<<dim3(1349), 256, 0, stream>>>(
        W1, Wq, Wk, Wv, h0, bk, bv, W1t, Wqt, Wkvt, ha, bkv);
    // 1. fc1
    mfma_gemm_k<1, false, float, bf16><<<dim3(4, 512), 256, 0, stream>>>(
        inputs, W1t, b1, x, 65536, 512, 128);
    // 2. q (gathered agent rows)
    mfma_gemm_k<0, true, bf16, bf16><<<dim3(4, 128), 256, 0, stream>>>(
        x, Wqt, bq, qb, 16384, 512, 512);
    // 3. fused k|v (relu on v-half)
    mfma_gemm_k<2, false, bf16, bf16><<<dim3(8, 512), 256, 0, stream>>>(
        x, Wkvt, bkv, kv, 65536, 1024, 512);
    // 4. attention -> xs bf16 (x dead); k/v stride 1024
    attn_k<<<dim3(16384), 64, 0, stream>>>(qb, kv, kv + 512, obs, smask, xs, 1024);
    // 5. GRU v9
    gru_xcd_k<<<dim3(256), 128, 0, stream>>>(
        xs, Wih, bih, Whh, bhh, h0, smask, hs_out, ha, hb, flags);
    // 6. qout
    gemm_k<0, false, false, true><<<dim3(1, 256), 256, 0, stream>>>(
        hs_out, Wo, bo, out, 16384, 32, 512, smask);
}

// Round 15
// 642.609 us; speedup vs baseline: 11.0187x; 1.0285x over previous
//
#include <hip/hip_runtime.h>
#include <hip/hip_bf16.h>
#include <cstddef>
#include <cstdint>

typedef __hip_bfloat16 bf16;
typedef __attribute__((ext_vector_type(2))) _Float16 half2v;
typedef __attribute__((ext_vector_type(8))) _Float16 half8;
typedef __attribute__((ext_vector_type(8))) short short8;
typedef __attribute__((ext_vector_type(4))) float f32x4;
typedef __attribute__((ext_vector_type(2))) unsigned long long u64x2;

// ---------- helpers ----------
__device__ inline float ldf(const float* p) { return *p; }
__device__ inline float ldf(const bf16* p) { return __bfloat162float(*p); }
__device__ inline void stf(float* p, float v) { *p = v; }
__device__ inline void stf(bf16* p, float v) { *p = __float2bfloat16(v); }
__device__ inline short bfb(float v) { return __builtin_bit_cast(short, __float2bfloat16(v)); }

__device__ inline half8 h8_from(unsigned long long lo, unsigned long long hi) {
    u64x2 t; t.x = lo; t.y = hi;
    return __builtin_bit_cast(half8, t);
}
__device__ inline float fsig(float x) {
    x = fminf(fmaxf(x, -60.f), 60.f);
    return 1.f / (1.f + __expf(-x));
}
__device__ inline float ftanh(float x) {
    x = fminf(fmaxf(x, -15.f), 15.f);
    float e = __expf(2.f * x);
    return 1.f - 2.f / (e + 1.f);
}
__device__ inline void unpack8(uint4 u, float4& lo, float4& hi) {
    uint32_t w0 = u.x, w1 = u.y, w2 = u.z, w3 = u.w;
    lo.x = __builtin_bit_cast(float, (w0 & 0xffffu) << 16);
    lo.y = __builtin_bit_cast(float, w0 & 0xffff0000u);
    lo.z = __builtin_bit_cast(float, (w1 & 0xffffu) << 16);
    lo.w = __builtin_bit_cast(float, w1 & 0xffff0000u);
    hi.x = __builtin_bit_cast(float, (w2 & 0xffffu) << 16);
    hi.y = __builtin_bit_cast(float, w2 & 0xffff0000u);
    hi.z = __builtin_bit_cast(float, (w3 & 0xffffu) << 16);
    hi.w = __builtin_bit_cast(float, w3 & 0xffff0000u);
}

// Problem constants: BS=32, T=64, NE=32, NA=8, ED=128, H=512, A=512, NH=8, HD=64, NACT=32

// ---------- MFMA bf16 GEMM: C[M,N] = act(A[M,K] @ Bt[N,K]^T + bias) ----------
template<int ACT, bool QG, typename TA, typename TC>
__global__ __launch_bounds__(256) void mfma_gemm_k(
    const TA* __restrict__ A, const bf16* __restrict__ Bt,
    const float* __restrict__ bias, TC* __restrict__ C,
    int M, int N, int K)
{
    __shared__ short As[4096];   // [128][32] linear
    __shared__ short Bs[4096];
    const int tid = threadIdx.x;
    const int lane = tid & 63, wid = tid >> 6;
    const int wm = wid >> 1, wn = wid & 1;
    const int bm = blockIdx.y * 128, bn = blockIdx.x * 128;
    const int fr = lane & 15, fq = lane >> 4;

    f32x4 acc[4][4] = {};

    for (int k0 = 0; k0 < K; k0 += 32) {
#if __has_builtin(__builtin_amdgcn_global_load_lds)
        #pragma unroll
        for (int j = 0; j < 2; ++j) {
            int jj = wid * 2 + j;
            int row = jj * 16 + (lane >> 2);
            const short* src = (const short*)Bt + (size_t)(bn + row) * K + k0 + (lane & 3) * 8;
            __builtin_amdgcn_global_load_lds(
                (const __attribute__((address_space(1))) void*)src,
                (__attribute__((address_space(3))) void*)&Bs[jj * 512], 16, 0, 0);
        }
        if constexpr (sizeof(TA) == 2) {
            #pragma unroll
            for (int j = 0; j < 2; ++j) {
                int jj = wid * 2 + j;
                int row = jj * 16 + (lane >> 2);
                int gm = bm + row;
                int ar = QG ? (((gm >> 3) << 5) | (gm & 7)) : gm;
                const short* src = (const short*)A + (size_t)ar * K + k0 + (lane & 3) * 8;
                __builtin_amdgcn_global_load_lds(
                    (const __attribute__((address_space(1))) void*)src,
                    (__attribute__((address_space(3))) void*)&As[jj * 512], 16, 0, 0);
            }
        } else {
            int sr = tid >> 1, sk = (tid & 1) * 16;
            int gm = bm + sr;
            int ar = QG ? (((gm >> 3) << 5) | (gm & 7)) : gm;
            const float* ap = (const float*)A + (size_t)ar * K + k0 + sk;
            float4 f0 = *(const float4*)(ap);
            float4 f1 = *(const float4*)(ap + 4);
            float4 f2 = *(const float4*)(ap + 8);
            float4 f3 = *(const float4*)(ap + 12);
            short tmp[16] = {bfb(f0.x), bfb(f0.y), bfb(f0.z), bfb(f0.w),
                             bfb(f1.x), bfb(f1.y), bfb(f1.z), bfb(f1.w),
                             bfb(f2.x), bfb(f2.y), bfb(f2.z), bfb(f2.w),
                             bfb(f3.x), bfb(f3.y), bfb(f3.z), bfb(f3.w)};
            *(uint4*)&As[sr * 32 + sk]     = *(const uint4*)&tmp[0];
            *(uint4*)&As[sr * 32 + sk + 8] = *(const uint4*)&tmp[8];
        }
#else
        {
            int sr = tid >> 1, sk = (tid & 1) * 16;
            int gm = bm + sr;
            int ar = QG ? (((gm >> 3) << 5) | (gm & 7)) : gm;
            if constexpr (sizeof(TA) == 4) {
                const float* ap = (const float*)A + (size_t)ar * K + k0 + sk;
                short tmp[16];
                #pragma unroll
                for (int j = 0; j < 16; ++j) tmp[j] = bfb(ap[j]);
                *(uint4*)&As[sr * 32 + sk]     = *(const uint4*)&tmp[0];
                *(uint4*)&As[sr * 32 + sk + 8] = *(const uint4*)&tmp[8];
            } else {
                const short* ap = (const short*)A + (size_t)ar * K + k0 + sk;
                *(uint4*)&As[sr * 32 + sk]     = *(const uint4*)(ap);
                *(uint4*)&As[sr * 32 + sk + 8] = *(const uint4*)(ap + 8);
            }
            const short* bp = (const short*)Bt + (size_t)(bn + sr) * K + k0 + sk;
            *(uint4*)&Bs[sr * 32 + sk]     = *(const uint4*)(bp);
            *(uint4*)&Bs[sr * 32 + sk + 8] = *(const uint4*)(bp + 8);
        }
#endif
        __syncthreads();

        short8 af[4], bg[4];
        #pragma unroll
        for (int m = 0; m < 4; ++m)
            af[m] = *(const short8*)&As[(wm * 64 + m * 16 + fr) * 32 + fq * 8];
        #pragma unroll
        for (int n = 0; n < 4; ++n)
            bg[n] = *(const short8*)&Bs[(wn * 64 + n * 16 + fr) * 32 + fq * 8];
        #pragma unroll
        for (int m = 0; m < 4; ++m)
            #pragma unroll
            for (int n = 0; n < 4; ++n)
                acc[m][n] = __builtin_amdgcn_mfma_f32_16x16x32_bf16(
                    af[m], bg[n], acc[m][n], 0, 0, 0);
        __syncthreads();
    }

    #pragma unroll
    for (int m = 0; m < 4; ++m) {
        #pragma unroll
        for (int n = 0; n < 4; ++n) {
            int col = bn + wn * 64 + n * 16 + fr;
            float bv = bias[col];
            #pragma unroll
            for (int r = 0; r < 4; ++r) {
                int row = bm + wm * 64 + m * 16 + fq * 4 + r;
                float v = acc[m][n][r] + bv;
                if (ACT == 1) v = fmaxf(v, 0.f);
                if (ACT == 2 && col >= 512) v = fmaxf(v, 0.f);
                stf(&C[(size_t)row * N + col], v);
            }
        }
    }
}

// ---------- prep: tiled transposes (stride-aware) + ha/bkv tail ----------
// 0..63: W1 (N=512,K=128); 64..319: Wq; 320..575: Wk; 576..831: Wv (all N=512,K=512);
// 832..847: Wo (N=32,K=512). 848..: ha + bkv elementwise.
__global__ __launch_bounds__(256) void prep_all_k(
    const float* __restrict__ W1, const float* __restrict__ Wq,
    const float* __restrict__ Wk, const float* __restrict__ Wv,
    const float* __restrict__ Wo, const float* __restrict__ h0,
    const float* __restrict__ bk, const float* __restrict__ bv,
    bf16* __restrict__ W1t, bf16* __restrict__ Wqt, bf16* __restrict__ Wkvt,
    bf16* __restrict__ Wot, _Float16* __restrict__ ha, float* __restrict__ bkv)
{
    int blk = blockIdx.x;
    int tid = threadIdx.x;
    if (blk < 848) {
        const float* src; bf16* dst; int K, N, ti;
        if (blk < 64)       { src = W1; dst = W1t;  K = 128; N = 512; ti = blk; }
        else if (blk < 320) { src = Wq; dst = Wqt;  K = 512; N = 512; ti = blk - 64; }
        else if (blk < 576) { src = Wk; dst = Wkvt; K = 512; N = 512; ti = blk - 320; }
        else if (blk < 832) { src = Wv; dst = Wkvt + 512 * 512; K = 512; N = 512; ti = blk - 576; }
        else                { src = Wo; dst = Wot;  K = 512; N = 32;  ti = blk - 832; }
        int kt = K >> 5;
        int tk = ti % kt, tn = ti / kt;
        int k0 = tk * 32, n0 = tn * 32;
        __shared__ float tile[32][33];
        int tx = tid & 31, ty = tid >> 5;
        #pragma unroll
        for (int i = 0; i < 4; ++i) {
            int r = ty + i * 8;
            tile[r][tx] = src[(size_t)(k0 + r) * N + n0 + tx];
        }
        __syncthreads();
        #pragma unroll
        for (int i = 0; i < 4; ++i) {
            int r = ty + i * 8;
            if (n0 + r < N)
                dst[(size_t)(n0 + r) * K + k0 + tx] = __float2bfloat16(tile[tx][r]);
        }
        return;
    }
    int idx = (blk - 848) * 256 + tid;
    if (idx < 131072) { ha[idx] = (_Float16)h0[idx]; return; }
    idx -= 131072;
    if (idx < 1024) { bkv[idx] = (idx < 512) ? bk[idx] : bv[idx - 512]; return; }
}

// ---------- qout MFMA: out[16384,32] = mask(hs[16384,512] @ Wot^T + bo) ----------
__global__ __launch_bounds__(256) void qout_mfma_k(
    const float* __restrict__ hs, const bf16* __restrict__ Wot,
    const float* __restrict__ bo, const int* __restrict__ smask,
    float* __restrict__ out)
{
    __shared__ short Bs2[32 * 520];    // Wot staged once, padded stride
    __shared__ short As2[128 * 32];
    const int tid = threadIdx.x;
    const int lane = tid & 63, wid = tid >> 6;
    const int bm = blockIdx.x * 128;
    const int fr = lane & 15, fq = lane >> 4;

    // stage Wot [32][512] -> Bs2 [32][520]
    for (int i = tid; i < 2048; i += 256) {     // 8-short groups
        int row = i >> 6, col = (i & 63) * 8;
        *(uint4*)&Bs2[row * 520 + col] = *(const uint4*)((const short*)Wot + row * 512 + col);
    }

    f32x4 acc[2][2] = {};
    for (int k0 = 0; k0 < 512; k0 += 32) {
        {
            int sr = tid >> 1, sk = (tid & 1) * 16;
            const float* ap = hs + (size_t)(bm + sr) * 512 + k0 + sk;
            float4 f0 = *(const float4*)(ap);
            float4 f1 = *(const float4*)(ap + 4);
            float4 f2 = *(const float4*)(ap + 8);
            float4 f3 = *(const float4*)(ap + 12);
            short tmp[16] = {bfb(f0.x), bfb(f0.y), bfb(f0.z), bfb(f0.w),
                             bfb(f1.x), bfb(f1.y), bfb(f1.z), bfb(f1.w),
                             bfb(f2.x), bfb(f2.y), bfb(f2.z), bfb(f2.w),
                             bfb(f3.x), bfb(f3.y), bfb(f3.z), bfb(f3.w)};
            *(uint4*)&As2[sr * 32 + sk]     = *(const uint4*)&tmp[0];
            *(uint4*)&As2[sr * 32 + sk + 8] = *(const uint4*)&tmp[8];
        }
        __syncthreads();
        short8 af[2], bg[2];
        #pragma unroll
        for (int m = 0; m < 2; ++m)
            af[m] = *(const short8*)&As2[(wid * 32 + m * 16 + fr) * 32 + fq * 8];
        #pragma unroll
        for (int n = 0; n < 2; ++n)
            bg[n] = *(const short8*)&Bs2[(n * 16 + fr) * 520 + k0 + fq * 8];
        #pragma unroll
        for (int m = 0; m < 2; ++m)
            #pragma unroll
            for (int n = 0; n < 2; ++n)
                acc[m][n] = __builtin_amdgcn_mfma_f32_16x16x32_bf16(
                    af[m], bg[n], acc[m][n], 0, 0, 0);
        __syncthreads();
    }

    #pragma unroll
    for (int m = 0; m < 2; ++m) {
        #pragma unroll
        for (int n = 0; n < 2; ++n) {
            int col = n * 16 + fr;
            float bv = bo[col];
            #pragma unroll
            for (int r = 0; r < 4; ++r) {
                int row = bm + wid * 32 + m * 16 + fq * 4 + r;
                int a_ = row & 7, t_ = (row >> 3) & 63, b_ = row >> 9;
                bool mz = smask[((b_ << 6) + t_) * 32 + a_] != 0;
                out[(size_t)row * 32 + col] = mz ? 0.f : (acc[m][n][r] + bv);
            }
        }
    }
}

// ---------- attention: one wave per (b,t,h); stride-68 LDS ----------
#define AST 68
__global__ __launch_bounds__(64) void attn_k(
    const bf16* __restrict__ qb, const bf16* __restrict__ kb, const bf16* __restrict__ vb,
    const int* __restrict__ obs, const int* __restrict__ smask, bf16* __restrict__ xs,
    int kvstride)
{
    __shared__ float qs[8 * AST], ks[32 * AST], vs[32 * AST], wsm[8 * 32];
    int bid = blockIdx.x;
    int h = bid & 7;
    int bt = bid >> 3;
    int t = bt & 63, b = bt >> 6;
    int tid = threadIdx.x;

    {
        int srow = tid >> 3, c0 = (tid & 7) * 8;
        float4 lo, hi;
        uint4 qv = *(const uint4*)&qb[((size_t)bt * 8 + srow) * 512 + h * 64 + c0];
        unpack8(qv, lo, hi);
        *(float4*)&qs[srow * AST + c0] = lo;
        *(float4*)&qs[srow * AST + c0 + 4] = hi;
        #pragma unroll
        for (int i = 0; i < 4; ++i) {
            int row = srow + i * 8;
            uint4 kv4 = *(const uint4*)&kb[((size_t)bt * 32 + row) * kvstride + h * 64 + c0];
            unpack8(kv4, lo, hi);
            *(float4*)&ks[row * AST + c0] = lo;
            *(float4*)&ks[row * AST + c0 + 4] = hi;
            uint4 vv4 = *(const uint4*)&vb[((size_t)bt * 32 + row) * kvstride + h * 64 + c0];
            unpack8(vv4, lo, hi);
            *(float4*)&vs[row * AST + c0] = lo;
            *(float4*)&vs[row * AST + c0 + 4] = hi;
        }
    }
    __syncthreads();

    int ql = tid >> 3, jl = tid & 7;
    float s[4];
    #pragma unroll
    for (int c = 0; c < 4; ++c) {
        int kl = jl + c * 8;
        float acc = 0.f;
        for (int d = 0; d < 64; ++d) acc += qs[ql * AST + d] * ks[kl * AST + d];
        acc *= 0.125f;
        bool m = obs[(((size_t)bt * 32) + ql) * 32 + kl] != 0;
        s[c] = m ? -__builtin_inff() : acc;
    }
    float mx = fmaxf(fmaxf(s[0], s[1]), fmaxf(s[2], s[3]));
    for (int off = 1; off < 8; off <<= 1) mx = fmaxf(mx, __shfl_xor(mx, off));
    float e4[4]; float sum = 0.f;
    bool allmasked = (mx == -__builtin_inff());
    #pragma unroll
    for (int c = 0; c < 4; ++c) {
        e4[c] = (allmasked || s[c] == -__builtin_inff()) ? 0.f : expf(s[c] - mx);
        sum += e4[c];
    }
    for (int off = 1; off < 8; off <<= 1) sum += __shfl_xor(sum, off);
    float inv = (sum > 0.f) ? 1.f / sum : 0.f;
    #pragma unroll
    for (int c = 0; c < 4; ++c) wsm[ql * 32 + jl + c * 8] = e4[c] * inv;
    __syncthreads();

    bool amask = smask[(size_t)bt * 32 + ql] != 0;
    #pragma unroll
    for (int dd = 0; dd < 8; ++dd) {
        int d = jl + dd * 8;
        float acc = 0.f;
        for (int kl = 0; kl < 32; ++kl) acc += wsm[ql * 32 + kl] * vs[kl * AST + d];
        if (amask) acc = 0.f;
        xs[((size_t)(t * 256 + b * 8 + ql)) * 512 + h * 64 + d] = __float2bfloat16(acc);
    }
}

// ---------- GRU v10: byte-flag cacheline poll (coalesced), gi in poll shadow ----------
// flags8: [grp][t][64 waves] uchar — one 64B line per (grp,t); wave poll = 1 transaction.
__global__ __launch_bounds__(128, 1) void gru_xcd_k(
    const bf16* __restrict__ xs, const float* __restrict__ Wih,
    const float* __restrict__ bih,
    const float* __restrict__ Whh, const float* __restrict__ bhh,
    const float* __restrict__ h0,
    const int* __restrict__ smask, float* __restrict__ hs_out,
    _Float16* __restrict__ ha, _Float16* __restrict__ hb,
    unsigned char* __restrict__ flags8)
{
    __shared__ _Float16 wh16[48 * 520];
    __shared__ short    wi16[48 * 520];
    const int tid = threadIdx.x;
    const int lane = tid & 63, wid = tid >> 6;
    const int g = blockIdx.x;
    const int grp = g & 7, cu = g >> 3;
    const int r0 = grp * 32;
    const int hc0 = cu * 16;
    const int fr = lane & 15, fq = lane >> 4;
    const int hcol = hc0 + fr;
    const int rw0 = r0 + wid * 16;
    const int row0 = rw0 + fq * 4;

    for (int i = tid; i < 6144; i += 128) {
        int flat = i * 4;
        int r = flat >> 9, c = flat & 511;
        int wr = (r >> 4) * 512 + hc0 + (r & 15);
        float4 v = *(const float4*)(Whh + (size_t)wr * 512 + c);
        half2v p0; p0[0] = (_Float16)v.x; p0[1] = (_Float16)v.y;
        half2v p1; p1[0] = (_Float16)v.z; p1[1] = (_Float16)v.w;
        *(uint32_t*)&wh16[r * 520 + c]     = __builtin_bit_cast(uint32_t, p0);
        *(uint32_t*)&wh16[r * 520 + c + 2] = __builtin_bit_cast(uint32_t, p1);
        float4 u = *(const float4*)(Wih + (size_t)wr * 512 + c);
        uint32_t w0 = (uint32_t)(uint16_t)bfb(u.x) | ((uint32_t)(uint16_t)bfb(u.y) << 16);
        uint32_t w1 = (uint32_t)(uint16_t)bfb(u.z) | ((uint32_t)(uint16_t)bfb(u.w) << 16);
        *(uint32_t*)&wi16[r * 520 + c]     = w0;
        *(uint32_t*)&wi16[r * 520 + c + 2] = w1;
    }

    const float bhr = bhh[hcol], bhz = bhh[512 + hcol], bhn = bhh[1024 + hcol];
    const float bir = bih[hcol], biz = bih[512 + hcol], bin_ = bih[1024 + hcol];

    float hp[4];
    #pragma unroll
    for (int r = 0; r < 4; ++r)
        hp[r] = h0[(size_t)(row0 + r) * 512 + hcol];

    __syncthreads();

    f32x4 gcur[3] = {};
    int mcur[4];
    {
        const short* xp = (const short*)xs + ((size_t)0 * 256 + rw0 + fr) * 512 + fq * 8;
        short8 ax[16];
        #pragma unroll
        for (int ks = 0; ks < 16; ++ks) ax[ks] = *(const short8*)(xp + ks * 32);
        #pragma unroll
        for (int ks = 0; ks < 16; ++ks) {
            const short* bb = &wi16[fr * 520 + ks * 32 + fq * 8];
            short8 b0 = *(const short8*)(bb);
            short8 b1 = *(const short8*)(bb + 16 * 520);
            short8 b2 = *(const short8*)(bb + 32 * 520);
            gcur[0] = __builtin_amdgcn_mfma_f32_16x16x32_bf16(ax[ks], b0, gcur[0], 0, 0, 0);
            gcur[1] = __builtin_amdgcn_mfma_f32_16x16x32_bf16(ax[ks], b1, gcur[1], 0, 0, 0);
            gcur[2] = __builtin_amdgcn_mfma_f32_16x16x32_bf16(ax[ks], b2, gcur[2], 0, 0, 0);
        }
        #pragma unroll
        for (int r = 0; r < 4; ++r) {
            int row = row0 + r;
            mcur[r] = smask[(((row >> 3) << 6) + 0) * 32 + (row & 7)];
        }
    }

    for (int t = 0; t < 64; ++t) {
        const _Float16* hsrc = (t & 1) ? hb : ha;
        _Float16*       hdst = (t & 1) ? ha : hb;

        half8 aA[16];
        {
            const unsigned long long* ap = (const unsigned long long*)
                (hsrc + (size_t)(rw0 + fr) * 512 + fq * 8);
            #pragma unroll
            for (int ks = 0; ks < 16; ++ks) {
                unsigned long long lo = __hip_atomic_load(ap + ks * 8,
                    __ATOMIC_RELAXED, __HIP_MEMORY_SCOPE_AGENT);
                unsigned long long hi = __hip_atomic_load(ap + ks * 8 + 1,
                    __ATOMIC_RELAXED, __HIP_MEMORY_SCOPE_AGENT);
                aA[ks] = h8_from(lo, hi);
            }
        }

        f32x4 acc[3] = {};
        #pragma unroll
        for (int ks = 0; ks < 16; ++ks) {
            const _Float16* bbase = &wh16[fr * 520 + ks * 32 + fq * 8];
            half8 b0 = *(const half8*)(bbase);
            half8 b1 = *(const half8*)(bbase + 16 * 520);
            half8 b2 = *(const half8*)(bbase + 32 * 520);
            acc[0] = __builtin_amdgcn_mfma_f32_16x16x32_f16(aA[ks], b0, acc[0], 0, 0, 0);
            acc[1] = __builtin_amdgcn_mfma_f32_16x16x32_f16(aA[ks], b1, acc[1], 0, 0, 0);
            acc[2] = __builtin_amdgcn_mfma_f32_16x16x32_f16(aA[ks], b2, acc[2], 0, 0, 0);
        }

        float hnv[4];
        #pragma unroll
        for (int r = 0; r < 4; ++r) {
            float rg = fsig(gcur[0][r] + bir + acc[0][r] + bhr);
            float zg = fsig(gcur[1][r] + biz + acc[1][r] + bhz);
            float ng = ftanh(gcur[2][r] + bin_ + rg * (acc[2][r] + bhn));
            float hn = (1.f - zg) * ng + zg * hp[r];
            hp[r] = hn;
            hnv[r] = hn;
            unsigned short hbits = __builtin_bit_cast(unsigned short, (_Float16)hn);
            __hip_atomic_store((unsigned short*)(hdst + (size_t)(row0 + r) * 512 + hcol),
                               hbits, __ATOMIC_RELAXED, __HIP_MEMORY_SCOPE_AGENT);
        }

        if (t != 63) {
            asm volatile("s_waitcnt vmcnt(0)" ::: "memory");
            __builtin_amdgcn_sched_barrier(0);
            if (lane == 0)
                __hip_atomic_store(flags8 + ((size_t)grp * 64 + t) * 64 + cu * 2 + wid,
                                   (unsigned char)1,
                                   __ATOMIC_RELAXED, __HIP_MEMORY_SCOPE_AGENT);
            #pragma unroll
            for (int r = 0; r < 4; ++r) {
                int row = row0 + r;
                int b_ = row >> 3, a_ = row & 7;
                hs_out[((size_t)((b_ << 6) + t) * 8 + a_) * 512 + hcol] =
                    mcur[r] ? 0.f : hnv[r];
            }
            f32x4 gnx[3] = {};
            {
                const short* xp = (const short*)xs +
                    ((size_t)(t + 1) * 256 + rw0 + fr) * 512 + fq * 8;
                short8 ax[16];
                #pragma unroll
                for (int ks = 0; ks < 16; ++ks) ax[ks] = *(const short8*)(xp + ks * 32);
                #pragma unroll
                for (int ks = 0; ks < 16; ++ks) {
                    const short* bb = &wi16[fr * 520 + ks * 32 + fq * 8];
                    short8 b0 = *(const short8*)(bb);
                    short8 b1 = *(const short8*)(bb + 16 * 520);
                    short8 b2 = *(const short8*)(bb + 32 * 520);
                    gnx[0] = __builtin_amdgcn_mfma_f32_16x16x32_bf16(ax[ks], b0, gnx[0], 0, 0, 0);
                    gnx[1] = __builtin_amdgcn_mfma_f32_16x16x32_bf16(ax[ks], b1, gnx[1], 0, 0, 0);
                    gnx[2] = __builtin_amdgcn_mfma_f32_16x16x32_bf16(ax[ks], b2, gnx[2], 0, 0, 0);
                }
            }
            int mnx[4];
            #pragma unroll
            for (int r = 0; r < 4; ++r) {
                int row = row0 + r;
                mnx[r] = smask[(((row >> 3) << 6) + (t + 1)) * 32 + (row & 7)];
            }
            // poll: lane i watches byte i of ONE 64B line (coalesced single transaction)
            const unsigned char* fp = flags8 + ((size_t)grp * 64 + t) * 64 + lane;
            long it = 0;
            for (;;) {
                unsigned char f = __hip_atomic_load(fp, __ATOMIC_RELAXED,
                                                    __HIP_MEMORY_SCOPE_AGENT);
                if (__all(f != 0) || it > 200000000L) break;
                ++it;
            }
            __builtin_amdgcn_sched_barrier(0);
            gcur[0] = gnx[0]; gcur[1] = gnx[1]; gcur[2] = gnx[2];
            mcur[0] = mnx[0]; mcur[1] = mnx[1]; mcur[2] = mnx[2]; mcur[3] = mnx[3];
        } else {
            #pragma unroll
            for (int r = 0; r < 4; ++r) {
                int row = row0 + r;
                int b_ = row >> 3, a_ = row & 7;
                hs_out[((size_t)((b_ << 6) + t) * 8 + a_) * 512 + hcol] =
                    mcur[r] ? 0.f : hnv[r];
            }
        }
    }
}

// ---------- launch ----------
extern "C" void kernel_launch(void* const* d_in, const int* in_sizes, int n_in,
                              void* d_out, int out_size, void* d_ws, size_t ws_size,
                              hipStream_t stream)
{
    const float* inputs = (const float*)d_in[0];
    const int*   obs    = (const int*)d_in[1];
    const int*   smask  = (const int*)d_in[2];
    const float* h0     = (const float*)d_in[3];
    const float* W1  = (const float*)d_in[4];  const float* b1  = (const float*)d_in[5];
    const float* Wq  = (const float*)d_in[6];  const float* bq  = (const float*)d_in[7];
    const float* Wk  = (const float*)d_in[8];  const float* bk  = (const float*)d_in[9];
    const float* Wv  = (const float*)d_in[10]; const float* bv  = (const float*)d_in[11];
    const float* Wih = (const float*)d_in[12]; const float* bih = (const float*)d_in[13];
    const float* Whh = (const float*)d_in[14]; const float* bhh = (const float*)d_in[15];
    const float* Wo  = (const float*)d_in[16]; const float* bo  = (const float*)d_in[17];

    char* ws = (char*)d_ws;
    bf16*  x    = (bf16*)(ws + 0);
    bf16*  xs   = (bf16*)(ws + 0);
    bf16*  qb   = (bf16*)(ws + 67108864ull);
    bf16*  kv   = (bf16*)(ws + 83886080ull);           // 128 MB
    bf16*  W1t  = (bf16*)(ws + 218103808ull);          // 128 KB
    bf16*  Wqt  = (bf16*)(ws + 218234880ull);          // 512 KB
    bf16*  Wkvt = (bf16*)(ws + 218759168ull);          // 1 MB
    _Float16* ha = (_Float16*)(ws + 219807744ull);     // 256 KB
    _Float16* hb = (_Float16*)(ws + 220069888ull);     // 256 KB
    unsigned char* flags8 = (unsigned char*)(ws + 220332032ull);  // 32 KB
    float* bkv  = (float*)(ws + 220364800ull);         // 4 KB
    bf16*  Wot  = (bf16*)(ws + 220368896ull);          // 32 KB

    float* out    = (float*)d_out;
    float* hs_out = out + 524288;

    hipMemsetAsync(flags8, 0, 32768, stream);

    // 0. prep: tiled transposes (848 tiles incl. Wo) + ha/bkv tail (517 blocks)
    prep_all_k<<<dim3(1365), 256, 0, stream>>>(
        W1, Wq, Wk, Wv, Wo, h0, bk, bv, W1t, Wqt, Wkvt, Wot, ha, bkv);
    // 1. fc1
    mfma_gemm_k<1, false, float, bf16><<<dim3(4, 512), 256, 0, stream>>>(
        inputs, W1t, b1, x, 65536, 512, 128);
    // 2. q (gathered agent rows)
    mfma_gemm_k<0, true, bf16, bf16><<<dim3(4, 128), 256, 0, stream>>>(
        x, Wqt, bq, qb, 16384, 512, 512);
    // 3. fused k|v (relu on v-half)
    mfma_gemm_k<2, false, bf16, bf16><<<dim3(8, 512), 256, 0, stream>>>(
        x, Wkvt, bkv, kv, 65536, 1024, 512);
    // 4. attention -> xs bf16 (x dead); k/v stride 1024
    attn_k<<<dim3(16384), 64, 0, stream>>>(qb, kv, kv + 512, obs, smask, xs, 1024);
    // 5. GRU v10: coalesced byte-flag poll
    gru_xcd_k<<<dim3(256), 128, 0, stream>>>(
        xs, Wih, bih, Whh, bhh, h0, smask, hs_out, ha, hb, flags8);
    // 6. qout via MFMA
    qout_mfma_k<<<dim3(128), 256, 0, stream>>>(hs_out, Wot, bo, smask, out);
}

// Round 16
// 600.740 us; speedup vs baseline: 11.7867x; 1.0697x over previous
//
#include <hip/hip_runtime.h>
#include <hip/hip_bf16.h>
#include <cstddef>
#include <cstdint>

typedef __hip_bfloat16 bf16;
typedef __attribute__((ext_vector_type(2))) _Float16 half2v;
typedef __attribute__((ext_vector_type(8))) _Float16 half8;
typedef __attribute__((ext_vector_type(8))) short short8;
typedef __attribute__((ext_vector_type(4))) float f32x4;
typedef __attribute__((ext_vector_type(2))) unsigned long long u64x2;

// ---------- helpers ----------
__device__ inline float ldf(const float* p) { return *p; }
__device__ inline float ldf(const bf16* p) { return __bfloat162float(*p); }
__device__ inline void stf(float* p, float v) { *p = v; }
__device__ inline void stf(bf16* p, float v) { *p = __float2bfloat16(v); }
__device__ inline short bfb(float v) { return __builtin_bit_cast(short, __float2bfloat16(v)); }

__device__ inline half8 h8_from(unsigned long long lo, unsigned long long hi) {
    u64x2 t; t.x = lo; t.y = hi;
    return __builtin_bit_cast(half8, t);
}
__device__ inline float fsig(float x) {
    x = fminf(fmaxf(x, -60.f), 60.f);
    return 1.f / (1.f + __expf(-x));
}
__device__ inline float ftanh(float x) {
    x = fminf(fmaxf(x, -15.f), 15.f);
    float e = __expf(2.f * x);
    return 1.f - 2.f / (e + 1.f);
}
__device__ inline void unpack8(uint4 u, float4& lo, float4& hi) {
    uint32_t w0 = u.x, w1 = u.y, w2 = u.z, w3 = u.w;
    lo.x = __builtin_bit_cast(float, (w0 & 0xffffu) << 16);
    lo.y = __builtin_bit_cast(float, w0 & 0xffff0000u);
    lo.z = __builtin_bit_cast(float, (w1 & 0xffffu) << 16);
    lo.w = __builtin_bit_cast(float, w1 & 0xffff0000u);
    hi.x = __builtin_bit_cast(float, (w2 & 0xffffu) << 16);
    hi.y = __builtin_bit_cast(float, w2 & 0xffff0000u);
    hi.z = __builtin_bit_cast(float, (w3 & 0xffffu) << 16);
    hi.w = __builtin_bit_cast(float, w3 & 0xffff0000u);
}

// Problem constants: BS=32, T=64, NE=32, NA=8, ED=128, H=512, A=512, NH=8, HD=64, NACT=32

// ---------- MFMA bf16 GEMM, 2-phase double-buffered staging ----------
// ACT: 0 none, 1 relu, 2 relu iff col>=512 (fused k|v).
template<int ACT, bool QG, typename TA, typename TC>
__global__ __launch_bounds__(256) void mfma_gemm_k(
    const TA* __restrict__ A, const bf16* __restrict__ Bt,
    const float* __restrict__ bias, TC* __restrict__ C,
    int M, int N, int K)
{
    __shared__ short As[2][4096];   // [128][32] linear, double-buffered
    __shared__ short Bs[2][4096];
    const int tid = threadIdx.x;
    const int lane = tid & 63, wid = tid >> 6;
    const int wm = wid >> 1, wn = wid & 1;
    const int bm = blockIdx.y * 128, bn = blockIdx.x * 128;
    const int fr = lane & 15, fq = lane >> 4;

    f32x4 acc[4][4] = {};

    auto stage = [&](int buf, int k0) {
#if __has_builtin(__builtin_amdgcn_global_load_lds)
        #pragma unroll
        for (int j = 0; j < 2; ++j) {
            int jj = wid * 2 + j;
            int row = jj * 16 + (lane >> 2);
            const short* src = (const short*)Bt + (size_t)(bn + row) * K + k0 + (lane & 3) * 8;
            __builtin_amdgcn_global_load_lds(
                (const __attribute__((address_space(1))) void*)src,
                (__attribute__((address_space(3))) void*)&Bs[buf][jj * 512], 16, 0, 0);
        }
        if constexpr (sizeof(TA) == 2) {
            #pragma unroll
            for (int j = 0; j < 2; ++j) {
                int jj = wid * 2 + j;
                int row = jj * 16 + (lane >> 2);
                int gm = bm + row;
                int ar = QG ? (((gm >> 3) << 5) | (gm & 7)) : gm;
                const short* src = (const short*)A + (size_t)ar * K + k0 + (lane & 3) * 8;
                __builtin_amdgcn_global_load_lds(
                    (const __attribute__((address_space(1))) void*)src,
                    (__attribute__((address_space(3))) void*)&As[buf][jj * 512], 16, 0, 0);
            }
        } else {
            int sr = tid >> 1, sk = (tid & 1) * 16;
            int gm = bm + sr;
            int ar = QG ? (((gm >> 3) << 5) | (gm & 7)) : gm;
            const float* ap = (const float*)A + (size_t)ar * K + k0 + sk;
            float4 f0 = *(const float4*)(ap);
            float4 f1 = *(const float4*)(ap + 4);
            float4 f2 = *(const float4*)(ap + 8);
            float4 f3 = *(const float4*)(ap + 12);
            short tmp[16] = {bfb(f0.x), bfb(f0.y), bfb(f0.z), bfb(f0.w),
                             bfb(f1.x), bfb(f1.y), bfb(f1.z), bfb(f1.w),
                             bfb(f2.x), bfb(f2.y), bfb(f2.z), bfb(f2.w),
                             bfb(f3.x), bfb(f3.y), bfb(f3.z), bfb(f3.w)};
            *(uint4*)&As[buf][sr * 32 + sk]     = *(const uint4*)&tmp[0];
            *(uint4*)&As[buf][sr * 32 + sk + 8] = *(const uint4*)&tmp[8];
        }
#else
        {
            int sr = tid >> 1, sk = (tid & 1) * 16;
            int gm = bm + sr;
            int ar = QG ? (((gm >> 3) << 5) | (gm & 7)) : gm;
            if constexpr (sizeof(TA) == 4) {
                const float* ap = (const float*)A + (size_t)ar * K + k0 + sk;
                short tmp[16];
                #pragma unroll
                for (int j = 0; j < 16; ++j) tmp[j] = bfb(ap[j]);
                *(uint4*)&As[buf][sr * 32 + sk]     = *(const uint4*)&tmp[0];
                *(uint4*)&As[buf][sr * 32 + sk + 8] = *(const uint4*)&tmp[8];
            } else {
                const short* ap = (const short*)A + (size_t)ar * K + k0 + sk;
                *(uint4*)&As[buf][sr * 32 + sk]     = *(const uint4*)(ap);
                *(uint4*)&As[buf][sr * 32 + sk + 8] = *(const uint4*)(ap + 8);
            }
            const short* bp = (const short*)Bt + (size_t)(bn + sr) * K + k0 + sk;
            *(uint4*)&Bs[buf][sr * 32 + sk]     = *(const uint4*)(bp);
            *(uint4*)&Bs[buf][sr * 32 + sk + 8] = *(const uint4*)(bp + 8);
        }
#endif
    };

    const int nt = K >> 5;
    stage(0, 0);
    __syncthreads();              // pre-barrier drain covers prologue stage

    for (int t = 0; t < nt; ++t) {
        int cur = t & 1;
        if (t + 1 < nt) stage(cur ^ 1, (t + 1) * 32);   // prefetch overlaps MFMA

        short8 af[4], bg[4];
        #pragma unroll
        for (int m = 0; m < 4; ++m)
            af[m] = *(const short8*)&As[cur][(wm * 64 + m * 16 + fr) * 32 + fq * 8];
        #pragma unroll
        for (int n = 0; n < 4; ++n)
            bg[n] = *(const short8*)&Bs[cur][(wn * 64 + n * 16 + fr) * 32 + fq * 8];
        #pragma unroll
        for (int m = 0; m < 4; ++m)
            #pragma unroll
            for (int n = 0; n < 4; ++n)
                acc[m][n] = __builtin_amdgcn_mfma_f32_16x16x32_bf16(
                    af[m], bg[n], acc[m][n], 0, 0, 0);
        __syncthreads();          // drains this tile's prefetch + read-reuse safety
    }

    #pragma unroll
    for (int m = 0; m < 4; ++m) {
        #pragma unroll
        for (int n = 0; n < 4; ++n) {
            int col = bn + wn * 64 + n * 16 + fr;
            float bv = bias[col];
            #pragma unroll
            for (int r = 0; r < 4; ++r) {
                int row = bm + wm * 64 + m * 16 + fq * 4 + r;
                float v = acc[m][n][r] + bv;
                if (ACT == 1) v = fmaxf(v, 0.f);
                if (ACT == 2 && col >= 512) v = fmaxf(v, 0.f);
                stf(&C[(size_t)row * N + col], v);
            }
        }
    }
}

// ---------- prep: tiled transposes (stride-aware) + ha/bkv tail ----------
__global__ __launch_bounds__(256) void prep_all_k(
    const float* __restrict__ W1, const float* __restrict__ Wq,
    const float* __restrict__ Wk, const float* __restrict__ Wv,
    const float* __restrict__ Wo, const float* __restrict__ h0,
    const float* __restrict__ bk, const float* __restrict__ bv,
    bf16* __restrict__ W1t, bf16* __restrict__ Wqt, bf16* __restrict__ Wkvt,
    bf16* __restrict__ Wot, _Float16* __restrict__ ha, float* __restrict__ bkv)
{
    int blk = blockIdx.x;
    int tid = threadIdx.x;
    if (blk < 848) {
        const float* src; bf16* dst; int K, N, ti;
        if (blk < 64)       { src = W1; dst = W1t;  K = 128; N = 512; ti = blk; }
        else if (blk < 320) { src = Wq; dst = Wqt;  K = 512; N = 512; ti = blk - 64; }
        else if (blk < 576) { src = Wk; dst = Wkvt; K = 512; N = 512; ti = blk - 320; }
        else if (blk < 832) { src = Wv; dst = Wkvt + 512 * 512; K = 512; N = 512; ti = blk - 576; }
        else                { src = Wo; dst = Wot;  K = 512; N = 32;  ti = blk - 832; }
        int kt = K >> 5;
        int tk = ti % kt, tn = ti / kt;
        int k0 = tk * 32, n0 = tn * 32;
        __shared__ float tile[32][33];
        int tx = tid & 31, ty = tid >> 5;
        #pragma unroll
        for (int i = 0; i < 4; ++i) {
            int r = ty + i * 8;
            tile[r][tx] = src[(size_t)(k0 + r) * N + n0 + tx];
        }
        __syncthreads();
        #pragma unroll
        for (int i = 0; i < 4; ++i) {
            int r = ty + i * 8;
            if (n0 + r < N)
                dst[(size_t)(n0 + r) * K + k0 + tx] = __float2bfloat16(tile[tx][r]);
        }
        return;
    }
    int idx = (blk - 848) * 256 + tid;
    if (idx < 131072) { ha[idx] = (_Float16)h0[idx]; return; }
    idx -= 131072;
    if (idx < 1024) { bkv[idx] = (idx < 512) ? bk[idx] : bv[idx - 512]; return; }
}

// ---------- qout MFMA: out[16384,32] = mask(hs[16384,512] @ Wot^T + bo) ----------
__global__ __launch_bounds__(256) void qout_mfma_k(
    const float* __restrict__ hs, const bf16* __restrict__ Wot,
    const float* __restrict__ bo, const int* __restrict__ smask,
    float* __restrict__ out)
{
    __shared__ short Bs2[32 * 520];
    __shared__ short As2[128 * 32];
    const int tid = threadIdx.x;
    const int lane = tid & 63, wid = tid >> 6;
    const int bm = blockIdx.x * 128;
    const int fr = lane & 15, fq = lane >> 4;

    for (int i = tid; i < 2048; i += 256) {
        int row = i >> 6, col = (i & 63) * 8;
        *(uint4*)&Bs2[row * 520 + col] = *(const uint4*)((const short*)Wot + row * 512 + col);
    }

    f32x4 acc[2][2] = {};
    for (int k0 = 0; k0 < 512; k0 += 32) {
        {
            int sr = tid >> 1, sk = (tid & 1) * 16;
            const float* ap = hs + (size_t)(bm + sr) * 512 + k0 + sk;
            float4 f0 = *(const float4*)(ap);
            float4 f1 = *(const float4*)(ap + 4);
            float4 f2 = *(const float4*)(ap + 8);
            float4 f3 = *(const float4*)(ap + 12);
            short tmp[16] = {bfb(f0.x), bfb(f0.y), bfb(f0.z), bfb(f0.w),
                             bfb(f1.x), bfb(f1.y), bfb(f1.z), bfb(f1.w),
                             bfb(f2.x), bfb(f2.y), bfb(f2.z), bfb(f2.w),
                             bfb(f3.x), bfb(f3.y), bfb(f3.z), bfb(f3.w)};
            *(uint4*)&As2[sr * 32 + sk]     = *(const uint4*)&tmp[0];
            *(uint4*)&As2[sr * 32 + sk + 8] = *(const uint4*)&tmp[8];
        }
        __syncthreads();
        short8 af[2], bg[2];
        #pragma unroll
        for (int m = 0; m < 2; ++m)
            af[m] = *(const short8*)&As2[(wid * 32 + m * 16 + fr) * 32 + fq * 8];
        #pragma unroll
        for (int n = 0; n < 2; ++n)
            bg[n] = *(const short8*)&Bs2[(n * 16 + fr) * 520 + k0 + fq * 8];
        #pragma unroll
        for (int m = 0; m < 2; ++m)
            #pragma unroll
            for (int n = 0; n < 2; ++n)
                acc[m][n] = __builtin_amdgcn_mfma_f32_16x16x32_bf16(
                    af[m], bg[n], acc[m][n], 0, 0, 0);
        __syncthreads();
    }

    #pragma unroll
    for (int m = 0; m < 2; ++m) {
        #pragma unroll
        for (int n = 0; n < 2; ++n) {
            int col = n * 16 + fr;
            float bv = bo[col];
            #pragma unroll
            for (int r = 0; r < 4; ++r) {
                int row = bm + wid * 32 + m * 16 + fq * 4 + r;
                int a_ = row & 7, t_ = (row >> 3) & 63, b_ = row >> 9;
                bool mz = smask[((b_ << 6) + t_) * 32 + a_] != 0;
                out[(size_t)row * 32 + col] = mz ? 0.f : (acc[m][n][r] + bv);
            }
        }
    }
}

// ---------- attention: one wave per (b,t,h); stride-68 LDS ----------
#define AST 68
__global__ __launch_bounds__(64) void attn_k(
    const bf16* __restrict__ qb, const bf16* __restrict__ kb, const bf16* __restrict__ vb,
    const int* __restrict__ obs, const int* __restrict__ smask, bf16* __restrict__ xs,
    int kvstride)
{
    __shared__ float qs[8 * AST], ks[32 * AST], vs[32 * AST], wsm[8 * 32];
    int bid = blockIdx.x;
    int h = bid & 7;
    int bt = bid >> 3;
    int t = bt & 63, b = bt >> 6;
    int tid = threadIdx.x;

    {
        int srow = tid >> 3, c0 = (tid & 7) * 8;
        float4 lo, hi;
        uint4 qv = *(const uint4*)&qb[((size_t)bt * 8 + srow) * 512 + h * 64 + c0];
        unpack8(qv, lo, hi);
        *(float4*)&qs[srow * AST + c0] = lo;
        *(float4*)&qs[srow * AST + c0 + 4] = hi;
        #pragma unroll
        for (int i = 0; i < 4; ++i) {
            int row = srow + i * 8;
            uint4 kv4 = *(const uint4*)&kb[((size_t)bt * 32 + row) * kvstride + h * 64 + c0];
            unpack8(kv4, lo, hi);
            *(float4*)&ks[row * AST + c0] = lo;
            *(float4*)&ks[row * AST + c0 + 4] = hi;
            uint4 vv4 = *(const uint4*)&vb[((size_t)bt * 32 + row) * kvstride + h * 64 + c0];
            unpack8(vv4, lo, hi);
            *(float4*)&vs[row * AST + c0] = lo;
            *(float4*)&vs[row * AST + c0 + 4] = hi;
        }
    }
    __syncthreads();

    int ql = tid >> 3, jl = tid & 7;
    float s[4];
    #pragma unroll
    for (int c = 0; c < 4; ++c) {
        int kl = jl + c * 8;
        float acc = 0.f;
        for (int d = 0; d < 64; ++d) acc += qs[ql * AST + d] * ks[kl * AST + d];
        acc *= 0.125f;
        bool m = obs[(((size_t)bt * 32) + ql) * 32 + kl] != 0;
        s[c] = m ? -__builtin_inff() : acc;
    }
    float mx = fmaxf(fmaxf(s[0], s[1]), fmaxf(s[2], s[3]));
    for (int off = 1; off < 8; off <<= 1) mx = fmaxf(mx, __shfl_xor(mx, off));
    float e4[4]; float sum = 0.f;
    bool allmasked = (mx == -__builtin_inff());
    #pragma unroll
    for (int c = 0; c < 4; ++c) {
        e4[c] = (allmasked || s[c] == -__builtin_inff()) ? 0.f : expf(s[c] - mx);
        sum += e4[c];
    }
    for (int off = 1; off < 8; off <<= 1) sum += __shfl_xor(sum, off);
    float inv = (sum > 0.f) ? 1.f / sum : 0.f;
    #pragma unroll
    for (int c = 0; c < 4; ++c) wsm[ql * 32 + jl + c * 8] = e4[c] * inv;
    __syncthreads();

    bool amask = smask[(size_t)bt * 32 + ql] != 0;
    #pragma unroll
    for (int dd = 0; dd < 8; ++dd) {
        int d = jl + dd * 8;
        float acc = 0.f;
        for (int kl = 0; kl < 32; ++kl) acc += wsm[ql * 32 + kl] * vs[kl * AST + d];
        if (amask) acc = 0.f;
        xs[((size_t)(t * 256 + b * 8 + ql)) * 512 + h * 64 + d] = __float2bfloat16(acc);
    }
}

// ---------- GRU (round-14 proven): per-wave int flags + s_sleep poll, gi in shadow ----------
__global__ __launch_bounds__(128, 1) void gru_xcd_k(
    const bf16* __restrict__ xs, const float* __restrict__ Wih,
    const float* __restrict__ bih,
    const float* __restrict__ Whh, const float* __restrict__ bhh,
    const float* __restrict__ h0,
    const int* __restrict__ smask, float* __restrict__ hs_out,
    _Float16* __restrict__ ha, _Float16* __restrict__ hb, int* __restrict__ flags)
{
    __shared__ _Float16 wh16[48 * 520];
    __shared__ short    wi16[48 * 520];
    const int tid = threadIdx.x;
    const int lane = tid & 63, wid = tid >> 6;
    const int g = blockIdx.x;
    const int grp = g & 7, cu = g >> 3;
    const int r0 = grp * 32;
    const int hc0 = cu * 16;
    const int fr = lane & 15, fq = lane >> 4;
    const int hcol = hc0 + fr;
    const int rw0 = r0 + wid * 16;
    const int row0 = rw0 + fq * 4;

    for (int i = tid; i < 6144; i += 128) {
        int flat = i * 4;
        int r = flat >> 9, c = flat & 511;
        int wr = (r >> 4) * 512 + hc0 + (r & 15);
        float4 v = *(const float4*)(Whh + (size_t)wr * 512 + c);
        half2v p0; p0[0] = (_Float16)v.x; p0[1] = (_Float16)v.y;
        half2v p1; p1[0] = (_Float16)v.z; p1[1] = (_Float16)v.w;
        *(uint32_t*)&wh16[r * 520 + c]     = __builtin_bit_cast(uint32_t, p0);
        *(uint32_t*)&wh16[r * 520 + c + 2] = __builtin_bit_cast(uint32_t, p1);
        float4 u = *(const float4*)(Wih + (size_t)wr * 512 + c);
        uint32_t w0 = (uint32_t)(uint16_t)bfb(u.x) | ((uint32_t)(uint16_t)bfb(u.y) << 16);
        uint32_t w1 = (uint32_t)(uint16_t)bfb(u.z) | ((uint32_t)(uint16_t)bfb(u.w) << 16);
        *(uint32_t*)&wi16[r * 520 + c]     = w0;
        *(uint32_t*)&wi16[r * 520 + c + 2] = w1;
    }

    const float bhr = bhh[hcol], bhz = bhh[512 + hcol], bhn = bhh[1024 + hcol];
    const float bir = bih[hcol], biz = bih[512 + hcol], bin_ = bih[1024 + hcol];

    float hp[4];
    #pragma unroll
    for (int r = 0; r < 4; ++r)
        hp[r] = h0[(size_t)(row0 + r) * 512 + hcol];

    __syncthreads();

    f32x4 gcur[3] = {};
    int mcur[4];
    {
        const short* xp = (const short*)xs + ((size_t)0 * 256 + rw0 + fr) * 512 + fq * 8;
        short8 ax[16];
        #pragma unroll
        for (int ks = 0; ks < 16; ++ks) ax[ks] = *(const short8*)(xp + ks * 32);
        #pragma unroll
        for (int ks = 0; ks < 16; ++ks) {
            const short* bb = &wi16[fr * 520 + ks * 32 + fq * 8];
            short8 b0 = *(const short8*)(bb);
            short8 b1 = *(const short8*)(bb + 16 * 520);
            short8 b2 = *(const short8*)(bb + 32 * 520);
            gcur[0] = __builtin_amdgcn_mfma_f32_16x16x32_bf16(ax[ks], b0, gcur[0], 0, 0, 0);
            gcur[1] = __builtin_amdgcn_mfma_f32_16x16x32_bf16(ax[ks], b1, gcur[1], 0, 0, 0);
            gcur[2] = __builtin_amdgcn_mfma_f32_16x16x32_bf16(ax[ks], b2, gcur[2], 0, 0, 0);
        }
        #pragma unroll
        for (int r = 0; r < 4; ++r) {
            int row = row0 + r;
            mcur[r] = smask[(((row >> 3) << 6) + 0) * 32 + (row & 7)];
        }
    }

    for (int t = 0; t < 64; ++t) {
        const _Float16* hsrc = (t & 1) ? hb : ha;
        _Float16*       hdst = (t & 1) ? ha : hb;

        half8 aA[16];
        {
            const unsigned long long* ap = (const unsigned long long*)
                (hsrc + (size_t)(rw0 + fr) * 512 + fq * 8);
            #pragma unroll
            for (int ks = 0; ks < 16; ++ks) {
                unsigned long long lo = __hip_atomic_load(ap + ks * 8,
                    __ATOMIC_RELAXED, __HIP_MEMORY_SCOPE_AGENT);
                unsigned long long hi = __hip_atomic_load(ap + ks * 8 + 1,
                    __ATOMIC_RELAXED, __HIP_MEMORY_SCOPE_AGENT);
                aA[ks] = h8_from(lo, hi);
            }
        }

        f32x4 acc[3] = {};
        #pragma unroll
        for (int ks = 0; ks < 16; ++ks) {
            const _Float16* bbase = &wh16[fr * 520 + ks * 32 + fq * 8];
            half8 b0 = *(const half8*)(bbase);
            half8 b1 = *(const half8*)(bbase + 16 * 520);
            half8 b2 = *(const half8*)(bbase + 32 * 520);
            acc[0] = __builtin_amdgcn_mfma_f32_16x16x32_f16(aA[ks], b0, acc[0], 0, 0, 0);
            acc[1] = __builtin_amdgcn_mfma_f32_16x16x32_f16(aA[ks], b1, acc[1], 0, 0, 0);
            acc[2] = __builtin_amdgcn_mfma_f32_16x16x32_f16(aA[ks], b2, acc[2], 0, 0, 0);
        }

        float hnv[4];
        #pragma unroll
        for (int r = 0; r < 4; ++r) {
            float rg = fsig(gcur[0][r] + bir + acc[0][r] + bhr);
            float zg = fsig(gcur[1][r] + biz + acc[1][r] + bhz);
            float ng = ftanh(gcur[2][r] + bin_ + rg * (acc[2][r] + bhn));
            float hn = (1.f - zg) * ng + zg * hp[r];
            hp[r] = hn;
            hnv[r] = hn;
            unsigned short hbits = __builtin_bit_cast(unsigned short, (_Float16)hn);
            __hip_atomic_store((unsigned short*)(hdst + (size_t)(row0 + r) * 512 + hcol),
                               hbits, __ATOMIC_RELAXED, __HIP_MEMORY_SCOPE_AGENT);
        }

        if (t != 63) {
            asm volatile("s_waitcnt vmcnt(0)" ::: "memory");
            __builtin_amdgcn_sched_barrier(0);
            if (lane == 0)
                __hip_atomic_store(flags + ((size_t)grp * 64 + t) * 64 + cu * 2 + wid, 1,
                                   __ATOMIC_RELAXED, __HIP_MEMORY_SCOPE_AGENT);
            #pragma unroll
            for (int r = 0; r < 4; ++r) {
                int row = row0 + r;
                int b_ = row >> 3, a_ = row & 7;
                hs_out[((size_t)((b_ << 6) + t) * 8 + a_) * 512 + hcol] =
                    mcur[r] ? 0.f : hnv[r];
            }
            f32x4 gnx[3] = {};
            {
                const short* xp = (const short*)xs +
                    ((size_t)(t + 1) * 256 + rw0 + fr) * 512 + fq * 8;
                short8 ax[16];
                #pragma unroll
                for (int ks = 0; ks < 16; ++ks) ax[ks] = *(const short8*)(xp + ks * 32);
                #pragma unroll
                for (int ks = 0; ks < 16; ++ks) {
                    const short* bb = &wi16[fr * 520 + ks * 32 + fq * 8];
                    short8 b0 = *(const short8*)(bb);
                    short8 b1 = *(const short8*)(bb + 16 * 520);
                    short8 b2 = *(const short8*)(bb + 32 * 520);
                    gnx[0] = __builtin_amdgcn_mfma_f32_16x16x32_bf16(ax[ks], b0, gnx[0], 0, 0, 0);
                    gnx[1] = __builtin_amdgcn_mfma_f32_16x16x32_bf16(ax[ks], b1, gnx[1], 0, 0, 0);
                    gnx[2] = __builtin_amdgcn_mfma_f32_16x16x32_bf16(ax[ks], b2, gnx[2], 0, 0, 0);
                }
            }
            int mnx[4];
            #pragma unroll
            for (int r = 0; r < 4; ++r) {
                int row = row0 + r;
                mnx[r] = smask[(((row >> 3) << 6) + (t + 1)) * 32 + (row & 7)];
            }
            const int* fp = flags + ((size_t)grp * 64 + t) * 64 + lane;
            long it = 0;
            for (;;) {
                int f = __hip_atomic_load(fp, __ATOMIC_RELAXED, __HIP_MEMORY_SCOPE_AGENT);
                if (__all(f != 0) || it > 100000000L) break;
                __builtin_amdgcn_s_sleep(1);
                ++it;
            }
            __builtin_amdgcn_sched_barrier(0);
            gcur[0] = gnx[0]; gcur[1] = gnx[1]; gcur[2] = gnx[2];
            mcur[0] = mnx[0]; mcur[1] = mnx[1]; mcur[2] = mnx[2]; mcur[3] = mnx[3];
        } else {
            #pragma unroll
            for (int r = 0; r < 4; ++r) {
                int row = row0 + r;
                int b_ = row >> 3, a_ = row & 7;
                hs_out[((size_t)((b_ << 6) + t) * 8 + a_) * 512 + hcol] =
                    mcur[r] ? 0.f : hnv[r];
            }
        }
    }
}

// ---------- launch ----------
extern "C" void kernel_launch(void* const* d_in, const int* in_sizes, int n_in,
                              void* d_out, int out_size, void* d_ws, size_t ws_size,
                              hipStream_t stream)
{
    const float* inputs = (const float*)d_in[0];
    const int*   obs    = (const int*)d_in[1];
    const int*   smask  = (const int*)d_in[2];
    const float* h0     = (const float*)d_in[3];
    const float* W1  = (const float*)d_in[4];  const float* b1  = (const float*)d_in[5];
    const float* Wq  = (const float*)d_in[6];  const float* bq  = (const float*)d_in[7];
    const float* Wk  = (const float*)d_in[8];  const float* bk  = (const float*)d_in[9];
    const float* Wv  = (const float*)d_in[10]; const float* bv  = (const float*)d_in[11];
    const float* Wih = (const float*)d_in[12]; const float* bih = (const float*)d_in[13];
    const float* Whh = (const float*)d_in[14]; const float* bhh = (const float*)d_in[15];
    const float* Wo  = (const float*)d_in[16]; const float* bo  = (const float*)d_in[17];

    char* ws = (char*)d_ws;
    bf16*  x    = (bf16*)(ws + 0);
    bf16*  xs   = (bf16*)(ws + 0);
    bf16*  qb   = (bf16*)(ws + 67108864ull);
    bf16*  kv   = (bf16*)(ws + 83886080ull);           // 128 MB
    bf16*  W1t  = (bf16*)(ws + 218103808ull);          // 128 KB
    bf16*  Wqt  = (bf16*)(ws + 218234880ull);          // 512 KB
    bf16*  Wkvt = (bf16*)(ws + 218759168ull);          // 1 MB
    _Float16* ha = (_Float16*)(ws + 219807744ull);     // 256 KB
    _Float16* hb = (_Float16*)(ws + 220069888ull);     // 256 KB
    int*   flags = (int*)(ws + 220332032ull);          // 128 KB
    float* bkv  = (float*)(ws + 220463104ull);         // 4 KB
    bf16*  Wot  = (bf16*)(ws + 220467200ull);          // 32 KB

    float* out    = (float*)d_out;
    float* hs_out = out + 524288;

    hipMemsetAsync(flags, 0, 131072, stream);

    // 0. prep: tiled transposes (848 tiles incl. Wo) + ha/bkv tail
    prep_all_k<<<dim3(1365), 256, 0, stream>>>(
        W1, Wq, Wk, Wv, Wo, h0, bk, bv, W1t, Wqt, Wkvt, Wot, ha, bkv);
    // 1. fc1
    mfma_gemm_k<1, false, float, bf16><<<dim3(4, 512), 256, 0, stream>>>(
        inputs, W1t, b1, x, 65536, 512, 128);
    // 2. q (gathered agent rows)
    mfma_gemm_k<0, true, bf16, bf16><<<dim3(4, 128), 256, 0, stream>>>(
        x, Wqt, bq, qb, 16384, 512, 512);
    // 3. fused k|v (relu on v-half)
    mfma_gemm_k<2, false, bf16, bf16><<<dim3(8, 512), 256, 0, stream>>>(
        x, Wkvt, bkv, kv, 65536, 1024, 512);
    // 4. attention -> xs bf16 (x dead); k/v stride 1024
    attn_k<<<dim3(16384), 64, 0, stream>>>(qb, kv, kv + 512, obs, smask, xs, 1024);
    // 5. GRU (r14 proven poll)
    gru_xcd_k<<<dim3(256), 128, 0, stream>>>(
        xs, Wih, bih, Whh, bhh, h0, smask, hs_out, ha, hb, flags);
    // 6. qout via MFMA
    qout_mfma_k<<<dim3(128), 256, 0, stream>>>(hs_out, Wot, bo, smask, out);
}

// Round 17
// 548.510 us; speedup vs baseline: 12.9090x; 1.0952x over previous
//
#include <hip/hip_runtime.h>
#include <hip/hip_bf16.h>
#include <cstddef>
#include <cstdint>

typedef __hip_bfloat16 bf16;
typedef __attribute__((ext_vector_type(2))) _Float16 half2v;
typedef __attribute__((ext_vector_type(8))) _Float16 half8;
typedef __attribute__((ext_vector_type(8))) short short8;
typedef __attribute__((ext_vector_type(4))) float f32x4;
typedef __attribute__((ext_vector_type(2))) unsigned long long u64x2;

// ---------- helpers ----------
__device__ inline float ldf(const float* p) { return *p; }
__device__ inline float ldf(const bf16* p) { return __bfloat162float(*p); }
__device__ inline void stf(float* p, float v) { *p = v; }
__device__ inline void stf(bf16* p, float v) { *p = __float2bfloat16(v); }
__device__ inline short bfb(float v) { return __builtin_bit_cast(short, __float2bfloat16(v)); }

__device__ inline half8 h8_from(unsigned long long lo, unsigned long long hi) {
    u64x2 t; t.x = lo; t.y = hi;
    return __builtin_bit_cast(half8, t);
}
__device__ inline float fsig(float x) {
    x = fminf(fmaxf(x, -60.f), 60.f);
    return 1.f / (1.f + __expf(-x));
}
__device__ inline float ftanh(float x) {
    x = fminf(fmaxf(x, -15.f), 15.f);
    float e = __expf(2.f * x);
    return 1.f - 2.f / (e + 1.f);
}
__device__ inline void unpack8(uint4 u, float4& lo, float4& hi) {
    uint32_t w0 = u.x, w1 = u.y, w2 = u.z, w3 = u.w;
    lo.x = __builtin_bit_cast(float, (w0 & 0xffffu) << 16);
    lo.y = __builtin_bit_cast(float, w0 & 0xffff0000u);
    lo.z = __builtin_bit_cast(float, (w1 & 0xffffu) << 16);
    lo.w = __builtin_bit_cast(float, w1 & 0xffff0000u);
    hi.x = __builtin_bit_cast(float, (w2 & 0xffffu) << 16);
    hi.y = __builtin_bit_cast(float, w2 & 0xffff0000u);
    hi.z = __builtin_bit_cast(float, (w3 & 0xffffu) << 16);
    hi.w = __builtin_bit_cast(float, w3 & 0xffff0000u);
}
__device__ inline uint32_t pk2(float a, float b) {
    return ((uint32_t)(uint16_t)bfb(a)) | (((uint32_t)(uint16_t)bfb(b)) << 16);
}

// Problem constants: BS=32, T=64, NE=32, NA=8, ED=128, H=512, A=512, NH=8, HD=64, NACT=32

// ---------- MFMA bf16 GEMM, 2-phase double-buffered staging ----------
template<int ACT, bool QG, typename TA, typename TC>
__global__ __launch_bounds__(256) void mfma_gemm_k(
    const TA* __restrict__ A, const bf16* __restrict__ Bt,
    const float* __restrict__ bias, TC* __restrict__ C,
    int M, int N, int K)
{
    __shared__ short As[2][4096];
    __shared__ short Bs[2][4096];
    const int tid = threadIdx.x;
    const int lane = tid & 63, wid = tid >> 6;
    const int wm = wid >> 1, wn = wid & 1;
    const int bm = blockIdx.y * 128, bn = blockIdx.x * 128;
    const int fr = lane & 15, fq = lane >> 4;

    f32x4 acc[4][4] = {};

    auto stage = [&](int buf, int k0) {
#if __has_builtin(__builtin_amdgcn_global_load_lds)
        #pragma unroll
        for (int j = 0; j < 2; ++j) {
            int jj = wid * 2 + j;
            int row = jj * 16 + (lane >> 2);
            const short* src = (const short*)Bt + (size_t)(bn + row) * K + k0 + (lane & 3) * 8;
            __builtin_amdgcn_global_load_lds(
                (const __attribute__((address_space(1))) void*)src,
                (__attribute__((address_space(3))) void*)&Bs[buf][jj * 512], 16, 0, 0);
        }
        if constexpr (sizeof(TA) == 2) {
            #pragma unroll
            for (int j = 0; j < 2; ++j) {
                int jj = wid * 2 + j;
                int row = jj * 16 + (lane >> 2);
                int gm = bm + row;
                int ar = QG ? (((gm >> 3) << 5) | (gm & 7)) : gm;
                const short* src = (const short*)A + (size_t)ar * K + k0 + (lane & 3) * 8;
                __builtin_amdgcn_global_load_lds(
                    (const __attribute__((address_space(1))) void*)src,
                    (__attribute__((address_space(3))) void*)&As[buf][jj * 512], 16, 0, 0);
            }
        } else {
            int sr = tid >> 1, sk = (tid & 1) * 16;
            int gm = bm + sr;
            int ar = QG ? (((gm >> 3) << 5) | (gm & 7)) : gm;
            const float* ap = (const float*)A + (size_t)ar * K + k0 + sk;
            float4 f0 = *(const float4*)(ap);
            float4 f1 = *(const float4*)(ap + 4);
            float4 f2 = *(const float4*)(ap + 8);
            float4 f3 = *(const float4*)(ap + 12);
            short tmp[16] = {bfb(f0.x), bfb(f0.y), bfb(f0.z), bfb(f0.w),
                             bfb(f1.x), bfb(f1.y), bfb(f1.z), bfb(f1.w),
                             bfb(f2.x), bfb(f2.y), bfb(f2.z), bfb(f2.w),
                             bfb(f3.x), bfb(f3.y), bfb(f3.z), bfb(f3.w)};
            *(uint4*)&As[buf][sr * 32 + sk]     = *(const uint4*)&tmp[0];
            *(uint4*)&As[buf][sr * 32 + sk + 8] = *(const uint4*)&tmp[8];
        }
#else
        {
            int sr = tid >> 1, sk = (tid & 1) * 16;
            int gm = bm + sr;
            int ar = QG ? (((gm >> 3) << 5) | (gm & 7)) : gm;
            if constexpr (sizeof(TA) == 4) {
                const float* ap = (const float*)A + (size_t)ar * K + k0 + sk;
                short tmp[16];
                #pragma unroll
                for (int j = 0; j < 16; ++j) tmp[j] = bfb(ap[j]);
                *(uint4*)&As[buf][sr * 32 + sk]     = *(const uint4*)&tmp[0];
                *(uint4*)&As[buf][sr * 32 + sk + 8] = *(const uint4*)&tmp[8];
            } else {
                const short* ap = (const short*)A + (size_t)ar * K + k0 + sk;
                *(uint4*)&As[buf][sr * 32 + sk]     = *(const uint4*)(ap);
                *(uint4*)&As[buf][sr * 32 + sk + 8] = *(const uint4*)(ap + 8);
            }
            const short* bp = (const short*)Bt + (size_t)(bn + sr) * K + k0 + sk;
            *(uint4*)&Bs[buf][sr * 32 + sk]     = *(const uint4*)(bp);
            *(uint4*)&Bs[buf][sr * 32 + sk + 8] = *(const uint4*)(bp + 8);
        }
#endif
    };

    const int nt = K >> 5;
    stage(0, 0);
    __syncthreads();

    for (int t = 0; t < nt; ++t) {
        int cur = t & 1;
        if (t + 1 < nt) stage(cur ^ 1, (t + 1) * 32);

        short8 af[4], bg[4];
        #pragma unroll
        for (int m = 0; m < 4; ++m)
            af[m] = *(const short8*)&As[cur][(wm * 64 + m * 16 + fr) * 32 + fq * 8];
        #pragma unroll
        for (int n = 0; n < 4; ++n)
            bg[n] = *(const short8*)&Bs[cur][(wn * 64 + n * 16 + fr) * 32 + fq * 8];
        #pragma unroll
        for (int m = 0; m < 4; ++m)
            #pragma unroll
            for (int n = 0; n < 4; ++n)
                acc[m][n] = __builtin_amdgcn_mfma_f32_16x16x32_bf16(
                    af[m], bg[n], acc[m][n], 0, 0, 0);
        __syncthreads();
    }

    #pragma unroll
    for (int m = 0; m < 4; ++m) {
        #pragma unroll
        for (int n = 0; n < 4; ++n) {
            int col = bn + wn * 64 + n * 16 + fr;
            float bv = bias[col];
            #pragma unroll
            for (int r = 0; r < 4; ++r) {
                int row = bm + wm * 64 + m * 16 + fq * 4 + r;
                float v = acc[m][n][r] + bv;
                if (ACT == 1) v = fmaxf(v, 0.f);
                if (ACT == 2 && col >= 512) v = fmaxf(v, 0.f);
                stf(&C[(size_t)row * N + col], v);
            }
        }
    }
}

// ---------- prep: tiled transposes + ha/bkv tail ----------
__global__ __launch_bounds__(256) void prep_all_k(
    const float* __restrict__ W1, const float* __restrict__ Wq,
    const float* __restrict__ Wk, const float* __restrict__ Wv,
    const float* __restrict__ Wo, const float* __restrict__ h0,
    const float* __restrict__ bk, const float* __restrict__ bv,
    bf16* __restrict__ W1t, bf16* __restrict__ Wqt, bf16* __restrict__ Wkvt,
    bf16* __restrict__ Wot, _Float16* __restrict__ ha, float* __restrict__ bkv)
{
    int blk = blockIdx.x;
    int tid = threadIdx.x;
    if (blk < 848) {
        const float* src; bf16* dst; int K, N, ti;
        if (blk < 64)       { src = W1; dst = W1t;  K = 128; N = 512; ti = blk; }
        else if (blk < 320) { src = Wq; dst = Wqt;  K = 512; N = 512; ti = blk - 64; }
        else if (blk < 576) { src = Wk; dst = Wkvt; K = 512; N = 512; ti = blk - 320; }
        else if (blk < 832) { src = Wv; dst = Wkvt + 512 * 512; K = 512; N = 512; ti = blk - 576; }
        else                { src = Wo; dst = Wot;  K = 512; N = 32;  ti = blk - 832; }
        int kt = K >> 5;
        int tk = ti % kt, tn = ti / kt;
        int k0 = tk * 32, n0 = tn * 32;
        __shared__ float tile[32][33];
        int tx = tid & 31, ty = tid >> 5;
        #pragma unroll
        for (int i = 0; i < 4; ++i) {
            int r = ty + i * 8;
            tile[r][tx] = src[(size_t)(k0 + r) * N + n0 + tx];
        }
        __syncthreads();
        #pragma unroll
        for (int i = 0; i < 4; ++i) {
            int r = ty + i * 8;
            if (n0 + r < N)
                dst[(size_t)(n0 + r) * K + k0 + tx] = __float2bfloat16(tile[tx][r]);
        }
        return;
    }
    int idx = (blk - 848) * 256 + tid;
    if (idx < 131072) { ha[idx] = (_Float16)h0[idx]; return; }
    idx -= 131072;
    if (idx < 1024) { bkv[idx] = (idx < 512) ? bk[idx] : bv[idx - 512]; return; }
}

// ---------- qout MFMA ----------
__global__ __launch_bounds__(256) void qout_mfma_k(
    const float* __restrict__ hs, const bf16* __restrict__ Wot,
    const float* __restrict__ bo, const int* __restrict__ smask,
    float* __restrict__ out)
{
    __shared__ short Bs2[32 * 520];
    __shared__ short As2[128 * 32];
    const int tid = threadIdx.x;
    const int lane = tid & 63, wid = tid >> 6;
    const int bm = blockIdx.x * 128;
    const int fr = lane & 15, fq = lane >> 4;

    for (int i = tid; i < 2048; i += 256) {
        int row = i >> 6, col = (i & 63) * 8;
        *(uint4*)&Bs2[row * 520 + col] = *(const uint4*)((const short*)Wot + row * 512 + col);
    }

    f32x4 acc[2][2] = {};
    for (int k0 = 0; k0 < 512; k0 += 32) {
        {
            int sr = tid >> 1, sk = (tid & 1) * 16;
            const float* ap = hs + (size_t)(bm + sr) * 512 + k0 + sk;
            float4 f0 = *(const float4*)(ap);
            float4 f1 = *(const float4*)(ap + 4);
            float4 f2 = *(const float4*)(ap + 8);
            float4 f3 = *(const float4*)(ap + 12);
            short tmp[16] = {bfb(f0.x), bfb(f0.y), bfb(f0.z), bfb(f0.w),
                             bfb(f1.x), bfb(f1.y), bfb(f1.z), bfb(f1.w),
                             bfb(f2.x), bfb(f2.y), bfb(f2.z), bfb(f2.w),
                             bfb(f3.x), bfb(f3.y), bfb(f3.z), bfb(f3.w)};
            *(uint4*)&As2[sr * 32 + sk]     = *(const uint4*)&tmp[0];
            *(uint4*)&As2[sr * 32 + sk + 8] = *(const uint4*)&tmp[8];
        }
        __syncthreads();
        short8 af[2], bg[2];
        #pragma unroll
        for (int m = 0; m < 2; ++m)
            af[m] = *(const short8*)&As2[(wid * 32 + m * 16 + fr) * 32 + fq * 8];
        #pragma unroll
        for (int n = 0; n < 2; ++n)
            bg[n] = *(const short8*)&Bs2[(n * 16 + fr) * 520 + k0 + fq * 8];
        #pragma unroll
        for (int m = 0; m < 2; ++m)
            #pragma unroll
            for (int n = 0; n < 2; ++n)
                acc[m][n] = __builtin_amdgcn_mfma_f32_16x16x32_bf16(
                    af[m], bg[n], acc[m][n], 0, 0, 0);
        __syncthreads();
    }

    #pragma unroll
    for (int m = 0; m < 2; ++m) {
        #pragma unroll
        for (int n = 0; n < 2; ++n) {
            int col = n * 16 + fr;
            float bv = bo[col];
            #pragma unroll
            for (int r = 0; r < 4; ++r) {
                int row = bm + wid * 32 + m * 16 + fq * 4 + r;
                int a_ = row & 7, t_ = (row >> 3) & 63, b_ = row >> 9;
                bool mz = smask[((b_ << 6) + t_) * 32 + a_] != 0;
                out[(size_t)row * 32 + col] = mz ? 0.f : (acc[m][n][r] + bv);
            }
        }
    }
}

// ---------- attention: vectorized LDS (b128 reads), packed bf16 store ----------
#define AST 68   // row stride (floats): 68 % 32 = 4; 272B rows, 16B-aligned
__global__ __launch_bounds__(64) void attn_k(
    const bf16* __restrict__ qb, const bf16* __restrict__ kb, const bf16* __restrict__ vb,
    const int* __restrict__ obs, const int* __restrict__ smask, bf16* __restrict__ xs,
    int kvstride)
{
    __shared__ float qs[8 * AST], ks[32 * AST], vs[32 * AST], wsm[8 * 33];
    int bid = blockIdx.x;
    int h = bid & 7;
    int bt = bid >> 3;
    int t = bt & 63, b = bt >> 6;
    int tid = threadIdx.x;

    {
        int srow = tid >> 3, c0 = (tid & 7) * 8;
        float4 lo, hi;
        uint4 qv = *(const uint4*)&qb[((size_t)bt * 8 + srow) * 512 + h * 64 + c0];
        unpack8(qv, lo, hi);
        *(float4*)&qs[srow * AST + c0] = lo;
        *(float4*)&qs[srow * AST + c0 + 4] = hi;
        #pragma unroll
        for (int i = 0; i < 4; ++i) {
            int row = srow + i * 8;
            uint4 kv4 = *(const uint4*)&kb[((size_t)bt * 32 + row) * kvstride + h * 64 + c0];
            unpack8(kv4, lo, hi);
            *(float4*)&ks[row * AST + c0] = lo;
            *(float4*)&ks[row * AST + c0 + 4] = hi;
            uint4 vv4 = *(const uint4*)&vb[((size_t)bt * 32 + row) * kvstride + h * 64 + c0];
            unpack8(vv4, lo, hi);
            *(float4*)&vs[row * AST + c0] = lo;
            *(float4*)&vs[row * AST + c0 + 4] = hi;
        }
    }
    __syncthreads();

    int ql = tid >> 3, jl = tid & 7;
    // ---- QK: float4 LDS reads ----
    float s[4];
    #pragma unroll
    for (int c = 0; c < 4; ++c) {
        int kl = jl + c * 8;
        float4 a4 = make_float4(0.f, 0.f, 0.f, 0.f);
        #pragma unroll 4
        for (int d4 = 0; d4 < 16; ++d4) {
            float4 q4 = *(const float4*)&qs[ql * AST + d4 * 4];
            float4 k4 = *(const float4*)&ks[kl * AST + d4 * 4];
            a4.x += q4.x * k4.x; a4.y += q4.y * k4.y;
            a4.z += q4.z * k4.z; a4.w += q4.w * k4.w;
        }
        float acc = (a4.x + a4.y) + (a4.z + a4.w);
        acc *= 0.125f;
        bool m = obs[(((size_t)bt * 32) + ql) * 32 + kl] != 0;
        s[c] = m ? -__builtin_inff() : acc;
    }
    float mx = fmaxf(fmaxf(s[0], s[1]), fmaxf(s[2], s[3]));
    for (int off = 1; off < 8; off <<= 1) mx = fmaxf(mx, __shfl_xor(mx, off));
    float e4[4]; float sum = 0.f;
    bool allmasked = (mx == -__builtin_inff());
    #pragma unroll
    for (int c = 0; c < 4; ++c) {
        e4[c] = (allmasked || s[c] == -__builtin_inff()) ? 0.f : expf(s[c] - mx);
        sum += e4[c];
    }
    for (int off = 1; off < 8; off <<= 1) sum += __shfl_xor(sum, off);
    float inv = (sum > 0.f) ? 1.f / sum : 0.f;
    #pragma unroll
    for (int c = 0; c < 4; ++c) wsm[ql * 33 + jl + c * 8] = e4[c] * inv;
    __syncthreads();

    // ---- PV: lane owns (ql, d = jl*8..+7); float4 v-reads; packed 16B store ----
    bool amask = smask[(size_t)bt * 32 + ql] != 0;
    int d0 = jl * 8;
    float4 o0 = make_float4(0.f, 0.f, 0.f, 0.f);
    float4 o1 = make_float4(0.f, 0.f, 0.f, 0.f);
    #pragma unroll 4
    for (int kl = 0; kl < 32; ++kl) {
        float w = wsm[ql * 33 + kl];
        float4 v0 = *(const float4*)&vs[kl * AST + d0];
        float4 v1 = *(const float4*)&vs[kl * AST + d0 + 4];
        o0.x += w * v0.x; o0.y += w * v0.y; o0.z += w * v0.z; o0.w += w * v0.w;
        o1.x += w * v1.x; o1.y += w * v1.y; o1.z += w * v1.z; o1.w += w * v1.w;
    }
    if (amask) { o0 = make_float4(0.f, 0.f, 0.f, 0.f); o1 = o0; }
    uint4 pk;
    pk.x = pk2(o0.x, o0.y); pk.y = pk2(o0.z, o0.w);
    pk.z = pk2(o1.x, o1.y); pk.w = pk2(o1.z, o1.w);
    *(uint4*)&xs[((size_t)(t * 256 + b * 8 + ql)) * 512 + h * 64 + d0] = pk;
}

// ---------- GRU (round-14 proven): per-wave int flags + s_sleep poll, gi in shadow ----------
__global__ __launch_bounds__(128, 1) void gru_xcd_k(
    const bf16* __restrict__ xs, const float* __restrict__ Wih,
    const float* __restrict__ bih,
    const float* __restrict__ Whh, const float* __restrict__ bhh,
    const float* __restrict__ h0,
    const int* __restrict__ smask, float* __restrict__ hs_out,
    _Float16* __restrict__ ha, _Float16* __restrict__ hb, int* __restrict__ flags)
{
    __shared__ _Float16 wh16[48 * 520];
    __shared__ short    wi16[48 * 520];
    const int tid = threadIdx.x;
    const int lane = tid & 63, wid = tid >> 6;
    const int g = blockIdx.x;
    const int grp = g & 7, cu = g >> 3;
    const int r0 = grp * 32;
    const int hc0 = cu * 16;
    const int fr = lane & 15, fq = lane >> 4;
    const int hcol = hc0 + fr;
    const int rw0 = r0 + wid * 16;
    const int row0 = rw0 + fq * 4;

    for (int i = tid; i < 6144; i += 128) {
        int flat = i * 4;
        int r = flat >> 9, c = flat & 511;
        int wr = (r >> 4) * 512 + hc0 + (r & 15);
        float4 v = *(const float4*)(Whh + (size_t)wr * 512 + c);
        half2v p0; p0[0] = (_Float16)v.x; p0[1] = (_Float16)v.y;
        half2v p1; p1[0] = (_Float16)v.z; p1[1] = (_Float16)v.w;
        *(uint32_t*)&wh16[r * 520 + c]     = __builtin_bit_cast(uint32_t, p0);
        *(uint32_t*)&wh16[r * 520 + c + 2] = __builtin_bit_cast(uint32_t, p1);
        float4 u = *(const float4*)(Wih + (size_t)wr * 512 + c);
        uint32_t w0 = (uint32_t)(uint16_t)bfb(u.x) | ((uint32_t)(uint16_t)bfb(u.y) << 16);
        uint32_t w1 = (uint32_t)(uint16_t)bfb(u.z) | ((uint32_t)(uint16_t)bfb(u.w) << 16);
        *(uint32_t*)&wi16[r * 520 + c]     = w0;
        *(uint32_t*)&wi16[r * 520 + c + 2] = w1;
    }

    const float bhr = bhh[hcol], bhz = bhh[512 + hcol], bhn = bhh[1024 + hcol];
    const float bir = bih[hcol], biz = bih[512 + hcol], bin_ = bih[1024 + hcol];

    float hp[4];
    #pragma unroll
    for (int r = 0; r < 4; ++r)
        hp[r] = h0[(size_t)(row0 + r) * 512 + hcol];

    __syncthreads();

    f32x4 gcur[3] = {};
    int mcur[4];
    {
        const short* xp = (const short*)xs + ((size_t)0 * 256 + rw0 + fr) * 512 + fq * 8;
        short8 ax[16];
        #pragma unroll
        for (int ks = 0; ks < 16; ++ks) ax[ks] = *(const short8*)(xp + ks * 32);
        #pragma unroll
        for (int ks = 0; ks < 16; ++ks) {
            const short* bb = &wi16[fr * 520 + ks * 32 + fq * 8];
            short8 b0 = *(const short8*)(bb);
            short8 b1 = *(const short8*)(bb + 16 * 520);
            short8 b2 = *(const short8*)(bb + 32 * 520);
            gcur[0] = __builtin_amdgcn_mfma_f32_16x16x32_bf16(ax[ks], b0, gcur[0], 0, 0, 0);
            gcur[1] = __builtin_amdgcn_mfma_f32_16x16x32_bf16(ax[ks], b1, gcur[1], 0, 0, 0);
            gcur[2] = __builtin_amdgcn_mfma_f32_16x16x32_bf16(ax[ks], b2, gcur[2], 0, 0, 0);
        }
        #pragma unroll
        for (int r = 0; r < 4; ++r) {
            int row = row0 + r;
            mcur[r] = smask[(((row >> 3) << 6) + 0) * 32 + (row & 7)];
        }
    }

    for (int t = 0; t < 64; ++t) {
        const _Float16* hsrc = (t & 1) ? hb : ha;
        _Float16*       hdst = (t & 1) ? ha : hb;

        half8 aA[16];
        {
            const unsigned long long* ap = (const unsigned long long*)
                (hsrc + (size_t)(rw0 + fr) * 512 + fq * 8);
            #pragma unroll
            for (int ks = 0; ks < 16; ++ks) {
                unsigned long long lo = __hip_atomic_load(ap + ks * 8,
                    __ATOMIC_RELAXED, __HIP_MEMORY_SCOPE_AGENT);
                unsigned long long hi = __hip_atomic_load(ap + ks * 8 + 1,
                    __ATOMIC_RELAXED, __HIP_MEMORY_SCOPE_AGENT);
                aA[ks] = h8_from(lo, hi);
            }
        }

        f32x4 acc[3] = {};
        #pragma unroll
        for (int ks = 0; ks < 16; ++ks) {
            const _Float16* bbase = &wh16[fr * 520 + ks * 32 + fq * 8];
            half8 b0 = *(const half8*)(bbase);
            half8 b1 = *(const half8*)(bbase + 16 * 520);
            half8 b2 = *(const half8*)(bbase + 32 * 520);
            acc[0] = __builtin_amdgcn_mfma_f32_16x16x32_f16(aA[ks], b0, acc[0], 0, 0, 0);
            acc[1] = __builtin_amdgcn_mfma_f32_16x16x32_f16(aA[ks], b1, acc[1], 0, 0, 0);
            acc[2] = __builtin_amdgcn_mfma_f32_16x16x32_f16(aA[ks], b2, acc[2], 0, 0, 0);
        }

        float hnv[4];
        #pragma unroll
        for (int r = 0; r < 4; ++r) {
            float rg = fsig(gcur[0][r] + bir + acc[0][r] + bhr);
            float zg = fsig(gcur[1][r] + biz + acc[1][r] + bhz);
            float ng = ftanh(gcur[2][r] + bin_ + rg * (acc[2][r] + bhn));
            float hn = (1.f - zg) * ng + zg * hp[r];
            hp[r] = hn;
            hnv[r] = hn;
            unsigned short hbits = __builtin_bit_cast(unsigned short, (_Float16)hn);
            __hip_atomic_store((unsigned short*)(hdst + (size_t)(row0 + r) * 512 + hcol),
                               hbits, __ATOMIC_RELAXED, __HIP_MEMORY_SCOPE_AGENT);
        }

        if (t != 63) {
            asm volatile("s_waitcnt vmcnt(0)" ::: "memory");
            __builtin_amdgcn_sched_barrier(0);
            if (lane == 0)
                __hip_atomic_store(flags + ((size_t)grp * 64 + t) * 64 + cu * 2 + wid, 1,
                                   __ATOMIC_RELAXED, __HIP_MEMORY_SCOPE_AGENT);
            #pragma unroll
            for (int r = 0; r < 4; ++r) {
                int row = row0 + r;
                int b_ = row >> 3, a_ = row & 7;
                hs_out[((size_t)((b_ << 6) + t) * 8 + a_) * 512 + hcol] =
                    mcur[r] ? 0.f : hnv[r];
            }
            f32x4 gnx[3] = {};
            {
                const short* xp = (const short*)xs +
                    ((size_t)(t + 1) * 256 + rw0 + fr) * 512 + fq * 8;
                short8 ax[16];
                #pragma unroll
                for (int ks = 0; ks < 16; ++ks) ax[ks] = *(const short8*)(xp + ks * 32);
                #pragma unroll
                for (int ks = 0; ks < 16; ++ks) {
                    const short* bb = &wi16[fr * 520 + ks * 32 + fq * 8];
                    short8 b0 = *(const short8*)(bb);
                    short8 b1 = *(const short8*)(bb + 16 * 520);
                    short8 b2 = *(const short8*)(bb + 32 * 520);
                    gnx[0] = __builtin_amdgcn_mfma_f32_16x16x32_bf16(ax[ks], b0, gnx[0], 0, 0, 0);
                    gnx[1] = __builtin_amdgcn_mfma_f32_16x16x32_bf16(ax[ks], b1, gnx[1], 0, 0, 0);
                    gnx[2] = __builtin_amdgcn_mfma_f32_16x16x32_bf16(ax[ks], b2, gnx[2], 0, 0, 0);
                }
            }
            int mnx[4];
            #pragma unroll
            for (int r = 0; r < 4; ++r) {
                int row = row0 + r;
                mnx[r] = smask[(((row >> 3) << 6) + (t + 1)) * 32 + (row & 7)];
            }
            const int* fp = flags + ((size_t)grp * 64 + t) * 64 + lane;
            long it = 0;
            for (;;) {
                int f = __hip_atomic_load(fp, __ATOMIC_RELAXED, __HIP_MEMORY_SCOPE_AGENT);
                if (__all(f != 0) || it > 100000000L) break;
                __builtin_amdgcn_s_sleep(1);
                ++it;
            }
            __builtin_amdgcn_sched_barrier(0);
            gcur[0] = gnx[0]; gcur[1] = gnx[1]; gcur[2] = gnx[2];
            mcur[0] = mnx[0]; mcur[1] = mnx[1]; mcur[2] = mnx[2]; mcur[3] = mnx[3];
        } else {
            #pragma unroll
            for (int r = 0; r < 4; ++r) {
                int row = row0 + r;
                int b_ = row >> 3, a_ = row & 7;
                hs_out[((size_t)((b_ << 6) + t) * 8 + a_) * 512 + hcol] =
                    mcur[r] ? 0.f : hnv[r];
            }
        }
    }
}

// ---------- launch ----------
extern "C" void kernel_launch(void* const* d_in, const int* in_sizes, int n_in,
                              void* d_out, int out_size, void* d_ws, size_t ws_size,
                              hipStream_t stream)
{
    const float* inputs = (const float*)d_in[0];
    const int*   obs    = (const int*)d_in[1];
    const int*   smask  = (const int*)d_in[2];
    const float* h0     = (const float*)d_in[3];
    const float* W1  = (const float*)d_in[4];  const float* b1  = (const float*)d_in[5];
    const float* Wq  = (const float*)d_in[6];  const float* bq  = (const float*)d_in[7];
    const float* Wk  = (const float*)d_in[8];  const float* bk  = (const float*)d_in[9];
    const float* Wv  = (const float*)d_in[10]; const float* bv  = (const float*)d_in[11];
    const float* Wih = (const float*)d_in[12]; const float* bih = (const float*)d_in[13];
    const float* Whh = (const float*)d_in[14]; const float* bhh = (const float*)d_in[15];
    const float* Wo  = (const float*)d_in[16]; const float* bo  = (const float*)d_in[17];

    char* ws = (char*)d_ws;
    bf16*  x    = (bf16*)(ws + 0);
    bf16*  xs   = (bf16*)(ws + 0);
    bf16*  qb   = (bf16*)(ws + 67108864ull);
    bf16*  kv   = (bf16*)(ws + 83886080ull);           // 128 MB
    bf16*  W1t  = (bf16*)(ws + 218103808ull);
    bf16*  Wqt  = (bf16*)(ws + 218234880ull);
    bf16*  Wkvt = (bf16*)(ws + 218759168ull);
    _Float16* ha = (_Float16*)(ws + 219807744ull);
    _Float16* hb = (_Float16*)(ws + 220069888ull);
    int*   flags = (int*)(ws + 220332032ull);
    float* bkv  = (float*)(ws + 220463104ull);
    bf16*  Wot  = (bf16*)(ws + 220467200ull);

    float* out    = (float*)d_out;
    float* hs_out = out + 524288;

    hipMemsetAsync(flags, 0, 131072, stream);

    prep_all_k<<<dim3(1365), 256, 0, stream>>>(
        W1, Wq, Wk, Wv, Wo, h0, bk, bv, W1t, Wqt, Wkvt, Wot, ha, bkv);
    mfma_gemm_k<1, false, float, bf16><<<dim3(4, 512), 256, 0, stream>>>(
        inputs, W1t, b1, x, 65536, 512, 128);
    mfma_gemm_k<0, true, bf16, bf16><<<dim3(4, 128), 256, 0, stream>>>(
        x, Wqt, bq, qb, 16384, 512, 512);
    mfma_gemm_k<2, false, bf16, bf16><<<dim3(8, 512), 256, 0, stream>>>(
        x, Wkvt, bkv, kv, 65536, 1024, 512);
    attn_k<<<dim3(16384), 64, 0, stream>>>(qb, kv, kv + 512, obs, smask, xs, 1024);
    gru_xcd_k<<<dim3(256), 128, 0, stream>>>(
        xs, Wih, bih, Whh, bhh, h0, smask, hs_out, ha, hb, flags);
    qout_mfma_k<<<dim3(128), 256, 0, stream>>>(hs_out, Wot, bo, smask, out);
}